// Round 1
// baseline (1011.139 us; speedup 1.0000x reference)
//
#include <hip/hip_runtime.h>
#include <hip/hip_bf16.h>
#include <stdint.h>

// MambaBlock: B=2, T=1024, D_MODEL=1024, D_INNER=2048, GROUPS=16, D_STATE=16
#define ROWS 2048      // B*T
#define DM   1024
#define DI   2048
#define PPAD 640       // 528 param rows padded to 5*128

typedef __bf16 bf16_t;
typedef __attribute__((ext_vector_type(8))) __bf16 bf16x8;
typedef __attribute__((ext_vector_type(4))) float f32x4;
typedef __attribute__((address_space(1))) void gvoid_t;
typedef __attribute__((address_space(3))) void lvoid_t;

// ---------------- weight fp32 -> bf16 (with zero row padding) ----------------
__global__ __launch_bounds__(256) void cvt_pad(const float* __restrict__ src,
                                               bf16_t* __restrict__ dst,
                                               int nsrc, int K) {
  int gid = blockIdx.x * 256 + threadIdx.x;
  int64_t e = (int64_t)gid * 4;
  int row = (int)(e / K);
  int col = (int)(e % K);
  float4 v = make_float4(0.f, 0.f, 0.f, 0.f);
  if (row < nsrc) v = *(const float4*)(src + (int64_t)row * K + col);
  bf16_t* o = dst + e;
  o[0] = (bf16_t)v.x; o[1] = (bf16_t)v.y; o[2] = (bf16_t)v.z; o[3] = (bf16_t)v.w;
}

// ---------------- rmsnorm (D=1024), fp32 in -> bf16 out ----------------
__global__ __launch_bounds__(256) void rmsnorm_k(const float* __restrict__ x,
                                                 const float* __restrict__ g,
                                                 bf16_t* __restrict__ out) {
  int row = blockIdx.x;
  int tid = threadIdx.x;
  const float4 v = *(const float4*)(x + (int64_t)row * DM + tid * 4);
  float ss = v.x * v.x + v.y * v.y + v.z * v.z + v.w * v.w;
#pragma unroll
  for (int o = 32; o; o >>= 1) ss += __shfl_xor(ss, o, 64);
  __shared__ float red[4];
  if ((tid & 63) == 0) red[tid >> 6] = ss;
  __syncthreads();
  float tot = red[0] + red[1] + red[2] + red[3];
  float sc = rsqrtf(tot * (1.0f / DM) + 1e-6f);
  const float4 gv = *(const float4*)(g + tid * 4);
  bf16_t* o = out + (int64_t)row * DM + tid * 4;
  o[0] = (bf16_t)(v.x * sc * gv.x);
  o[1] = (bf16_t)(v.y * sc * gv.y);
  o[2] = (bf16_t)(v.z * sc * gv.z);
  o[3] = (bf16_t)(v.w * sc * gv.w);
}

// ---------------- silu + fp32 -> bf16 (strided input, packed output) ----------------
__global__ __launch_bounds__(256) void silu_cvt(const float* __restrict__ in,
                                                bf16_t* __restrict__ out,
                                                int in_stride, int ncols) {
  int64_t e = ((int64_t)blockIdx.x * 256 + threadIdx.x) * 4;
  int row = (int)(e / ncols);
  int col = (int)(e % ncols);
  const float4 v = *(const float4*)(in + (int64_t)row * in_stride + col);
  bf16_t* o = out + e;
  o[0] = (bf16_t)(v.x / (1.f + expf(-v.x)));
  o[1] = (bf16_t)(v.y / (1.f + expf(-v.y)));
  o[2] = (bf16_t)(v.z / (1.f + expf(-v.z)));
  o[3] = (bf16_t)(v.w / (1.f + expf(-v.w)));
}

// ---------------- SSM coefficient prep: per (b,g,t) -> 48 floats ----------------
// layout ssmp[bg][t][48] = { expA[16], frac*b[16], c[16] }
__global__ __launch_bounds__(256) void ssm_prep(const float* __restrict__ params,
                                                const float* __restrict__ A_log,
                                                float* __restrict__ ssmp) {
  int gid = blockIdx.x * 256 + threadIdx.x;  // 32 * 1024
  int bg = gid >> 10, t = gid & 1023;
  int b = bg >> 4, g = bg & 15;
  const float* pr = params + (int64_t)(b * 1024 + t) * PPAD + g * 33;
  float raw = pr[0];
  float delta = raw > 0.f ? raw + log1pf(expf(-raw)) : log1pf(expf(raw));
  float* o = ssmp + (int64_t)gid * 48;
#pragma unroll
  for (int s = 0; s < 16; ++s) {
    float A = -expf(A_log[s]);
    float dA = delta * A;
    dA = fminf(10.f, fmaxf(-10.f, dA));
    float e = expf(dA);
    float frac = (fabsf(dA) < 1e-4f) ? delta : (e - 1.f) / (A + 1e-12f);
    o[s] = e;
    o[16 + s] = frac * pr[1 + s];
    o[32 + s] = pr[17 + s];
  }
}

// ---------------- sequential scan: 1 block per (b,group), 1 thread per channel ----
// fuses y = y_ssm * silu(gate), writes bf16
__global__ __launch_bounds__(128) void ssm_scan(const float* __restrict__ ssmp,
                                                const bf16_t* __restrict__ u,
                                                const float* __restrict__ xzg,
                                                bf16_t* __restrict__ yout) {
  __shared__ float sp[64 * 48];  // 12 KB: one 64-t block of coefficients
  int bg = blockIdx.x, b = bg >> 4, g = bg & 15;
  int tid = threadIdx.x;  // channel within group (0..127)
  int col = g * 128 + tid;
  float h[16];
#pragma unroll
  for (int s = 0; s < 16; ++s) h[s] = 0.f;
  const float* P = ssmp + (int64_t)bg * 1024 * 48;
  const bf16_t* up = u + (int64_t)b * 1024 * 2048 + col;
  const float* gp = xzg + (int64_t)b * 1024 * 4096 + 2048 + col;
  bf16_t* yp = yout + (int64_t)b * 1024 * 2048 + col;
  for (int t0 = 0; t0 < 1024; t0 += 64) {
    __syncthreads();
    const float4* src = (const float4*)(P + (int64_t)t0 * 48);
    float4* dst = (float4*)sp;
#pragma unroll
    for (int i = 0; i < 6; ++i) dst[i * 128 + tid] = src[i * 128 + tid];
    __syncthreads();
#pragma unroll 2
    for (int tt = 0; tt < 64; ++tt) {
      int64_t t = t0 + tt;
      float uv = (float)up[t * 2048];
      float gv = gp[t * 4096];
      const float* pt = sp + tt * 48;
      float acc = 0.f;
#pragma unroll
      for (int s = 0; s < 16; ++s) {
        float e = pt[s], fb = pt[16 + s], c = pt[32 + s];
        h[s] = fmaf(e, h[s], fb * uv);
        acc = fmaf(h[s], c, acc);
      }
      float sg = gv / (1.f + expf(-gv));
      yp[t * 2048] = (bf16_t)(acc * sg);
    }
  }
}

// ---------------- bf16 GEMM, B given as (N,K) row-major ("B^T"), fp32 out ------
// C[M,N] = A[M,K] * B[N,K]^T (+bias[N]) (+res[M,N]); M=2048 fixed by grid.y=16
// m97 structure: 128x128 tile, BK=64, 4 waves, global_load_lds dwordx4.
template <int EPI>  // bit0: bias, bit1: residual
__global__ __launch_bounds__(256) void gemm_bt(const bf16_t* __restrict__ A,
                                               const bf16_t* __restrict__ Bw,
                                               float* __restrict__ C,
                                               const float* __restrict__ bias,
                                               const float* __restrict__ res,
                                               int N, int K) {
  __shared__ bf16_t As[128 * 64];
  __shared__ bf16_t Bs[128 * 64];
  const int tid = threadIdx.x;
  const int wave = tid >> 6;
  const int lane = tid & 63;
  const int64_t m0 = (int64_t)blockIdx.y * 128;
  const int64_t n0 = (int64_t)blockIdx.x * 128;
  const int wm = (wave >> 1) * 64;
  const int wn = (wave & 1) * 64;
  f32x4 acc[4][4] = {};

  const int er = tid >> 3;        // row within 32-row stripe
  const int ec = (tid * 8) & 63;  // col (k) within tile

  for (int k0 = 0; k0 < K; k0 += 64) {
#pragma unroll
    for (int i = 0; i < 4; ++i) {
      const bf16_t* ga = A + (m0 + er + i * 32) * K + k0 + ec;
      __builtin_amdgcn_global_load_lds((gvoid_t*)ga,
                                       (lvoid_t*)&As[(i * 256 + wave * 64) * 8],
                                       16, 0, 0);
    }
#pragma unroll
    for (int i = 0; i < 4; ++i) {
      const bf16_t* gb = Bw + (n0 + er + i * 32) * K + k0 + ec;
      __builtin_amdgcn_global_load_lds((gvoid_t*)gb,
                                       (lvoid_t*)&Bs[(i * 256 + wave * 64) * 8],
                                       16, 0, 0);
    }
    __syncthreads();
    const int fr = lane & 15;
    const int kq = (lane >> 4) * 8;
#pragma unroll
    for (int kk = 0; kk < 2; ++kk) {
      bf16x8 af[4], bf[4];
#pragma unroll
      for (int mi = 0; mi < 4; ++mi)
        af[mi] = *reinterpret_cast<const bf16x8*>(&As[(wm + mi * 16 + fr) * 64 + kk * 32 + kq]);
#pragma unroll
      for (int ni = 0; ni < 4; ++ni)
        bf[ni] = *reinterpret_cast<const bf16x8*>(&Bs[(wn + ni * 16 + fr) * 64 + kk * 32 + kq]);
#pragma unroll
      for (int mi = 0; mi < 4; ++mi)
#pragma unroll
        for (int ni = 0; ni < 4; ++ni)
          acc[mi][ni] = __builtin_amdgcn_mfma_f32_16x16x32_bf16(af[mi], bf[ni], acc[mi][ni], 0, 0, 0);
    }
    __syncthreads();
  }
  // epilogue: C/D layout col=lane&15, row=(lane>>4)*4+j  [m89/m91 verified]
  const int crow = (lane >> 4) * 4;
  const int ccol = lane & 15;
#pragma unroll
  for (int mi = 0; mi < 4; ++mi) {
#pragma unroll
    for (int ni = 0; ni < 4; ++ni) {
#pragma unroll
      for (int j = 0; j < 4; ++j) {
        int64_t r = m0 + wm + mi * 16 + crow + j;
        int64_t cn = n0 + wn + ni * 16 + ccol;
        float v = acc[mi][ni][j];
        if (EPI & 1) v += bias[cn];
        if (EPI & 2) v += res[r * N + cn];
        C[r * N + cn] = v;
      }
    }
  }
}

extern "C" void kernel_launch(void* const* d_in, const int* in_sizes, int n_in,
                              void* d_out, int out_size, void* d_ws, size_t ws_size,
                              hipStream_t stream) {
  const float* x       = (const float*)d_in[0];
  const float* A_log   = (const float*)d_in[1];
  const float* g1      = (const float*)d_in[2];
  const float* g2      = (const float*)d_in[3];
  const float* W_in    = (const float*)d_in[4];
  const float* W_param = (const float*)d_in[5];
  const float* W_out   = (const float*)d_in[6];
  const float* W_ffn1  = (const float*)d_in[7];
  const float* b_ffn1  = (const float*)d_in[8];
  const float* W_ffn2  = (const float*)d_in[9];
  const float* b_ffn2  = (const float*)d_in[10];
  float* out = (float*)d_out;

  char* ws = (char*)d_ws;
  size_t off = 0;
  auto alloc = [&](size_t bytes) {
    char* p = ws + off;
    off += (bytes + 255) & ~(size_t)255;
    return p;
  };
  bf16_t* wb_in  = (bf16_t*)alloc(4096ull * 1024 * 2);
  bf16_t* wb_par = (bf16_t*)alloc((size_t)PPAD * 2048 * 2);
  bf16_t* wb_out = (bf16_t*)alloc(1024ull * 2048 * 2);
  bf16_t* wb_f1  = (bf16_t*)alloc(4096ull * 1024 * 2);
  bf16_t* wb_f2  = (bf16_t*)alloc(1024ull * 4096 * 2);
  bf16_t* zbuf   = (bf16_t*)alloc(2048ull * 1024 * 2);   // z, later h2
  float*  xzg    = (float*)alloc(2048ull * 4096 * 4);    // xz|gate, later ffn1 raw
  float*  params = (float*)alloc(2048ull * PPAD * 4);
  float*  ssmp   = (float*)alloc(32ull * 1024 * 48 * 4);
  float*  xmid   = (float*)alloc(2048ull * 1024 * 4);
  char*   regA   = alloc(2048ull * 4096 * 2);            // 16MB union
  bf16_t* xz_act = (bf16_t*)regA;                        // 8MB (dead after scan)
  bf16_t* y_b16  = (bf16_t*)(regA + 2048ull * 2048 * 2); // 8MB (dead after gemm3)
  bf16_t* f_act  = (bf16_t*)regA;                        // 16MB (overlays both)

  dim3 b256(256);
  // weights -> bf16 (W_param zero-padded 528 -> 640 rows)
  cvt_pad<<<4096, b256, 0, stream>>>(W_in, wb_in, 4096, 1024);
  cvt_pad<<<1280, b256, 0, stream>>>(W_param, wb_par, 528, 2048);
  cvt_pad<<<2048, b256, 0, stream>>>(W_out, wb_out, 1024, 2048);
  cvt_pad<<<4096, b256, 0, stream>>>(W_ffn1, wb_f1, 4096, 1024);
  cvt_pad<<<4096, b256, 0, stream>>>(W_ffn2, wb_f2, 1024, 4096);
  // z = rmsnorm(x, g1)
  rmsnorm_k<<<2048, b256, 0, stream>>>(x, g1, zbuf);
  // xz|gate = z @ W_in^T
  gemm_bt<0><<<dim3(32, 16), b256, 0, stream>>>(zbuf, wb_in, xzg, nullptr, nullptr, 4096, 1024);
  // xz_act = silu(xz)
  silu_cvt<<<4096, b256, 0, stream>>>(xzg, xz_act, 4096, 2048);
  // params = xz_act @ W_param^T
  gemm_bt<0><<<dim3(PPAD / 128, 16), b256, 0, stream>>>(xz_act, wb_par, params, nullptr, nullptr, PPAD, 2048);
  // SSM coefficients
  ssm_prep<<<128, b256, 0, stream>>>(params, A_log, ssmp);
  // scan + gate -> y (bf16)
  ssm_scan<<<32, dim3(128), 0, stream>>>(ssmp, xz_act, xzg, y_b16);
  // xmid = x + y @ W_out^T
  gemm_bt<2><<<dim3(8, 16), b256, 0, stream>>>(y_b16, wb_out, xmid, nullptr, x, 1024, 2048);
  // h2 = rmsnorm(xmid, g2)
  rmsnorm_k<<<2048, b256, 0, stream>>>(xmid, g2, zbuf);
  // ffn1 = h2 @ W_ffn1^T + b_ffn1
  gemm_bt<1><<<dim3(32, 16), b256, 0, stream>>>(zbuf, wb_f1, xzg, b_ffn1, nullptr, 4096, 1024);
  // act = silu(ffn1)
  silu_cvt<<<8192, b256, 0, stream>>>(xzg, f_act, 4096, 4096);
  // out = xmid + act @ W_ffn2^T + b_ffn2
  gemm_bt<3><<<dim3(8, 16), b256, 0, stream>>>(f_act, wb_f2, out, b_ffn2, xmid, 1024, 4096);
}

// Round 2
// 354.146 us; speedup vs baseline: 2.8552x; 2.8552x over previous
//
#include <hip/hip_runtime.h>
#include <hip/hip_bf16.h>
#include <stdint.h>

// MambaBlock: B=2, T=1024, D_MODEL=1024, D_INNER=2048, GROUPS=16, D_STATE=16
#define ROWS 2048      // B*T
#define DM   1024
#define DI   2048
#define PPAD 640       // 528 param rows padded to 5*128

typedef __bf16 bf16_t;
typedef __attribute__((ext_vector_type(8))) __bf16 bf16x8;
typedef __attribute__((ext_vector_type(4))) float f32x4;
typedef __attribute__((address_space(1))) void gvoid_t;
typedef __attribute__((address_space(3))) void lvoid_t;

// ---------------- weight fp32 -> bf16 (with zero row padding) ----------------
__global__ __launch_bounds__(256) void cvt_pad(const float* __restrict__ src,
                                               bf16_t* __restrict__ dst,
                                               int nsrc, int K) {
  int gid = blockIdx.x * 256 + threadIdx.x;
  int64_t e = (int64_t)gid * 4;
  int row = (int)(e / K);
  int col = (int)(e % K);
  float4 v = make_float4(0.f, 0.f, 0.f, 0.f);
  if (row < nsrc) v = *(const float4*)(src + (int64_t)row * K + col);
  bf16_t* o = dst + e;
  o[0] = (bf16_t)v.x; o[1] = (bf16_t)v.y; o[2] = (bf16_t)v.z; o[3] = (bf16_t)v.w;
}

// ---------------- rmsnorm (D=1024), fp32 in -> bf16 out ----------------
__global__ __launch_bounds__(256) void rmsnorm_k(const float* __restrict__ x,
                                                 const float* __restrict__ g,
                                                 bf16_t* __restrict__ out) {
  int row = blockIdx.x;
  int tid = threadIdx.x;
  const float4 v = *(const float4*)(x + (int64_t)row * DM + tid * 4);
  float ss = v.x * v.x + v.y * v.y + v.z * v.z + v.w * v.w;
#pragma unroll
  for (int o = 32; o; o >>= 1) ss += __shfl_xor(ss, o, 64);
  __shared__ float red[4];
  if ((tid & 63) == 0) red[tid >> 6] = ss;
  __syncthreads();
  float tot = red[0] + red[1] + red[2] + red[3];
  float sc = rsqrtf(tot * (1.0f / DM) + 1e-6f);
  const float4 gv = *(const float4*)(g + tid * 4);
  bf16_t* o = out + (int64_t)row * DM + tid * 4;
  o[0] = (bf16_t)(v.x * sc * gv.x);
  o[1] = (bf16_t)(v.y * sc * gv.y);
  o[2] = (bf16_t)(v.z * sc * gv.z);
  o[3] = (bf16_t)(v.w * sc * gv.w);
}

// ---------------- silu + fp32 -> bf16 (strided input, packed output) ----------------
__global__ __launch_bounds__(256) void silu_cvt(const float* __restrict__ in,
                                                bf16_t* __restrict__ out,
                                                int in_stride, int ncols) {
  int64_t e = ((int64_t)blockIdx.x * 256 + threadIdx.x) * 4;
  int row = (int)(e / ncols);
  int col = (int)(e % ncols);
  const float4 v = *(const float4*)(in + (int64_t)row * in_stride + col);
  bf16_t* o = out + e;
  o[0] = (bf16_t)(v.x / (1.f + expf(-v.x)));
  o[1] = (bf16_t)(v.y / (1.f + expf(-v.y)));
  o[2] = (bf16_t)(v.z / (1.f + expf(-v.z)));
  o[3] = (bf16_t)(v.w / (1.f + expf(-v.w)));
}

// ---------------- SSM coefficient prep: per (b,g,t) -> 48 floats ----------------
// layout ssmp[bg][t][48] = { dA_clipped[16], frac*b[16], c[16] }
__global__ __launch_bounds__(256) void ssm_prep(const float* __restrict__ params,
                                                const float* __restrict__ A_log,
                                                float* __restrict__ ssmp) {
  int gid = blockIdx.x * 256 + threadIdx.x;  // 32 * 1024
  int bg = gid >> 10, t = gid & 1023;
  int b = bg >> 4, g = bg & 15;
  const float* pr = params + (int64_t)(b * 1024 + t) * PPAD + g * 33;
  float raw = pr[0];
  float delta = raw > 0.f ? raw + log1pf(expf(-raw)) : log1pf(expf(raw));
  float* o = ssmp + (int64_t)gid * 48;
#pragma unroll
  for (int s = 0; s < 16; ++s) {
    float A = -expf(A_log[s]);
    float dA = delta * A;
    dA = fminf(10.f, fmaxf(-10.f, dA));
    float e = expf(dA);
    float frac = (fabsf(dA) < 1e-4f) ? delta : (e - 1.f) / (A + 1e-12f);
    o[s] = dA;
    o[16 + s] = frac * pr[1 + s];
    o[32 + s] = pr[17 + s];
  }
}

// swizzled transposed-u LDS accessor: element (ch, t) at
//   Ut[ch*64 + (((t>>3) ^ (ch&7)) << 3) + (t&7)]
// -> conflict-free ds_read_b128 of 8 consecutive t for lanes ch=0..63.

// ---------------- Phase A: per-chunk boundary operator -----------------------
// grid 512 = (bg=32) x (chunk=16); S[bgc][s][128], Etot[bgc][s]
__global__ __launch_bounds__(256) void ssm_chunk(const float* __restrict__ ssmp,
                                                 const bf16_t* __restrict__ u,
                                                 float* __restrict__ S,
                                                 float* __restrict__ Etot) {
  __shared__ __align__(16) float cf[64 * 48];
  __shared__ __align__(16) float Lb[64 * 16];
  __shared__ __align__(16) float w[16 * 64];
  __shared__ __align__(16) bf16_t Ut[128 * 64];
  int bgc = blockIdx.x;
  int bg = bgc >> 4, c = bgc & 15;
  int b = bg >> 4, g = bg & 15;
  int t0 = c * 64;
  int tid = threadIdx.x;
  // coeffs -> LDS
  {
    const float4* src = (const float4*)(ssmp + ((int64_t)bg * 1024 + t0) * 48);
    float4* dst = (float4*)cf;
#pragma unroll
    for (int i = 0; i < 3; ++i) dst[i * 256 + tid] = src[i * 256 + tid];
  }
  // u chunk -> LDS, transposed + swizzled
  {
    int lt = tid >> 4;
    int c8 = (tid & 15) * 8;
#pragma unroll
    for (int p = 0; p < 4; ++p) {
      int t = p * 16 + lt;
      bf16x8 v = *(const bf16x8*)(u + ((int64_t)(b * 1024) + t0 + t) * 2048 + g * 128 + c8);
#pragma unroll
      for (int j = 0; j < 8; ++j)
        Ut[(c8 + j) * 64 + (((t >> 3) ^ j) << 3) + (t & 7)] = v[j];
    }
  }
  __syncthreads();
  if (tid < 16) {  // inclusive cumsum of dA over t, per state s=tid
    float l = 0.f;
    for (int t = 0; t < 64; ++t) { l += cf[t * 48 + tid]; Lb[t * 16 + tid] = l; }
  }
  __syncthreads();
  {
    int s = tid >> 4, tb = (tid & 15) * 4;
    float lend = Lb[63 * 16 + s];
#pragma unroll
    for (int j = 0; j < 4; ++j) {
      int t = tb + j;
      w[s * 64 + t] = __expf(lend - Lb[t * 16 + s]) * cf[t * 48 + 16 + s];
    }
    if (tid < 16) Etot[(int64_t)bgc * 16 + tid] = __expf(Lb[63 * 16 + tid]);
  }
  __syncthreads();
  // S[s][ch] = sum_t w[s][t] * u[t][ch]
  {
    int ch = tid & 127;
    bf16x8 ur[8];
#pragma unroll
    for (int j = 0; j < 8; ++j)
      ur[j] = *(const bf16x8*)&Ut[ch * 64 + ((j ^ (ch & 7)) << 3)];
    float* Sp = S + (int64_t)bgc * 2048;
#pragma unroll
    for (int i = 0; i < 8; ++i) {
      int s = 2 * i + (tid >> 7);
      float acc = 0.f;
#pragma unroll
      for (int j = 0; j < 8; ++j) {
        float4 w0 = *(const float4*)&w[s * 64 + j * 8];
        float4 w1 = *(const float4*)&w[s * 64 + j * 8 + 4];
        acc += w0.x * (float)ur[j][0] + w0.y * (float)ur[j][1]
             + w0.z * (float)ur[j][2] + w0.w * (float)ur[j][3]
             + w1.x * (float)ur[j][4] + w1.y * (float)ur[j][5]
             + w1.z * (float)ur[j][6] + w1.w * (float)ur[j][7];
      }
      Sp[s * 128 + ch] = acc;
    }
  }
}

// ---------------- Phase B: sequential combine over 16 chunks ----------------
// 65536 threads; H[bgc][s][ch] = h_in of chunk
__global__ __launch_bounds__(256) void ssm_combine(const float* __restrict__ S,
                                                   const float* __restrict__ Etot,
                                                   float* __restrict__ H) {
  int gid = blockIdx.x * 256 + threadIdx.x;
  int bg = gid >> 11;
  int s = (gid >> 7) & 15;
  int ch = gid & 127;
  float h = 0.f;
  for (int c = 0; c < 16; ++c) {
    int bgc = bg * 16 + c;
    int64_t idx = ((int64_t)bgc * 16 + s) * 128 + ch;
    H[idx] = h;
    h = Etot[(int64_t)bgc * 16 + s] * h + S[idx];
  }
}

// ---------------- Phase C: intra-chunk kernel + h_in part + gate ------------
__global__ __launch_bounds__(256) void ssm_out(const float* __restrict__ ssmp,
                                               const bf16_t* __restrict__ u,
                                               const float* __restrict__ H,
                                               const float* __restrict__ xzg,
                                               bf16_t* __restrict__ yout) {
  __shared__ __align__(16) float cf[64 * 48];
  __shared__ __align__(16) float Lb[64 * 16];
  __shared__ __align__(16) float ce[64 * 16];
  __shared__ __align__(16) float Km[64 * 68];
  __shared__ __align__(16) bf16_t Ut[128 * 64];
  int bgc = blockIdx.x;
  int bg = bgc >> 4, c = bgc & 15;
  int b = bg >> 4, g = bg & 15;
  int t0 = c * 64;
  int tid = threadIdx.x;
  {
    const float4* src = (const float4*)(ssmp + ((int64_t)bg * 1024 + t0) * 48);
    float4* dst = (float4*)cf;
#pragma unroll
    for (int i = 0; i < 3; ++i) dst[i * 256 + tid] = src[i * 256 + tid];
  }
  {
    int lt = tid >> 4;
    int c8 = (tid & 15) * 8;
#pragma unroll
    for (int p = 0; p < 4; ++p) {
      int t = p * 16 + lt;
      bf16x8 v = *(const bf16x8*)(u + ((int64_t)(b * 1024) + t0 + t) * 2048 + g * 128 + c8);
#pragma unroll
      for (int j = 0; j < 8; ++j)
        Ut[(c8 + j) * 64 + (((t >> 3) ^ j) << 3) + (t & 7)] = v[j];
    }
  }
  __syncthreads();
  if (tid < 16) {
    float l = 0.f;
    for (int t = 0; t < 64; ++t) { l += cf[t * 48 + tid]; Lb[t * 16 + tid] = l; }
  }
  __syncthreads();
  // ce[t][s] = c[t][s] * exp(L[t][s])
  {
    int s = tid & 15, tq = tid >> 4;
#pragma unroll
    for (int j = 0; j < 4; ++j) {
      int t = tq * 4 + j;
      ce[t * 16 + s] = cf[t * 48 + 32 + s] * __expf(Lb[t * 16 + s]);
    }
  }
  // K[t][t'] = sum_s c[t,s] * exp(L[t,s]-L[t',s]) * fb[t',s]   (t >= t', else 0)
  {
    int t = tid >> 2, tp0 = (tid & 3) * 16;
    float4 cv[4], lv[4];
#pragma unroll
    for (int i = 0; i < 4; ++i) {
      cv[i] = *(const float4*)&cf[t * 48 + 32 + i * 4];
      lv[i] = *(const float4*)&Lb[t * 16 + i * 4];
    }
#pragma unroll
    for (int i = 0; i < 16; ++i) {
      int tp = tp0 + i;
      float k = 0.f;
      if (tp <= t) {
#pragma unroll
        for (int q = 0; q < 4; ++q) {
          float4 lpv = *(const float4*)&Lb[tp * 16 + q * 4];
          float4 fbv = *(const float4*)&cf[tp * 48 + 16 + q * 4];
          k += cv[q].x * __expf(lv[q].x - lpv.x) * fbv.x
             + cv[q].y * __expf(lv[q].y - lpv.y) * fbv.y
             + cv[q].z * __expf(lv[q].z - lpv.z) * fbv.z
             + cv[q].w * __expf(lv[q].w - lpv.w) * fbv.w;
        }
      }
      Km[t * 68 + tp] = k;
    }
  }
  __syncthreads();
  // y[t][ch] = sum_{t'<=t} K[t][t'] u[t'][ch] + sum_s ce[t][s] h_in[s][ch], * silu(gate)
  {
    int ch = tid & 127, th = tid >> 7;
    bf16x8 ur[8];
#pragma unroll
    for (int j = 0; j < 8; ++j)
      ur[j] = *(const bf16x8*)&Ut[ch * 64 + ((j ^ (ch & 7)) << 3)];
    float hr[16];
    const float* Hp = H + (int64_t)bgc * 2048 + ch;
#pragma unroll
    for (int s = 0; s < 16; ++s) hr[s] = Hp[s * 128];
    int col = g * 128 + ch;
    const float* gp = xzg + ((int64_t)(b * 1024) + t0) * 4096 + 2048 + col;
    bf16_t* yp = yout + ((int64_t)(b * 1024) + t0) * 2048 + col;
    for (int ti = 0; ti < 32; ++ti) {
      int t = th * 32 + ti;
      float acc = 0.f;
#pragma unroll
      for (int q = 0; q < 16; ++q) {
        float4 kv = *(const float4*)&Km[t * 68 + q * 4];
        int j = q >> 1;
        int e = (q & 1) * 4;
        acc += kv.x * (float)ur[j][e] + kv.y * (float)ur[j][e + 1]
             + kv.z * (float)ur[j][e + 2] + kv.w * (float)ur[j][e + 3];
      }
#pragma unroll
      for (int q = 0; q < 4; ++q) {
        float4 cev = *(const float4*)&ce[t * 16 + q * 4];
        acc += cev.x * hr[q * 4] + cev.y * hr[q * 4 + 1]
             + cev.z * hr[q * 4 + 2] + cev.w * hr[q * 4 + 3];
      }
      float gv = gp[(int64_t)t * 4096];
      float sg = gv / (1.f + __expf(-gv));
      yp[(int64_t)t * 2048] = (bf16_t)(acc * sg);
    }
  }
}

// ---------------- bf16 GEMM, B given as (N,K) row-major ("B^T"), fp32 out ------
template <int EPI>  // bit0: bias, bit1: residual
__global__ __launch_bounds__(256) void gemm_bt(const bf16_t* __restrict__ A,
                                               const bf16_t* __restrict__ Bw,
                                               float* __restrict__ C,
                                               const float* __restrict__ bias,
                                               const float* __restrict__ res,
                                               int N, int K) {
  __shared__ bf16_t As[128 * 64];
  __shared__ bf16_t Bs[128 * 64];
  const int tid = threadIdx.x;
  const int wave = tid >> 6;
  const int lane = tid & 63;
  const int64_t m0 = (int64_t)blockIdx.y * 128;
  const int64_t n0 = (int64_t)blockIdx.x * 128;
  const int wm = (wave >> 1) * 64;
  const int wn = (wave & 1) * 64;
  f32x4 acc[4][4] = {};

  const int er = tid >> 3;        // row within 32-row stripe
  const int ec = (tid * 8) & 63;  // col (k) within tile

  for (int k0 = 0; k0 < K; k0 += 64) {
#pragma unroll
    for (int i = 0; i < 4; ++i) {
      const bf16_t* ga = A + (m0 + er + i * 32) * K + k0 + ec;
      __builtin_amdgcn_global_load_lds((gvoid_t*)ga,
                                       (lvoid_t*)&As[(i * 256 + wave * 64) * 8],
                                       16, 0, 0);
    }
#pragma unroll
    for (int i = 0; i < 4; ++i) {
      const bf16_t* gb = Bw + (n0 + er + i * 32) * K + k0 + ec;
      __builtin_amdgcn_global_load_lds((gvoid_t*)gb,
                                       (lvoid_t*)&Bs[(i * 256 + wave * 64) * 8],
                                       16, 0, 0);
    }
    __syncthreads();
    const int fr = lane & 15;
    const int kq = (lane >> 4) * 8;
#pragma unroll
    for (int kk = 0; kk < 2; ++kk) {
      bf16x8 af[4], bf[4];
#pragma unroll
      for (int mi = 0; mi < 4; ++mi)
        af[mi] = *reinterpret_cast<const bf16x8*>(&As[(wm + mi * 16 + fr) * 64 + kk * 32 + kq]);
#pragma unroll
      for (int ni = 0; ni < 4; ++ni)
        bf[ni] = *reinterpret_cast<const bf16x8*>(&Bs[(wn + ni * 16 + fr) * 64 + kk * 32 + kq]);
#pragma unroll
      for (int mi = 0; mi < 4; ++mi)
#pragma unroll
        for (int ni = 0; ni < 4; ++ni)
          acc[mi][ni] = __builtin_amdgcn_mfma_f32_16x16x32_bf16(af[mi], bf[ni], acc[mi][ni], 0, 0, 0);
    }
    __syncthreads();
  }
  const int crow = (lane >> 4) * 4;
  const int ccol = lane & 15;
#pragma unroll
  for (int mi = 0; mi < 4; ++mi) {
#pragma unroll
    for (int ni = 0; ni < 4; ++ni) {
#pragma unroll
      for (int j = 0; j < 4; ++j) {
        int64_t r = m0 + wm + mi * 16 + crow + j;
        int64_t cn = n0 + wn + ni * 16 + ccol;
        float v = acc[mi][ni][j];
        if (EPI & 1) v += bias[cn];
        if (EPI & 2) v += res[r * N + cn];
        C[r * N + cn] = v;
      }
    }
  }
}

extern "C" void kernel_launch(void* const* d_in, const int* in_sizes, int n_in,
                              void* d_out, int out_size, void* d_ws, size_t ws_size,
                              hipStream_t stream) {
  const float* x       = (const float*)d_in[0];
  const float* A_log   = (const float*)d_in[1];
  const float* g1      = (const float*)d_in[2];
  const float* g2      = (const float*)d_in[3];
  const float* W_in    = (const float*)d_in[4];
  const float* W_param = (const float*)d_in[5];
  const float* W_out   = (const float*)d_in[6];
  const float* W_ffn1  = (const float*)d_in[7];
  const float* b_ffn1  = (const float*)d_in[8];
  const float* W_ffn2  = (const float*)d_in[9];
  const float* b_ffn2  = (const float*)d_in[10];
  float* out = (float*)d_out;

  char* ws = (char*)d_ws;
  size_t off = 0;
  auto alloc = [&](size_t bytes) {
    char* p = ws + off;
    off += (bytes + 255) & ~(size_t)255;
    return p;
  };
  bf16_t* wb_in  = (bf16_t*)alloc(4096ull * 1024 * 2);
  bf16_t* wb_par = (bf16_t*)alloc((size_t)PPAD * 2048 * 2);
  bf16_t* wb_out = (bf16_t*)alloc(1024ull * 2048 * 2);
  bf16_t* wb_f1  = (bf16_t*)alloc(4096ull * 1024 * 2);
  bf16_t* wb_f2  = (bf16_t*)alloc(1024ull * 4096 * 2);
  bf16_t* zbuf   = (bf16_t*)alloc(2048ull * 1024 * 2);   // z, later h2
  float*  xzg    = (float*)alloc(2048ull * 4096 * 4);    // xz|gate, later ffn1 raw
  float*  params = (float*)alloc(2048ull * PPAD * 4);    // dead after ssm_prep
  float*  ssmp   = (float*)alloc(32ull * 1024 * 48 * 4);
  float*  xmid   = (float*)alloc(2048ull * 1024 * 4);    // written after scan
  char*   regA   = alloc(2048ull * 4096 * 2);            // 16MB union
  bf16_t* xz_act = (bf16_t*)regA;                        // 8MB (dead after scan)
  bf16_t* y_b16  = (bf16_t*)(regA + 2048ull * 2048 * 2); // 8MB (dead after gemm3)
  bf16_t* f_act  = (bf16_t*)regA;                        // 16MB (overlays both)
  // scan scratch overlays dead regions:
  float* Sbuf = params;                                  // 4MB <= 5.24MB
  float* Etot = params + 32ull * 16 * 16 * 128;          // 32KB, after S
  float* Hbuf = xmid;                                    // 4MB <= 8MB, dead until gemm3

  dim3 b256(256);
  // weights -> bf16 (W_param zero-padded 528 -> 640 rows)
  cvt_pad<<<4096, b256, 0, stream>>>(W_in, wb_in, 4096, 1024);
  cvt_pad<<<1280, b256, 0, stream>>>(W_param, wb_par, 528, 2048);
  cvt_pad<<<2048, b256, 0, stream>>>(W_out, wb_out, 1024, 2048);
  cvt_pad<<<4096, b256, 0, stream>>>(W_ffn1, wb_f1, 4096, 1024);
  cvt_pad<<<4096, b256, 0, stream>>>(W_ffn2, wb_f2, 1024, 4096);
  // z = rmsnorm(x, g1)
  rmsnorm_k<<<2048, b256, 0, stream>>>(x, g1, zbuf);
  // xz|gate = z @ W_in^T
  gemm_bt<0><<<dim3(32, 16), b256, 0, stream>>>(zbuf, wb_in, xzg, nullptr, nullptr, 4096, 1024);
  // xz_act = silu(xz)
  silu_cvt<<<4096, b256, 0, stream>>>(xzg, xz_act, 4096, 2048);
  // params = xz_act @ W_param^T
  gemm_bt<0><<<dim3(PPAD / 128, 16), b256, 0, stream>>>(xz_act, wb_par, params, nullptr, nullptr, PPAD, 2048);
  // SSM coefficients
  ssm_prep<<<128, b256, 0, stream>>>(params, A_log, ssmp);
  // chunked scan
  ssm_chunk<<<512, b256, 0, stream>>>(ssmp, xz_act, Sbuf, Etot);
  ssm_combine<<<256, b256, 0, stream>>>(Sbuf, Etot, Hbuf);
  ssm_out<<<512, b256, 0, stream>>>(ssmp, xz_act, Hbuf, xzg, y_b16);
  // xmid = x + y @ W_out^T
  gemm_bt<2><<<dim3(8, 16), b256, 0, stream>>>(y_b16, wb_out, xmid, nullptr, x, 1024, 2048);
  // h2 = rmsnorm(xmid, g2)
  rmsnorm_k<<<2048, b256, 0, stream>>>(xmid, g2, zbuf);
  // ffn1 = h2 @ W_ffn1^T + b_ffn1
  gemm_bt<1><<<dim3(32, 16), b256, 0, stream>>>(zbuf, wb_f1, xzg, b_ffn1, nullptr, 4096, 1024);
  // act = silu(ffn1)
  silu_cvt<<<8192, b256, 0, stream>>>(xzg, f_act, 4096, 4096);
  // out = xmid + act @ W_ffn2^T + b_ffn2
  gemm_bt<3><<<dim3(8, 16), b256, 0, stream>>>(f_act, wb_f2, out, b_ffn2, xmid, 1024, 4096);
}

// Round 3
// 267.425 us; speedup vs baseline: 3.7810x; 1.3243x over previous
//
#include <hip/hip_runtime.h>
#include <hip/hip_bf16.h>
#include <stdint.h>

// MambaBlock: B=2, T=1024, D_MODEL=1024, D_INNER=2048, GROUPS=16, D_STATE=16
#define ROWS 2048      // B*T
#define DM   1024
#define DI   2048
#define PPAD 640       // 528 param rows padded to 5*128

typedef __bf16 bf16_t;
typedef __attribute__((ext_vector_type(8))) __bf16 bf16x8;
typedef __attribute__((ext_vector_type(4))) float f32x4;
typedef __attribute__((address_space(1))) void gvoid_t;
typedef __attribute__((address_space(3))) void lvoid_t;

// ---------------- weight fp32 -> bf16 (with zero row padding) ----------------
__global__ __launch_bounds__(256) void cvt_pad(const float* __restrict__ src,
                                               bf16_t* __restrict__ dst,
                                               int nsrc, int K) {
  int gid = blockIdx.x * 256 + threadIdx.x;
  int64_t e = (int64_t)gid * 4;
  int row = (int)(e / K);
  int col = (int)(e % K);
  float4 v = make_float4(0.f, 0.f, 0.f, 0.f);
  if (row < nsrc) v = *(const float4*)(src + (int64_t)row * K + col);
  bf16_t* o = dst + e;
  o[0] = (bf16_t)v.x; o[1] = (bf16_t)v.y; o[2] = (bf16_t)v.z; o[3] = (bf16_t)v.w;
}

// ---------------- rmsnorm (D=1024), fp32 in -> bf16 out ----------------
__global__ __launch_bounds__(256) void rmsnorm_k(const float* __restrict__ x,
                                                 const float* __restrict__ g,
                                                 bf16_t* __restrict__ out) {
  int row = blockIdx.x;
  int tid = threadIdx.x;
  const float4 v = *(const float4*)(x + (int64_t)row * DM + tid * 4);
  float ss = v.x * v.x + v.y * v.y + v.z * v.z + v.w * v.w;
#pragma unroll
  for (int o = 32; o; o >>= 1) ss += __shfl_xor(ss, o, 64);
  __shared__ float red[4];
  if ((tid & 63) == 0) red[tid >> 6] = ss;
  __syncthreads();
  float tot = red[0] + red[1] + red[2] + red[3];
  float sc = rsqrtf(tot * (1.0f / DM) + 1e-6f);
  const float4 gv = *(const float4*)(g + tid * 4);
  bf16_t* o = out + (int64_t)row * DM + tid * 4;
  o[0] = (bf16_t)(v.x * sc * gv.x);
  o[1] = (bf16_t)(v.y * sc * gv.y);
  o[2] = (bf16_t)(v.z * sc * gv.z);
  o[3] = (bf16_t)(v.w * sc * gv.w);
}

// ---------------- silu + fp32 -> bf16 (strided input, packed output) ----------------
__global__ __launch_bounds__(256) void silu_cvt(const float* __restrict__ in,
                                                bf16_t* __restrict__ out,
                                                int in_stride, int ncols) {
  int64_t e = ((int64_t)blockIdx.x * 256 + threadIdx.x) * 4;
  int row = (int)(e / ncols);
  int col = (int)(e % ncols);
  const float4 v = *(const float4*)(in + (int64_t)row * in_stride + col);
  bf16_t* o = out + e;
  o[0] = (bf16_t)(v.x / (1.f + expf(-v.x)));
  o[1] = (bf16_t)(v.y / (1.f + expf(-v.y)));
  o[2] = (bf16_t)(v.z / (1.f + expf(-v.z)));
  o[3] = (bf16_t)(v.w / (1.f + expf(-v.w)));
}

// ---------------- SSM coefficient prep (sums nparts split-K partials) --------
// layout ssmp[bg][t][48] = { dA_clipped[16], frac*b[16], c[16] }
__global__ __launch_bounds__(256) void ssm_prep(const float* __restrict__ params,
                                                const float* __restrict__ A_log,
                                                float* __restrict__ ssmp, int nparts) {
  int gid = blockIdx.x * 256 + threadIdx.x;  // 32 * 1024
  int bg = gid >> 10, t = gid & 1023;
  int b = bg >> 4, g = bg & 15;
  float acc[33];
#pragma unroll
  for (int i = 0; i < 33; ++i) acc[i] = 0.f;
  for (int p = 0; p < nparts; ++p) {
    const float* pr = params + (int64_t)p * ROWS * PPAD + (int64_t)(b * 1024 + t) * PPAD + g * 33;
#pragma unroll
    for (int i = 0; i < 33; ++i) acc[i] += pr[i];
  }
  float raw = acc[0];
  float delta = raw > 0.f ? raw + log1pf(expf(-raw)) : log1pf(expf(raw));
  float* o = ssmp + (int64_t)gid * 48;
#pragma unroll
  for (int s = 0; s < 16; ++s) {
    float A = -expf(A_log[s]);
    float dA = delta * A;
    dA = fminf(10.f, fmaxf(-10.f, dA));
    float e = expf(dA);
    float frac = (fabsf(dA) < 1e-4f) ? delta : (e - 1.f) / (A + 1e-12f);
    o[s] = dA;
    o[16 + s] = frac * acc[1 + s];
    o[32 + s] = acc[17 + s];
  }
}

// ---------------- split-K reduce + residual + rmsnorm (fused) ---------------
// xmid = x + sum_p P[p]; zb = rmsnorm(xmid, g)
__global__ __launch_bounds__(256) void reduce_rms(const float* __restrict__ P,
                                                  const float* __restrict__ x,
                                                  const float* __restrict__ g,
                                                  float* __restrict__ xmid,
                                                  bf16_t* __restrict__ zb) {
  int row = blockIdx.x;
  int tid = threadIdx.x;
  int64_t base = (int64_t)row * DM + tid * 4;
  float4 v = *(const float4*)(x + base);
#pragma unroll
  for (int p = 0; p < 4; ++p) {
    float4 pv = *(const float4*)(P + (int64_t)p * ROWS * DM + base);
    v.x += pv.x; v.y += pv.y; v.z += pv.z; v.w += pv.w;
  }
  *(float4*)(xmid + base) = v;
  float ss = v.x * v.x + v.y * v.y + v.z * v.z + v.w * v.w;
#pragma unroll
  for (int o = 32; o; o >>= 1) ss += __shfl_xor(ss, o, 64);
  __shared__ float red[4];
  if ((tid & 63) == 0) red[tid >> 6] = ss;
  __syncthreads();
  float tot = red[0] + red[1] + red[2] + red[3];
  float sc = rsqrtf(tot * (1.0f / DM) + 1e-6f);
  const float4 gv = *(const float4*)(g + tid * 4);
  bf16_t* o = zb + base;
  o[0] = (bf16_t)(v.x * sc * gv.x);
  o[1] = (bf16_t)(v.y * sc * gv.y);
  o[2] = (bf16_t)(v.z * sc * gv.z);
  o[3] = (bf16_t)(v.w * sc * gv.w);
}

// out = res + bias + sum_p P[p]   (2048 x 1024)
__global__ __launch_bounds__(256) void reduce_bias(const float* __restrict__ P,
                                                   const float* __restrict__ res,
                                                   const float* __restrict__ bias,
                                                   float* __restrict__ out) {
  int64_t e = ((int64_t)blockIdx.x * 256 + threadIdx.x) * 4;
  int col = (int)(e % DM);
  float4 v = *(const float4*)(res + e);
  const float4 bv = *(const float4*)(bias + col);
  v.x += bv.x; v.y += bv.y; v.z += bv.z; v.w += bv.w;
#pragma unroll
  for (int p = 0; p < 4; ++p) {
    float4 pv = *(const float4*)(P + (int64_t)p * ROWS * DM + e);
    v.x += pv.x; v.y += pv.y; v.z += pv.z; v.w += pv.w;
  }
  *(float4*)(out + e) = v;
}

// swizzled transposed-u LDS accessor: element (ch, t) at
//   Ut[ch*64 + (((t>>3) ^ (ch&7)) << 3) + (t&7)]

// ---------------- Phase A: per-chunk boundary operator -----------------------
__global__ __launch_bounds__(256) void ssm_chunk(const float* __restrict__ ssmp,
                                                 const bf16_t* __restrict__ u,
                                                 float* __restrict__ S,
                                                 float* __restrict__ Etot) {
  __shared__ __align__(16) float cf[64 * 48];
  __shared__ __align__(16) float Lb[64 * 16];
  __shared__ __align__(16) float w[16 * 64];
  __shared__ __align__(16) bf16_t Ut[128 * 64];
  int bgc = blockIdx.x;
  int bg = bgc >> 4, c = bgc & 15;
  int b = bg >> 4, g = bg & 15;
  int t0 = c * 64;
  int tid = threadIdx.x;
  {
    const float4* src = (const float4*)(ssmp + ((int64_t)bg * 1024 + t0) * 48);
    float4* dst = (float4*)cf;
#pragma unroll
    for (int i = 0; i < 3; ++i) dst[i * 256 + tid] = src[i * 256 + tid];
  }
  {
    int lt = tid >> 4;
    int c8 = (tid & 15) * 8;
#pragma unroll
    for (int p = 0; p < 4; ++p) {
      int t = p * 16 + lt;
      bf16x8 v = *(const bf16x8*)(u + ((int64_t)(b * 1024) + t0 + t) * 2048 + g * 128 + c8);
#pragma unroll
      for (int j = 0; j < 8; ++j)
        Ut[(c8 + j) * 64 + (((t >> 3) ^ j) << 3) + (t & 7)] = v[j];
    }
  }
  __syncthreads();
  if (tid < 16) {
    float l = 0.f;
    for (int t = 0; t < 64; ++t) { l += cf[t * 48 + tid]; Lb[t * 16 + tid] = l; }
  }
  __syncthreads();
  {
    int s = tid >> 4, tb = (tid & 15) * 4;
    float lend = Lb[63 * 16 + s];
#pragma unroll
    for (int j = 0; j < 4; ++j) {
      int t = tb + j;
      w[s * 64 + t] = __expf(lend - Lb[t * 16 + s]) * cf[t * 48 + 16 + s];
    }
    if (tid < 16) Etot[(int64_t)bgc * 16 + tid] = __expf(Lb[63 * 16 + tid]);
  }
  __syncthreads();
  {
    int ch = tid & 127;
    bf16x8 ur[8];
#pragma unroll
    for (int j = 0; j < 8; ++j)
      ur[j] = *(const bf16x8*)&Ut[ch * 64 + ((j ^ (ch & 7)) << 3)];
    float* Sp = S + (int64_t)bgc * 2048;
#pragma unroll
    for (int i = 0; i < 8; ++i) {
      int s = 2 * i + (tid >> 7);
      float acc = 0.f;
#pragma unroll
      for (int j = 0; j < 8; ++j) {
        float4 w0 = *(const float4*)&w[s * 64 + j * 8];
        float4 w1 = *(const float4*)&w[s * 64 + j * 8 + 4];
        acc += w0.x * (float)ur[j][0] + w0.y * (float)ur[j][1]
             + w0.z * (float)ur[j][2] + w0.w * (float)ur[j][3]
             + w1.x * (float)ur[j][4] + w1.y * (float)ur[j][5]
             + w1.z * (float)ur[j][6] + w1.w * (float)ur[j][7];
      }
      Sp[s * 128 + ch] = acc;
    }
  }
}

// ---------------- Phase B: sequential combine over 16 chunks ----------------
__global__ __launch_bounds__(256) void ssm_combine(const float* __restrict__ S,
                                                   const float* __restrict__ Etot,
                                                   float* __restrict__ H) {
  int gid = blockIdx.x * 256 + threadIdx.x;
  int bg = gid >> 11;
  int s = (gid >> 7) & 15;
  int ch = gid & 127;
  float h = 0.f;
  for (int c = 0; c < 16; ++c) {
    int bgc = bg * 16 + c;
    int64_t idx = ((int64_t)bgc * 16 + s) * 128 + ch;
    H[idx] = h;
    h = Etot[(int64_t)bgc * 16 + s] * h + S[idx];
  }
}

// ---------------- Phase C: intra-chunk kernel + h_in part + gate ------------
__global__ __launch_bounds__(256) void ssm_out(const float* __restrict__ ssmp,
                                               const bf16_t* __restrict__ u,
                                               const float* __restrict__ H,
                                               const float* __restrict__ xzg,
                                               bf16_t* __restrict__ yout) {
  __shared__ __align__(16) float cf[64 * 48];
  __shared__ __align__(16) float Lb[64 * 16];
  __shared__ __align__(16) float ce[64 * 16];
  __shared__ __align__(16) float Km[64 * 68];
  __shared__ __align__(16) bf16_t Ut[128 * 64];
  int bgc = blockIdx.x;
  int bg = bgc >> 4, c = bgc & 15;
  int b = bg >> 4, g = bg & 15;
  int t0 = c * 64;
  int tid = threadIdx.x;
  {
    const float4* src = (const float4*)(ssmp + ((int64_t)bg * 1024 + t0) * 48);
    float4* dst = (float4*)cf;
#pragma unroll
    for (int i = 0; i < 3; ++i) dst[i * 256 + tid] = src[i * 256 + tid];
  }
  {
    int lt = tid >> 4;
    int c8 = (tid & 15) * 8;
#pragma unroll
    for (int p = 0; p < 4; ++p) {
      int t = p * 16 + lt;
      bf16x8 v = *(const bf16x8*)(u + ((int64_t)(b * 1024) + t0 + t) * 2048 + g * 128 + c8);
#pragma unroll
      for (int j = 0; j < 8; ++j)
        Ut[(c8 + j) * 64 + (((t >> 3) ^ j) << 3) + (t & 7)] = v[j];
    }
  }
  __syncthreads();
  if (tid < 16) {
    float l = 0.f;
    for (int t = 0; t < 64; ++t) { l += cf[t * 48 + tid]; Lb[t * 16 + tid] = l; }
  }
  __syncthreads();
  {
    int s = tid & 15, tq = tid >> 4;
#pragma unroll
    for (int j = 0; j < 4; ++j) {
      int t = tq * 4 + j;
      ce[t * 16 + s] = cf[t * 48 + 32 + s] * __expf(Lb[t * 16 + s]);
    }
  }
  {
    int t = tid >> 2, tp0 = (tid & 3) * 16;
    float4 cv[4], lv[4];
#pragma unroll
    for (int i = 0; i < 4; ++i) {
      cv[i] = *(const float4*)&cf[t * 48 + 32 + i * 4];
      lv[i] = *(const float4*)&Lb[t * 16 + i * 4];
    }
#pragma unroll
    for (int i = 0; i < 16; ++i) {
      int tp = tp0 + i;
      float k = 0.f;
      if (tp <= t) {
#pragma unroll
        for (int q = 0; q < 4; ++q) {
          float4 lpv = *(const float4*)&Lb[tp * 16 + q * 4];
          float4 fbv = *(const float4*)&cf[tp * 48 + 16 + q * 4];
          k += cv[q].x * __expf(lv[q].x - lpv.x) * fbv.x
             + cv[q].y * __expf(lv[q].y - lpv.y) * fbv.y
             + cv[q].z * __expf(lv[q].z - lpv.z) * fbv.z
             + cv[q].w * __expf(lv[q].w - lpv.w) * fbv.w;
        }
      }
      Km[t * 68 + tp] = k;
    }
  }
  __syncthreads();
  {
    int ch = tid & 127, th = tid >> 7;
    bf16x8 ur[8];
#pragma unroll
    for (int j = 0; j < 8; ++j)
      ur[j] = *(const bf16x8*)&Ut[ch * 64 + ((j ^ (ch & 7)) << 3)];
    float hr[16];
    const float* Hp = H + (int64_t)bgc * 2048 + ch;
#pragma unroll
    for (int s = 0; s < 16; ++s) hr[s] = Hp[s * 128];
    int col = g * 128 + ch;
    const float* gp = xzg + ((int64_t)(b * 1024) + t0) * 4096 + 2048 + col;
    bf16_t* yp = yout + ((int64_t)(b * 1024) + t0) * 2048 + col;
    for (int ti = 0; ti < 32; ++ti) {
      int t = th * 32 + ti;
      float acc = 0.f;
#pragma unroll
      for (int q = 0; q < 16; ++q) {
        float4 kv = *(const float4*)&Km[t * 68 + q * 4];
        int j = q >> 1;
        int e = (q & 1) * 4;
        acc += kv.x * (float)ur[j][e] + kv.y * (float)ur[j][e + 1]
             + kv.z * (float)ur[j][e + 2] + kv.w * (float)ur[j][e + 3];
      }
#pragma unroll
      for (int q = 0; q < 4; ++q) {
        float4 cev = *(const float4*)&ce[t * 16 + q * 4];
        acc += cev.x * hr[q * 4] + cev.y * hr[q * 4 + 1]
             + cev.z * hr[q * 4 + 2] + cev.w * hr[q * 4 + 3];
      }
      float gv = gp[(int64_t)t * 4096];
      float sg = gv / (1.f + __expf(-gv));
      yp[(int64_t)t * 2048] = (bf16_t)(acc * sg);
    }
  }
}

// ---------------- bf16 GEMM, B given as (N,K) row-major ("B^T"), fp32 out ------
// grid: (N/128, M/128, SK). Each z computes K-slice [z*Kps, (z+1)*Kps) into
// C + z*2048*N. EPI epilogue (bias/res) only meaningful when SK==1.
template <int EPI>  // bit0: bias, bit1: residual
__global__ __launch_bounds__(256) void gemm_bt(const bf16_t* __restrict__ A,
                                               const bf16_t* __restrict__ Bw,
                                               float* __restrict__ C,
                                               const float* __restrict__ bias,
                                               const float* __restrict__ res,
                                               int N, int Kps) {
  __shared__ bf16_t As[128 * 64];
  __shared__ bf16_t Bs[128 * 64];
  const int tid = threadIdx.x;
  const int wave = tid >> 6;
  const int lane = tid & 63;
  const int64_t m0 = (int64_t)blockIdx.y * 128;
  const int64_t n0 = (int64_t)blockIdx.x * 128;
  const int K = Kps * gridDim.z;
  const int kbeg = blockIdx.z * Kps;
  float* Cz = C + (int64_t)blockIdx.z * ROWS * N;
  const int wm = (wave >> 1) * 64;
  const int wn = (wave & 1) * 64;
  f32x4 acc[4][4] = {};

  const int er = tid >> 3;        // row within 32-row stripe
  const int ec = (tid * 8) & 63;  // col (k) within tile

  for (int k0 = kbeg; k0 < kbeg + Kps; k0 += 64) {
#pragma unroll
    for (int i = 0; i < 4; ++i) {
      const bf16_t* ga = A + (m0 + er + i * 32) * K + k0 + ec;
      __builtin_amdgcn_global_load_lds((gvoid_t*)ga,
                                       (lvoid_t*)&As[(i * 256 + wave * 64) * 8],
                                       16, 0, 0);
    }
#pragma unroll
    for (int i = 0; i < 4; ++i) {
      const bf16_t* gb = Bw + (n0 + er + i * 32) * K + k0 + ec;
      __builtin_amdgcn_global_load_lds((gvoid_t*)gb,
                                       (lvoid_t*)&Bs[(i * 256 + wave * 64) * 8],
                                       16, 0, 0);
    }
    __syncthreads();
    const int fr = lane & 15;
    const int kq = (lane >> 4) * 8;
#pragma unroll
    for (int kk = 0; kk < 2; ++kk) {
      bf16x8 af[4], bf[4];
#pragma unroll
      for (int mi = 0; mi < 4; ++mi)
        af[mi] = *reinterpret_cast<const bf16x8*>(&As[(wm + mi * 16 + fr) * 64 + kk * 32 + kq]);
#pragma unroll
      for (int ni = 0; ni < 4; ++ni)
        bf[ni] = *reinterpret_cast<const bf16x8*>(&Bs[(wn + ni * 16 + fr) * 64 + kk * 32 + kq]);
#pragma unroll
      for (int mi = 0; mi < 4; ++mi)
#pragma unroll
        for (int ni = 0; ni < 4; ++ni)
          acc[mi][ni] = __builtin_amdgcn_mfma_f32_16x16x32_bf16(af[mi], bf[ni], acc[mi][ni], 0, 0, 0);
    }
    __syncthreads();
  }
  const int crow = (lane >> 4) * 4;
  const int ccol = lane & 15;
#pragma unroll
  for (int mi = 0; mi < 4; ++mi) {
#pragma unroll
    for (int ni = 0; ni < 4; ++ni) {
#pragma unroll
      for (int j = 0; j < 4; ++j) {
        int64_t r = m0 + wm + mi * 16 + crow + j;
        int64_t cn = n0 + wn + ni * 16 + ccol;
        float v = acc[mi][ni][j];
        if (EPI & 1) v += bias[cn];
        if (EPI & 2) v += res[r * N + cn];
        Cz[r * N + cn] = v;
      }
    }
  }
}

extern "C" void kernel_launch(void* const* d_in, const int* in_sizes, int n_in,
                              void* d_out, int out_size, void* d_ws, size_t ws_size,
                              hipStream_t stream) {
  const float* x       = (const float*)d_in[0];
  const float* A_log   = (const float*)d_in[1];
  const float* g1      = (const float*)d_in[2];
  const float* g2      = (const float*)d_in[3];
  const float* W_in    = (const float*)d_in[4];
  const float* W_param = (const float*)d_in[5];
  const float* W_out   = (const float*)d_in[6];
  const float* W_ffn1  = (const float*)d_in[7];
  const float* b_ffn1  = (const float*)d_in[8];
  const float* W_ffn2  = (const float*)d_in[9];
  const float* b_ffn2  = (const float*)d_in[10];
  float* out = (float*)d_out;

  char* ws = (char*)d_ws;
  size_t off = 0;
  auto alloc = [&](size_t bytes) {
    char* p = ws + off;
    off += (bytes + 255) & ~(size_t)255;
    return p;
  };
  bf16_t* wb_in  = (bf16_t*)alloc(4096ull * 1024 * 2);
  bf16_t* wb_par = (bf16_t*)alloc((size_t)PPAD * 2048 * 2);
  bf16_t* wb_out = (bf16_t*)alloc(1024ull * 2048 * 2);
  bf16_t* wb_f1  = (bf16_t*)alloc(4096ull * 1024 * 2);
  bf16_t* wb_f2  = (bf16_t*)alloc(1024ull * 4096 * 2);
  bf16_t* zbuf   = (bf16_t*)alloc(2048ull * 1024 * 2);   // z, later h2
  float*  xzg    = (float*)alloc(2048ull * 4096 * 4);    // xz|gate, later ffn1 raw
  float*  params = (float*)alloc(2048ull * PPAD * 4);    // fallback path only
  float*  ssmp   = (float*)alloc(32ull * 1024 * 48 * 4);
  float*  xmid   = (float*)alloc(2048ull * 1024 * 4);
  char*   regA   = alloc(2048ull * 4096 * 2);            // 16MB union
  bf16_t* xz_act = (bf16_t*)regA;
  bf16_t* y_b16  = (bf16_t*)(regA + 2048ull * 2048 * 2);
  bf16_t* f_act  = (bf16_t*)regA;
  float* Sbuf = params;
  float* Etot = params + 32ull * 16 * 16 * 128;
  float* Hbuf = xmid;
  // split-K partial region (4 x 2048 x 1024 fp32 = 33.6 MB), guarded by ws_size
  float* psum = (float*)alloc(4ull * ROWS * 1024 * 4);
  const bool sk = (off <= ws_size);

  dim3 b256(256);
  cvt_pad<<<4096, b256, 0, stream>>>(W_in, wb_in, 4096, 1024);
  cvt_pad<<<1280, b256, 0, stream>>>(W_param, wb_par, 528, 2048);
  cvt_pad<<<2048, b256, 0, stream>>>(W_out, wb_out, 1024, 2048);
  cvt_pad<<<4096, b256, 0, stream>>>(W_ffn1, wb_f1, 4096, 1024);
  cvt_pad<<<4096, b256, 0, stream>>>(W_ffn2, wb_f2, 1024, 4096);
  rmsnorm_k<<<2048, b256, 0, stream>>>(x, g1, zbuf);
  gemm_bt<0><<<dim3(32, 16), b256, 0, stream>>>(zbuf, wb_in, xzg, nullptr, nullptr, 4096, 1024);
  silu_cvt<<<4096, b256, 0, stream>>>(xzg, xz_act, 4096, 2048);

  if (sk) {  // params = xz_act @ W_param^T, split-K=4 (320 blocks)
    gemm_bt<0><<<dim3(PPAD / 128, 16, 4), b256, 0, stream>>>(xz_act, wb_par, psum, nullptr, nullptr, PPAD, 512);
    ssm_prep<<<128, b256, 0, stream>>>(psum, A_log, ssmp, 4);
  } else {
    gemm_bt<0><<<dim3(PPAD / 128, 16), b256, 0, stream>>>(xz_act, wb_par, params, nullptr, nullptr, PPAD, 2048);
    ssm_prep<<<128, b256, 0, stream>>>(params, A_log, ssmp, 1);
  }
  // NOTE: Sbuf/Etot overlay params — only used below, after ssm_prep consumed it
  ssm_chunk<<<512, b256, 0, stream>>>(ssmp, xz_act, Sbuf, Etot);
  ssm_combine<<<256, b256, 0, stream>>>(Sbuf, Etot, Hbuf);
  ssm_out<<<512, b256, 0, stream>>>(ssmp, xz_act, Hbuf, xzg, y_b16);

  if (sk) {  // xmid = x + y @ W_out^T (SK=4, 512 blocks), fused reduce+rmsnorm
    gemm_bt<0><<<dim3(8, 16, 4), b256, 0, stream>>>(y_b16, wb_out, psum, nullptr, nullptr, 1024, 512);
    reduce_rms<<<2048, b256, 0, stream>>>(psum, x, g2, xmid, zbuf);
  } else {
    gemm_bt<2><<<dim3(8, 16), b256, 0, stream>>>(y_b16, wb_out, xmid, nullptr, x, 1024, 2048);
    rmsnorm_k<<<2048, b256, 0, stream>>>(xmid, g2, zbuf);
  }
  gemm_bt<1><<<dim3(32, 16), b256, 0, stream>>>(zbuf, wb_f1, xzg, b_ffn1, nullptr, 4096, 1024);
  silu_cvt<<<8192, b256, 0, stream>>>(xzg, f_act, 4096, 4096);
  if (sk) {  // out = xmid + b_ffn2 + f_act @ W_ffn2^T (SK=4, 512 blocks)
    gemm_bt<0><<<dim3(8, 16, 4), b256, 0, stream>>>(f_act, wb_f2, psum, nullptr, nullptr, 1024, 1024);
    reduce_bias<<<2048, b256, 0, stream>>>(psum, xmid, b_ffn2, out);
  } else {
    gemm_bt<3><<<dim3(8, 16), b256, 0, stream>>>(f_act, wb_f2, out, b_ffn2, xmid, 1024, 4096);
  }
}

// Round 4
// 227.886 us; speedup vs baseline: 4.4370x; 1.1735x over previous
//
#include <hip/hip_runtime.h>
#include <hip/hip_bf16.h>
#include <stdint.h>

// MambaBlock: B=2, T=1024, D_MODEL=1024, D_INNER=2048, GROUPS=16, D_STATE=16
#define ROWS 2048      // B*T
#define DM   1024
#define DI   2048
#define PPAD 640       // 528 param rows padded to 5*128

typedef __bf16 bf16_t;
typedef __attribute__((ext_vector_type(8))) __bf16 bf16x8;
typedef __attribute__((ext_vector_type(4))) __bf16 bf16x4;
typedef __attribute__((ext_vector_type(4))) float f32x4;
typedef __attribute__((address_space(1))) void gvoid_t;
typedef __attribute__((address_space(3))) void lvoid_t;

// ---------------- weight fp32 -> bf16 (with zero row padding) ----------------
__global__ __launch_bounds__(256) void cvt_pad(const float* __restrict__ src,
                                               bf16_t* __restrict__ dst,
                                               int nsrc, int K) {
  int gid = blockIdx.x * 256 + threadIdx.x;
  int64_t e = (int64_t)gid * 4;
  int row = (int)(e / K);
  int col = (int)(e % K);
  float4 v = make_float4(0.f, 0.f, 0.f, 0.f);
  if (row < nsrc) v = *(const float4*)(src + (int64_t)row * K + col);
  bf16_t* o = dst + e;
  o[0] = (bf16_t)v.x; o[1] = (bf16_t)v.y; o[2] = (bf16_t)v.z; o[3] = (bf16_t)v.w;
}

// ---------------- rmsnorm (D=1024), fp32 in -> bf16 out ----------------
__global__ __launch_bounds__(256) void rmsnorm_k(const float* __restrict__ x,
                                                 const float* __restrict__ g,
                                                 bf16_t* __restrict__ out) {
  int row = blockIdx.x;
  int tid = threadIdx.x;
  const float4 v = *(const float4*)(x + (int64_t)row * DM + tid * 4);
  float ss = v.x * v.x + v.y * v.y + v.z * v.z + v.w * v.w;
#pragma unroll
  for (int o = 32; o; o >>= 1) ss += __shfl_xor(ss, o, 64);
  __shared__ float red[4];
  if ((tid & 63) == 0) red[tid >> 6] = ss;
  __syncthreads();
  float tot = red[0] + red[1] + red[2] + red[3];
  float sc = rsqrtf(tot * (1.0f / DM) + 1e-6f);
  const float4 gv = *(const float4*)(g + tid * 4);
  bf16_t* o = out + (int64_t)row * DM + tid * 4;
  o[0] = (bf16_t)(v.x * sc * gv.x);
  o[1] = (bf16_t)(v.y * sc * gv.y);
  o[2] = (bf16_t)(v.z * sc * gv.z);
  o[3] = (bf16_t)(v.w * sc * gv.w);
}

// ---------------- silu + fp32 -> bf16 (fallback path only) ----------------
__global__ __launch_bounds__(256) void silu_cvt(const float* __restrict__ in,
                                                bf16_t* __restrict__ out,
                                                int in_stride, int ncols) {
  int64_t e = ((int64_t)blockIdx.x * 256 + threadIdx.x) * 4;
  int row = (int)(e / ncols);
  int col = (int)(e % ncols);
  const float4 v = *(const float4*)(in + (int64_t)row * in_stride + col);
  bf16_t* o = out + e;
  o[0] = (bf16_t)(v.x / (1.f + expf(-v.x)));
  o[1] = (bf16_t)(v.y / (1.f + expf(-v.y)));
  o[2] = (bf16_t)(v.z / (1.f + expf(-v.z)));
  o[3] = (bf16_t)(v.w / (1.f + expf(-v.w)));
}

// ---------------- SSM coefficient prep (sums nparts split-K partials) --------
// layout ssmp[bg][t][48] = { dA_clipped[16], frac*b[16], c[16] }
__global__ __launch_bounds__(256) void ssm_prep(const float* __restrict__ params,
                                                const float* __restrict__ A_log,
                                                float* __restrict__ ssmp, int nparts) {
  int gid = blockIdx.x * 256 + threadIdx.x;  // 32 * 1024
  int bg = gid >> 10, t = gid & 1023;
  int b = bg >> 4, g = bg & 15;
  float acc[33];
#pragma unroll
  for (int i = 0; i < 33; ++i) acc[i] = 0.f;
  for (int p = 0; p < nparts; ++p) {
    const float* pr = params + (int64_t)p * ROWS * PPAD + (int64_t)(b * 1024 + t) * PPAD + g * 33;
#pragma unroll
    for (int i = 0; i < 33; ++i) acc[i] += pr[i];
  }
  float raw = acc[0];
  float delta = raw > 0.f ? raw + log1pf(expf(-raw)) : log1pf(expf(raw));
  float* o = ssmp + (int64_t)gid * 48;
#pragma unroll
  for (int s = 0; s < 16; ++s) {
    float A = -expf(A_log[s]);
    float dA = delta * A;
    dA = fminf(10.f, fmaxf(-10.f, dA));
    float e = expf(dA);
    float frac = (fabsf(dA) < 1e-4f) ? delta : (e - 1.f) / (A + 1e-12f);
    o[s] = dA;
    o[16 + s] = frac * acc[1 + s];
    o[32 + s] = acc[17 + s];
  }
}

// ---------------- split-K reduce + residual + rmsnorm (fused) ---------------
__global__ __launch_bounds__(256) void reduce_rms(const float* __restrict__ P,
                                                  const float* __restrict__ x,
                                                  const float* __restrict__ g,
                                                  float* __restrict__ xmid,
                                                  bf16_t* __restrict__ zb) {
  int row = blockIdx.x;
  int tid = threadIdx.x;
  int64_t base = (int64_t)row * DM + tid * 4;
  float4 v = *(const float4*)(x + base);
#pragma unroll
  for (int p = 0; p < 4; ++p) {
    float4 pv = *(const float4*)(P + (int64_t)p * ROWS * DM + base);
    v.x += pv.x; v.y += pv.y; v.z += pv.z; v.w += pv.w;
  }
  *(float4*)(xmid + base) = v;
  float ss = v.x * v.x + v.y * v.y + v.z * v.z + v.w * v.w;
#pragma unroll
  for (int o = 32; o; o >>= 1) ss += __shfl_xor(ss, o, 64);
  __shared__ float red[4];
  if ((tid & 63) == 0) red[tid >> 6] = ss;
  __syncthreads();
  float tot = red[0] + red[1] + red[2] + red[3];
  float sc = rsqrtf(tot * (1.0f / DM) + 1e-6f);
  const float4 gv = *(const float4*)(g + tid * 4);
  bf16_t* o = zb + base;
  o[0] = (bf16_t)(v.x * sc * gv.x);
  o[1] = (bf16_t)(v.y * sc * gv.y);
  o[2] = (bf16_t)(v.z * sc * gv.z);
  o[3] = (bf16_t)(v.w * sc * gv.w);
}

// out = res + bias + sum_p P[p]   (2048 x 1024)
__global__ __launch_bounds__(256) void reduce_bias(const float* __restrict__ P,
                                                   const float* __restrict__ res,
                                                   const float* __restrict__ bias,
                                                   float* __restrict__ out) {
  int64_t e = ((int64_t)blockIdx.x * 256 + threadIdx.x) * 4;
  int col = (int)(e % DM);
  float4 v = *(const float4*)(res + e);
  const float4 bv = *(const float4*)(bias + col);
  v.x += bv.x; v.y += bv.y; v.z += bv.z; v.w += bv.w;
#pragma unroll
  for (int p = 0; p < 4; ++p) {
    float4 pv = *(const float4*)(P + (int64_t)p * ROWS * DM + e);
    v.x += pv.x; v.y += pv.y; v.z += pv.z; v.w += pv.w;
  }
  *(float4*)(out + e) = v;
}

// Ut layout: element (ch, t) at byte ch*128 + ((t*2) ^ ((ch&7)<<4))
// == Ut[ch*64 + (((t>>3)^(ch&7))<<3) + (t&7)]; B-fragment reads are 2-way (free).

// ---------------- Phase A: per-chunk boundary operator (MFMA) ---------------
__global__ __launch_bounds__(256) void ssm_chunk(const float* __restrict__ ssmp,
                                                 const bf16_t* __restrict__ u,
                                                 float* __restrict__ S,
                                                 float* __restrict__ Etot) {
  __shared__ __align__(16) float cf[64 * 48];
  __shared__ __align__(16) float Lb[64 * 16];
  __shared__ __align__(16) bf16_t wl[16 * 64];
  __shared__ __align__(16) bf16_t Ut[128 * 64];
  int bgc = blockIdx.x;
  int bg = bgc >> 4, c = bgc & 15;
  int b = bg >> 4, g = bg & 15;
  int t0 = c * 64;
  int tid = threadIdx.x;
  {
    const float4* src = (const float4*)(ssmp + ((int64_t)bg * 1024 + t0) * 48);
    float4* dst = (float4*)cf;
#pragma unroll
    for (int i = 0; i < 3; ++i) dst[i * 256 + tid] = src[i * 256 + tid];
  }
  {
    int lt = tid >> 4;
    int c8 = (tid & 15) * 8;
#pragma unroll
    for (int p = 0; p < 4; ++p) {
      int t = p * 16 + lt;
      bf16x8 v = *(const bf16x8*)(u + ((int64_t)(b * 1024) + t0 + t) * 2048 + g * 128 + c8);
#pragma unroll
      for (int j = 0; j < 8; ++j)
        Ut[(c8 + j) * 64 + (((t >> 3) ^ j) << 3) + (t & 7)] = v[j];
    }
  }
  __syncthreads();
  if (tid < 16) {
    float l = 0.f;
    for (int t = 0; t < 64; ++t) { l += cf[t * 48 + tid]; Lb[t * 16 + tid] = l; }
  }
  __syncthreads();
  // w[s][t] = exp(Lend - L[t][s]) * fb[t][s], bf16, swizzled
  {
    int s = tid >> 4, tb4 = (tid & 15) * 4;
    float lend = Lb[63 * 16 + s];
    bf16x4 wv;
#pragma unroll
    for (int j = 0; j < 4; ++j) {
      int t = tb4 + j;
      wv[j] = (bf16_t)(__expf(lend - Lb[t * 16 + s]) * cf[t * 48 + 16 + s]);
    }
    unsigned byo = (unsigned)(s * 128 + tb4 * 2) ^ ((unsigned)(s & 7) << 4);
    *(bf16x4*)((char*)wl + byo) = wv;
    if (tid < 16) Etot[(int64_t)bgc * 16 + tid] = __expf(Lb[63 * 16 + tid]);
  }
  __syncthreads();
  // S(16x128) = w(16x64) @ Ut^T
  {
    int lane = tid & 63, wave = tid >> 6;
    int fr = lane & 15, kq = lane >> 4;
    f32x4 acc2[2] = {};
#pragma unroll
    for (int kk = 0; kk < 2; ++kk) {
      int kb = kk * 4 + kq;
      bf16x8 af = *(const bf16x8*)((const char*)wl +
                    ((unsigned)(fr * 128 + kb * 16) ^ ((unsigned)(fr & 7) << 4)));
#pragma unroll
      for (int q = 0; q < 2; ++q) {
        int ch = (wave * 2 + q) * 16 + fr;
        bf16x8 bfr = *(const bf16x8*)((const char*)Ut +
                       ((unsigned)(ch * 128 + kb * 16) ^ ((unsigned)(ch & 7) << 4)));
        acc2[q] = __builtin_amdgcn_mfma_f32_16x16x32_bf16(af, bfr, acc2[q], 0, 0, 0);
      }
    }
    float* Sp = S + (int64_t)bgc * 2048;
#pragma unroll
    for (int q = 0; q < 2; ++q) {
      int ch = (wave * 2 + q) * 16 + fr;
#pragma unroll
      for (int j = 0; j < 4; ++j) Sp[(kq * 4 + j) * 128 + ch] = acc2[q][j];
    }
  }
}

// ---------------- Phase B: sequential combine over 16 chunks ----------------
__global__ __launch_bounds__(256) void ssm_combine(const float* __restrict__ S,
                                                   const float* __restrict__ Etot,
                                                   float* __restrict__ H) {
  int gid = blockIdx.x * 256 + threadIdx.x;
  int bg = gid >> 11;
  int s = (gid >> 7) & 15;
  int ch = gid & 127;
  float h = 0.f;
  for (int c = 0; c < 16; ++c) {
    int bgc = bg * 16 + c;
    int64_t idx = ((int64_t)bgc * 16 + s) * 128 + ch;
    H[idx] = h;
    h = Etot[(int64_t)bgc * 16 + s] * h + S[idx];
  }
}

// ---------------- Phase C: y = tril(K)@U + ce@H, fused gate (MFMA) ----------
__global__ __launch_bounds__(256) void ssm_out(const float* __restrict__ ssmp,
                                               const bf16_t* __restrict__ u,
                                               const float* __restrict__ H,
                                               const float* __restrict__ gate, int gstride,
                                               bf16_t* __restrict__ yout) {
  __shared__ __align__(16) float cf[64 * 48];
  __shared__ __align__(16) float Lb[64 * 16];
  __shared__ __align__(16) bf16_t Km[64 * 64];
  __shared__ __align__(16) bf16_t Ut[128 * 64];
  __shared__ __align__(16) bf16_t Hb[128 * 32];
  int bgc = blockIdx.x;
  int bg = bgc >> 4, c = bgc & 15;
  int b = bg >> 4, g = bg & 15;
  int t0 = c * 64;
  int tid = threadIdx.x;
  int lane = tid & 63, wave = tid >> 6;
  {
    const float4* src = (const float4*)(ssmp + ((int64_t)bg * 1024 + t0) * 48);
    float4* dst = (float4*)cf;
#pragma unroll
    for (int i = 0; i < 3; ++i) dst[i * 256 + tid] = src[i * 256 + tid];
  }
  {
    int lt = tid >> 4;
    int c8 = (tid & 15) * 8;
#pragma unroll
    for (int p = 0; p < 4; ++p) {
      int t = p * 16 + lt;
      bf16x8 v = *(const bf16x8*)(u + ((int64_t)(b * 1024) + t0 + t) * 2048 + g * 128 + c8);
#pragma unroll
      for (int j = 0; j < 8; ++j)
        Ut[(c8 + j) * 64 + (((t >> 3) ^ j) << 3) + (t & 7)] = v[j];
    }
  }
  // H -> Hb[ch][s] bf16, zero-padded s=16..31
  {
    int ch = tid >> 1, h8 = (tid & 1) * 8;
    const float* Hp = H + (int64_t)bgc * 2048 + ch;
#pragma unroll
    for (int j = 0; j < 8; ++j) {
      Hb[ch * 32 + h8 + j] = (bf16_t)Hp[(h8 + j) * 128];
      Hb[ch * 32 + 16 + h8 + j] = (bf16_t)0.f;
    }
  }
  __syncthreads();
  if (tid < 16) {
    float l = 0.f;
    for (int t = 0; t < 64; ++t) { l += cf[t * 48 + tid]; Lb[t * 16 + tid] = l; }
  }
  __syncthreads();
  // K[t][t'] = sum_s c[t,s] exp(L[t,s]-L[t',s]) fb[t',s]  (t>=t', else 0) -> bf16
  {
    int t = tid >> 2, tp0 = (tid & 3) * 16;
    float4 cv[4], lv[4];
#pragma unroll
    for (int i = 0; i < 4; ++i) {
      cv[i] = *(const float4*)&cf[t * 48 + 32 + i * 4];
      lv[i] = *(const float4*)&Lb[t * 16 + i * 4];
    }
    float kv[16];
#pragma unroll
    for (int i = 0; i < 16; ++i) {
      int tp = tp0 + i;
      float k = 0.f;
      if (tp <= t) {
#pragma unroll
        for (int q = 0; q < 4; ++q) {
          float4 lpv = *(const float4*)&Lb[tp * 16 + q * 4];
          float4 fbv = *(const float4*)&cf[tp * 48 + 16 + q * 4];
          k += cv[q].x * __expf(lv[q].x - lpv.x) * fbv.x
             + cv[q].y * __expf(lv[q].y - lpv.y) * fbv.y
             + cv[q].z * __expf(lv[q].z - lpv.z) * fbv.z
             + cv[q].w * __expf(lv[q].w - lpv.w) * fbv.w;
        }
      }
      kv[i] = k;
    }
    bf16x8 lo, hi;
#pragma unroll
    for (int i = 0; i < 8; ++i) { lo[i] = (bf16_t)kv[i]; hi[i] = (bf16_t)kv[8 + i]; }
    unsigned b0 = (unsigned)(t * 128 + tp0 * 2) ^ ((unsigned)(t & 7) << 4);
    unsigned b1 = (unsigned)(t * 128 + tp0 * 2 + 16) ^ ((unsigned)(t & 7) << 4);
    *(bf16x8*)((char*)Km + b0) = lo;
    *(bf16x8*)((char*)Km + b1) = hi;
  }
  __syncthreads();
  int fr = lane & 15, kq = lane >> 4;
  int trow = (wave >> 1) * 32, wc = (wave & 1) * 64;
  f32x4 acc[2][4] = {};
#pragma unroll
  for (int kk = 0; kk < 2; ++kk) {
    int kb = kk * 4 + kq;
    bf16x8 af[2];
#pragma unroll
    for (int mi = 0; mi < 2; ++mi) {
      int row = trow + mi * 16 + fr;
      af[mi] = *(const bf16x8*)((const char*)Km +
                 ((unsigned)(row * 128 + kb * 16) ^ ((unsigned)(row & 7) << 4)));
    }
#pragma unroll
    for (int ni = 0; ni < 4; ++ni) {
      int ch = wc + ni * 16 + fr;
      bf16x8 bfr = *(const bf16x8*)((const char*)Ut +
                     ((unsigned)(ch * 128 + kb * 16) ^ ((unsigned)(ch & 7) << 4)));
#pragma unroll
      for (int mi = 0; mi < 2; ++mi)
        acc[mi][ni] = __builtin_amdgcn_mfma_f32_16x16x32_bf16(af[mi], bfr, acc[mi][ni], 0, 0, 0);
    }
  }
  // + ce(64x16) @ Hb^T : one K=32 MFMA, A-frag in registers (zero for k>=16)
  {
    int s0 = kq * 8;
    bf16x8 cef[2];
    if (s0 < 16) {
#pragma unroll
      for (int mi = 0; mi < 2; ++mi) {
        int t = trow + mi * 16 + fr;
#pragma unroll
        for (int j = 0; j < 8; ++j)
          cef[mi][j] = (bf16_t)(cf[t * 48 + 32 + s0 + j] * __expf(Lb[t * 16 + s0 + j]));
      }
    } else {
#pragma unroll
      for (int mi = 0; mi < 2; ++mi)
#pragma unroll
        for (int j = 0; j < 8; ++j) cef[mi][j] = (bf16_t)0.f;
    }
#pragma unroll
    for (int ni = 0; ni < 4; ++ni) {
      int ch = wc + ni * 16 + fr;
      bf16x8 bhf = *(const bf16x8*)((const char*)Hb + ch * 64 + s0 * 2);
#pragma unroll
      for (int mi = 0; mi < 2; ++mi)
        acc[mi][ni] = __builtin_amdgcn_mfma_f32_16x16x32_bf16(cef[mi], bhf, acc[mi][ni], 0, 0, 0);
    }
  }
  // epilogue: y *= silu(gate), store bf16
  {
    int64_t rowbase = (int64_t)b * 1024 + t0;
    int colbase = g * 128;
#pragma unroll
    for (int mi = 0; mi < 2; ++mi) {
#pragma unroll
      for (int ni = 0; ni < 4; ++ni) {
        int col = colbase + wc + ni * 16 + fr;
#pragma unroll
        for (int j = 0; j < 4; ++j) {
          int t = trow + mi * 16 + kq * 4 + j;
          float gv = gate[(rowbase + t) * gstride + col];
          float sg = gv / (1.f + __expf(-gv));
          yout[(rowbase + t) * 2048 + col] = (bf16_t)(acc[mi][ni][j] * sg);
        }
      }
    }
  }
}

// ---------------- bf16 GEMM, B given as (N,K) row-major ("B^T"), fp32 out ------
// grid: (N/128, M/128, SK). EPI: bit0 bias, bit1 residual,
// bit2 split-silu (cn<2048 -> obf bf16 silu; else ogate fp32), bit3 bias+silu->obf bf16
template <int EPI>
__global__ __launch_bounds__(256) void gemm_bt(const bf16_t* __restrict__ A,
                                               const bf16_t* __restrict__ Bw,
                                               float* __restrict__ C,
                                               const float* __restrict__ bias,
                                               const float* __restrict__ res,
                                               bf16_t* __restrict__ obf,
                                               float* __restrict__ ogate,
                                               int N, int Kps) {
  __shared__ bf16_t As[128 * 64];
  __shared__ bf16_t Bs[128 * 64];
  const int tid = threadIdx.x;
  const int wave = tid >> 6;
  const int lane = tid & 63;
  const int64_t m0 = (int64_t)blockIdx.y * 128;
  const int64_t n0 = (int64_t)blockIdx.x * 128;
  const int K = Kps * gridDim.z;
  const int kbeg = blockIdx.z * Kps;
  float* Cz = C + (int64_t)blockIdx.z * ROWS * N;
  const int wm = (wave >> 1) * 64;
  const int wn = (wave & 1) * 64;
  f32x4 acc[4][4] = {};

  const int er = tid >> 3;
  const int ec = (tid * 8) & 63;

  for (int k0 = kbeg; k0 < kbeg + Kps; k0 += 64) {
#pragma unroll
    for (int i = 0; i < 4; ++i) {
      const bf16_t* ga = A + (m0 + er + i * 32) * K + k0 + ec;
      __builtin_amdgcn_global_load_lds((gvoid_t*)ga,
                                       (lvoid_t*)&As[(i * 256 + wave * 64) * 8],
                                       16, 0, 0);
    }
#pragma unroll
    for (int i = 0; i < 4; ++i) {
      const bf16_t* gb = Bw + (n0 + er + i * 32) * K + k0 + ec;
      __builtin_amdgcn_global_load_lds((gvoid_t*)gb,
                                       (lvoid_t*)&Bs[(i * 256 + wave * 64) * 8],
                                       16, 0, 0);
    }
    __syncthreads();
    const int fr = lane & 15;
    const int kq = (lane >> 4) * 8;
#pragma unroll
    for (int kk = 0; kk < 2; ++kk) {
      bf16x8 af[4], bf[4];
#pragma unroll
      for (int mi = 0; mi < 4; ++mi)
        af[mi] = *reinterpret_cast<const bf16x8*>(&As[(wm + mi * 16 + fr) * 64 + kk * 32 + kq]);
#pragma unroll
      for (int ni = 0; ni < 4; ++ni)
        bf[ni] = *reinterpret_cast<const bf16x8*>(&Bs[(wn + ni * 16 + fr) * 64 + kk * 32 + kq]);
#pragma unroll
      for (int mi = 0; mi < 4; ++mi)
#pragma unroll
        for (int ni = 0; ni < 4; ++ni)
          acc[mi][ni] = __builtin_amdgcn_mfma_f32_16x16x32_bf16(af[mi], bf[ni], acc[mi][ni], 0, 0, 0);
    }
    __syncthreads();
  }
  const int crow = (lane >> 4) * 4;
  const int ccol = lane & 15;
#pragma unroll
  for (int mi = 0; mi < 4; ++mi) {
#pragma unroll
    for (int ni = 0; ni < 4; ++ni) {
#pragma unroll
      for (int j = 0; j < 4; ++j) {
        int64_t r = m0 + wm + mi * 16 + crow + j;
        int64_t cn = n0 + wn + ni * 16 + ccol;
        float v = acc[mi][ni][j];
        if (EPI & 1) v += bias[cn];
        if (EPI & 2) v += res[r * N + cn];
        if (EPI & 4) {
          if (cn < 2048) obf[r * 2048 + cn] = (bf16_t)(v / (1.f + __expf(-v)));
          else ogate[r * 2048 + cn - 2048] = v;
        } else if (EPI & 8) {
          obf[r * N + cn] = (bf16_t)(v / (1.f + __expf(-v)));
        } else {
          Cz[r * N + cn] = v;
        }
      }
    }
  }
}

extern "C" void kernel_launch(void* const* d_in, const int* in_sizes, int n_in,
                              void* d_out, int out_size, void* d_ws, size_t ws_size,
                              hipStream_t stream) {
  const float* x       = (const float*)d_in[0];
  const float* A_log   = (const float*)d_in[1];
  const float* g1      = (const float*)d_in[2];
  const float* g2      = (const float*)d_in[3];
  const float* W_in    = (const float*)d_in[4];
  const float* W_param = (const float*)d_in[5];
  const float* W_out   = (const float*)d_in[6];
  const float* W_ffn1  = (const float*)d_in[7];
  const float* b_ffn1  = (const float*)d_in[8];
  const float* W_ffn2  = (const float*)d_in[9];
  const float* b_ffn2  = (const float*)d_in[10];
  float* out = (float*)d_out;

  char* ws = (char*)d_ws;
  size_t off = 0;
  auto alloc = [&](size_t bytes) {
    char* p = ws + off;
    off += (bytes + 255) & ~(size_t)255;
    return p;
  };
  bf16_t* wb_in  = (bf16_t*)alloc(4096ull * 1024 * 2);
  bf16_t* wb_par = (bf16_t*)alloc((size_t)PPAD * 2048 * 2);
  bf16_t* wb_out = (bf16_t*)alloc(1024ull * 2048 * 2);
  bf16_t* wb_f1  = (bf16_t*)alloc(4096ull * 1024 * 2);
  bf16_t* wb_f2  = (bf16_t*)alloc(1024ull * 4096 * 2);
  bf16_t* zbuf   = (bf16_t*)alloc(2048ull * 1024 * 2);   // z, later h2
  float*  xzg    = (float*)alloc(2048ull * 4096 * 4);    // gate buf (sk) / xz|gate (fallback)
  float*  params = (float*)alloc(2048ull * PPAD * 4);    // fallback only; S/Etot overlay
  float*  ssmp   = (float*)alloc(32ull * 1024 * 48 * 4);
  float*  xmid   = (float*)alloc(2048ull * 1024 * 4);
  char*   regA   = alloc(2048ull * 4096 * 2);            // 16MB union
  bf16_t* xz_act = (bf16_t*)regA;
  bf16_t* y_b16  = (bf16_t*)(regA + 2048ull * 2048 * 2);
  bf16_t* f_act  = (bf16_t*)regA;
  float* gbuf = xzg;                                     // [2048][2048] fp32 (sk path)
  float* Sbuf = params;
  float* Etot = params + 32ull * 16 * 16 * 128;
  float* Hbuf = xmid;
  float* psum = (float*)alloc(4ull * ROWS * 1024 * 4);   // 33.6MB split-K partials
  const bool sk = (off <= ws_size);

  dim3 b256(256);
  cvt_pad<<<4096, b256, 0, stream>>>(W_in, wb_in, 4096, 1024);
  cvt_pad<<<1280, b256, 0, stream>>>(W_param, wb_par, 528, 2048);
  cvt_pad<<<2048, b256, 0, stream>>>(W_out, wb_out, 1024, 2048);
  cvt_pad<<<4096, b256, 0, stream>>>(W_ffn1, wb_f1, 4096, 1024);
  cvt_pad<<<4096, b256, 0, stream>>>(W_ffn2, wb_f2, 1024, 4096);
  rmsnorm_k<<<2048, b256, 0, stream>>>(x, g1, zbuf);

  if (sk) {
    // xz|gate = z @ W_in^T, fused split-silu: xz_act bf16, gbuf fp32
    gemm_bt<4><<<dim3(32, 16), b256, 0, stream>>>(zbuf, wb_in, psum, nullptr, nullptr, xz_act, gbuf, 4096, 1024);
    gemm_bt<0><<<dim3(PPAD / 128, 16, 4), b256, 0, stream>>>(xz_act, wb_par, psum, nullptr, nullptr, nullptr, nullptr, PPAD, 512);
    ssm_prep<<<128, b256, 0, stream>>>(psum, A_log, ssmp, 4);
    ssm_chunk<<<512, b256, 0, stream>>>(ssmp, xz_act, Sbuf, Etot);
    ssm_combine<<<256, b256, 0, stream>>>(Sbuf, Etot, Hbuf);
    ssm_out<<<512, b256, 0, stream>>>(ssmp, xz_act, Hbuf, gbuf, 2048, y_b16);
    gemm_bt<0><<<dim3(8, 16, 4), b256, 0, stream>>>(y_b16, wb_out, psum, nullptr, nullptr, nullptr, nullptr, 1024, 512);
    reduce_rms<<<2048, b256, 0, stream>>>(psum, x, g2, xmid, zbuf);
    // ffn1 + bias + silu -> f_act bf16 (fused)
    gemm_bt<9><<<dim3(32, 16), b256, 0, stream>>>(zbuf, wb_f1, psum, b_ffn1, nullptr, f_act, nullptr, 4096, 1024);
    gemm_bt<0><<<dim3(8, 16, 4), b256, 0, stream>>>(f_act, wb_f2, psum, nullptr, nullptr, nullptr, nullptr, 1024, 1024);
    reduce_bias<<<2048, b256, 0, stream>>>(psum, xmid, b_ffn2, out);
  } else {
    gemm_bt<0><<<dim3(32, 16), b256, 0, stream>>>(zbuf, wb_in, xzg, nullptr, nullptr, nullptr, nullptr, 4096, 1024);
    silu_cvt<<<4096, b256, 0, stream>>>(xzg, xz_act, 4096, 2048);
    gemm_bt<0><<<dim3(PPAD / 128, 16), b256, 0, stream>>>(xz_act, wb_par, params, nullptr, nullptr, nullptr, nullptr, PPAD, 2048);
    ssm_prep<<<128, b256, 0, stream>>>(params, A_log, ssmp, 1);
    ssm_chunk<<<512, b256, 0, stream>>>(ssmp, xz_act, Sbuf, Etot);
    ssm_combine<<<256, b256, 0, stream>>>(Sbuf, Etot, Hbuf);
    ssm_out<<<512, b256, 0, stream>>>(ssmp, xz_act, Hbuf, xzg + 2048, 4096, y_b16);
    gemm_bt<2><<<dim3(8, 16), b256, 0, stream>>>(y_b16, wb_out, xmid, nullptr, x, nullptr, nullptr, 1024, 2048);
    rmsnorm_k<<<2048, b256, 0, stream>>>(xmid, g2, zbuf);
    gemm_bt<1><<<dim3(32, 16), b256, 0, stream>>>(zbuf, wb_f1, xzg, b_ffn1, nullptr, nullptr, nullptr, 4096, 1024);
    silu_cvt<<<8192, b256, 0, stream>>>(xzg, f_act, 4096, 4096);
    gemm_bt<3><<<dim3(8, 16), b256, 0, stream>>>(f_act, wb_f2, out, b_ffn2, xmid, nullptr, nullptr, 1024, 4096);
  }
}

// Round 5
// 211.760 us; speedup vs baseline: 4.7749x; 1.0761x over previous
//
#include <hip/hip_runtime.h>
#include <hip/hip_bf16.h>
#include <stdint.h>

// MambaBlock: B=2, T=1024, D_MODEL=1024, D_INNER=2048, GROUPS=16, D_STATE=16
#define ROWS 2048      // B*T
#define DM   1024
#define DI   2048
#define PPAD 640       // 528 param rows padded to 5*128

typedef __bf16 bf16_t;
typedef __attribute__((ext_vector_type(8))) __bf16 bf16x8;
typedef __attribute__((ext_vector_type(4))) __bf16 bf16x4;
typedef __attribute__((ext_vector_type(4))) float f32x4;
typedef __attribute__((address_space(1))) void gvoid_t;
typedef __attribute__((address_space(3))) void lvoid_t;

// ---------------- all weights fp32 -> bf16, one launch ----------------------
// regions in 4-element groups: W_in | W_param(pad 528->640) | W_out | W_f1 | W_f2
#define G_IN   1048576ll
#define G_PAR  327680ll
#define G_OUT  524288ll
#define G_F1   1048576ll
#define G_F2   1048576ll
__global__ __launch_bounds__(256) void cvt_all(const float* __restrict__ W_in,
                                               const float* __restrict__ W_param,
                                               const float* __restrict__ W_out,
                                               const float* __restrict__ W_f1,
                                               const float* __restrict__ W_f2,
                                               bf16_t* o_in, bf16_t* o_par,
                                               bf16_t* o_out, bf16_t* o_f1,
                                               bf16_t* o_f2) {
  int64_t g4 = (int64_t)blockIdx.x * 256 + threadIdx.x;
  const float* src; bf16_t* dst; int64_t e;
  if (g4 < G_IN) { e = g4 * 4; src = W_in; dst = o_in; }
  else if (g4 < G_IN + G_PAR) {
    e = (g4 - G_IN) * 4;
    int row = (int)(e >> 11), col = (int)(e & 2047);
    float4 v = make_float4(0.f, 0.f, 0.f, 0.f);
    if (row < 528) v = *(const float4*)(W_param + (int64_t)row * 2048 + col);
    bf16_t* o = o_par + e;
    o[0] = (bf16_t)v.x; o[1] = (bf16_t)v.y; o[2] = (bf16_t)v.z; o[3] = (bf16_t)v.w;
    return;
  }
  else if (g4 < G_IN + G_PAR + G_OUT) { e = (g4 - G_IN - G_PAR) * 4; src = W_out; dst = o_out; }
  else if (g4 < G_IN + G_PAR + G_OUT + G_F1) { e = (g4 - G_IN - G_PAR - G_OUT) * 4; src = W_f1; dst = o_f1; }
  else { e = (g4 - G_IN - G_PAR - G_OUT - G_F1) * 4; src = W_f2; dst = o_f2; }
  float4 v = *(const float4*)(src + e);
  bf16_t* o = dst + e;
  o[0] = (bf16_t)v.x; o[1] = (bf16_t)v.y; o[2] = (bf16_t)v.z; o[3] = (bf16_t)v.w;
}

// ---------------- rmsnorm (D=1024), fp32 in -> bf16 out ----------------
__global__ __launch_bounds__(256) void rmsnorm_k(const float* __restrict__ x,
                                                 const float* __restrict__ g,
                                                 bf16_t* __restrict__ out) {
  int row = blockIdx.x;
  int tid = threadIdx.x;
  const float4 v = *(const float4*)(x + (int64_t)row * DM + tid * 4);
  float ss = v.x * v.x + v.y * v.y + v.z * v.z + v.w * v.w;
#pragma unroll
  for (int o = 32; o; o >>= 1) ss += __shfl_xor(ss, o, 64);
  __shared__ float red[4];
  if ((tid & 63) == 0) red[tid >> 6] = ss;
  __syncthreads();
  float tot = red[0] + red[1] + red[2] + red[3];
  float sc = rsqrtf(tot * (1.0f / DM) + 1e-6f);
  const float4 gv = *(const float4*)(g + tid * 4);
  bf16_t* o = out + (int64_t)row * DM + tid * 4;
  o[0] = (bf16_t)(v.x * sc * gv.x);
  o[1] = (bf16_t)(v.y * sc * gv.y);
  o[2] = (bf16_t)(v.z * sc * gv.z);
  o[3] = (bf16_t)(v.w * sc * gv.w);
}

// ---------------- silu + fp32 -> bf16 (fallback path only) ----------------
__global__ __launch_bounds__(256) void silu_cvt(const float* __restrict__ in,
                                                bf16_t* __restrict__ out,
                                                int in_stride, int ncols) {
  int64_t e = ((int64_t)blockIdx.x * 256 + threadIdx.x) * 4;
  int row = (int)(e / ncols);
  int col = (int)(e % ncols);
  const float4 v = *(const float4*)(in + (int64_t)row * in_stride + col);
  bf16_t* o = out + e;
  o[0] = (bf16_t)(v.x / (1.f + expf(-v.x)));
  o[1] = (bf16_t)(v.y / (1.f + expf(-v.y)));
  o[2] = (bf16_t)(v.z / (1.f + expf(-v.z)));
  o[3] = (bf16_t)(v.w / (1.f + expf(-v.w)));
}

// ---------------- SSM coefficient prep (sums nparts split-K fp32 partials) --
// layout ssmp[bg][t][48] = { dA_clipped[16], frac*b[16], c[16] }
__global__ __launch_bounds__(256) void ssm_prep(const float* __restrict__ params,
                                                const float* __restrict__ A_log,
                                                float* __restrict__ ssmp, int nparts) {
  int gid = blockIdx.x * 256 + threadIdx.x;  // 32 * 1024
  int bg = gid >> 10, t = gid & 1023;
  int b = bg >> 4, g = bg & 15;
  float acc[33];
#pragma unroll
  for (int i = 0; i < 33; ++i) acc[i] = 0.f;
  for (int p = 0; p < nparts; ++p) {
    const float* pr = params + (int64_t)p * ROWS * PPAD + (int64_t)(b * 1024 + t) * PPAD + g * 33;
#pragma unroll
    for (int i = 0; i < 33; ++i) acc[i] += pr[i];
  }
  float raw = acc[0];
  float delta = raw > 0.f ? raw + log1pf(expf(-raw)) : log1pf(expf(raw));
  float* o = ssmp + (int64_t)gid * 48;
#pragma unroll
  for (int s = 0; s < 16; ++s) {
    float A = -expf(A_log[s]);
    float dA = delta * A;
    dA = fminf(10.f, fmaxf(-10.f, dA));
    float e = expf(dA);
    float frac = (fabsf(dA) < 1e-4f) ? delta : (e - 1.f) / (A + 1e-12f);
    o[s] = dA;
    o[16 + s] = frac * acc[1 + s];
    o[32 + s] = acc[17 + s];
  }
}

// ---------------- split-K reduce (bf16 partials) + residual + rmsnorm -------
__global__ __launch_bounds__(256) void reduce_rms(const bf16_t* __restrict__ P,
                                                  const float* __restrict__ x,
                                                  const float* __restrict__ g,
                                                  float* __restrict__ xmid,
                                                  bf16_t* __restrict__ zb) {
  int row = blockIdx.x;
  int tid = threadIdx.x;
  int64_t base = (int64_t)row * DM + tid * 4;
  float4 v = *(const float4*)(x + base);
#pragma unroll
  for (int p = 0; p < 4; ++p) {
    bf16x4 pv = *(const bf16x4*)(P + (int64_t)p * ROWS * DM + base);
    v.x += (float)pv[0]; v.y += (float)pv[1]; v.z += (float)pv[2]; v.w += (float)pv[3];
  }
  *(float4*)(xmid + base) = v;
  float ss = v.x * v.x + v.y * v.y + v.z * v.z + v.w * v.w;
#pragma unroll
  for (int o = 32; o; o >>= 1) ss += __shfl_xor(ss, o, 64);
  __shared__ float red[4];
  if ((tid & 63) == 0) red[tid >> 6] = ss;
  __syncthreads();
  float tot = red[0] + red[1] + red[2] + red[3];
  float sc = rsqrtf(tot * (1.0f / DM) + 1e-6f);
  const float4 gv = *(const float4*)(g + tid * 4);
  bf16_t* o = zb + base;
  o[0] = (bf16_t)(v.x * sc * gv.x);
  o[1] = (bf16_t)(v.y * sc * gv.y);
  o[2] = (bf16_t)(v.z * sc * gv.z);
  o[3] = (bf16_t)(v.w * sc * gv.w);
}

// out = res + bias + sum_p P[p] (bf16 partials)  (2048 x 1024)
__global__ __launch_bounds__(256) void reduce_bias(const bf16_t* __restrict__ P,
                                                   const float* __restrict__ res,
                                                   const float* __restrict__ bias,
                                                   float* __restrict__ out) {
  int64_t e = ((int64_t)blockIdx.x * 256 + threadIdx.x) * 4;
  int col = (int)(e % DM);
  float4 v = *(const float4*)(res + e);
  const float4 bv = *(const float4*)(bias + col);
  v.x += bv.x; v.y += bv.y; v.z += bv.z; v.w += bv.w;
#pragma unroll
  for (int p = 0; p < 4; ++p) {
    bf16x4 pv = *(const bf16x4*)(P + (int64_t)p * ROWS * DM + e);
    v.x += (float)pv[0]; v.y += (float)pv[1]; v.z += (float)pv[2]; v.w += (float)pv[3];
  }
  *(float4*)(out + e) = v;
}

// Ut layout: element (ch, t) at byte ch*128 + ((t*2) ^ ((ch&7)<<4))

// ---------------- Phase A: per-chunk boundary operator (MFMA) ---------------
__global__ __launch_bounds__(256) void ssm_chunk(const float* __restrict__ ssmp,
                                                 const bf16_t* __restrict__ u,
                                                 float* __restrict__ S,
                                                 float* __restrict__ Etot) {
  __shared__ __align__(16) float cf[64 * 48];
  __shared__ __align__(16) float Lb[64 * 16];
  __shared__ __align__(16) bf16_t wl[16 * 64];
  __shared__ __align__(16) bf16_t Ut[128 * 64];
  int bgc = blockIdx.x;
  int bg = bgc >> 4, c = bgc & 15;
  int b = bg >> 4, g = bg & 15;
  int t0 = c * 64;
  int tid = threadIdx.x;
  {
    const float4* src = (const float4*)(ssmp + ((int64_t)bg * 1024 + t0) * 48);
    float4* dst = (float4*)cf;
#pragma unroll
    for (int i = 0; i < 3; ++i) dst[i * 256 + tid] = src[i * 256 + tid];
  }
  {
    int lt = tid >> 4;
    int c8 = (tid & 15) * 8;
#pragma unroll
    for (int p = 0; p < 4; ++p) {
      int t = p * 16 + lt;
      bf16x8 v = *(const bf16x8*)(u + ((int64_t)(b * 1024) + t0 + t) * 2048 + g * 128 + c8);
#pragma unroll
      for (int j = 0; j < 8; ++j)
        Ut[(c8 + j) * 64 + (((t >> 3) ^ j) << 3) + (t & 7)] = v[j];
    }
  }
  __syncthreads();
  if (tid < 16) {
    float l = 0.f;
    for (int t = 0; t < 64; ++t) { l += cf[t * 48 + tid]; Lb[t * 16 + tid] = l; }
  }
  __syncthreads();
  {
    int s = tid >> 4, tb4 = (tid & 15) * 4;
    float lend = Lb[63 * 16 + s];
    bf16x4 wv;
#pragma unroll
    for (int j = 0; j < 4; ++j) {
      int t = tb4 + j;
      wv[j] = (bf16_t)(__expf(lend - Lb[t * 16 + s]) * cf[t * 48 + 16 + s]);
    }
    unsigned byo = (unsigned)(s * 128 + tb4 * 2) ^ ((unsigned)(s & 7) << 4);
    *(bf16x4*)((char*)wl + byo) = wv;
    if (tid < 16) Etot[(int64_t)bgc * 16 + tid] = __expf(Lb[63 * 16 + tid]);
  }
  __syncthreads();
  {
    int lane = tid & 63, wave = tid >> 6;
    int fr = lane & 15, kq = lane >> 4;
    f32x4 acc2[2] = {};
#pragma unroll
    for (int kk = 0; kk < 2; ++kk) {
      int kb = kk * 4 + kq;
      bf16x8 af = *(const bf16x8*)((const char*)wl +
                    ((unsigned)(fr * 128 + kb * 16) ^ ((unsigned)(fr & 7) << 4)));
#pragma unroll
      for (int q = 0; q < 2; ++q) {
        int ch = (wave * 2 + q) * 16 + fr;
        bf16x8 bfr = *(const bf16x8*)((const char*)Ut +
                       ((unsigned)(ch * 128 + kb * 16) ^ ((unsigned)(ch & 7) << 4)));
        acc2[q] = __builtin_amdgcn_mfma_f32_16x16x32_bf16(af, bfr, acc2[q], 0, 0, 0);
      }
    }
    float* Sp = S + (int64_t)bgc * 2048;
#pragma unroll
    for (int q = 0; q < 2; ++q) {
      int ch = (wave * 2 + q) * 16 + fr;
#pragma unroll
      for (int j = 0; j < 4; ++j) Sp[(kq * 4 + j) * 128 + ch] = acc2[q][j];
    }
  }
}

// ---------------- Phase B: sequential combine over 16 chunks ----------------
__global__ __launch_bounds__(256) void ssm_combine(const float* __restrict__ S,
                                                   const float* __restrict__ Etot,
                                                   float* __restrict__ H) {
  int gid = blockIdx.x * 256 + threadIdx.x;
  int bg = gid >> 11;
  int s = (gid >> 7) & 15;
  int ch = gid & 127;
  float h = 0.f;
  for (int c = 0; c < 16; ++c) {
    int bgc = bg * 16 + c;
    int64_t idx = ((int64_t)bgc * 16 + s) * 128 + ch;
    H[idx] = h;
    h = Etot[(int64_t)bgc * 16 + s] * h + S[idx];
  }
}

// ---------------- Phase C: y = tril(K)@U + ce@H, fused gate (MFMA) ----------
// GM=1: gate_b = bf16 pre-silu'd, stride 2048. GM=0: gate_f fp32 raw, gstride.
template <int GM>
__global__ __launch_bounds__(256) void ssm_out(const float* __restrict__ ssmp,
                                               const bf16_t* __restrict__ u,
                                               const float* __restrict__ H,
                                               const float* __restrict__ gate_f,
                                               const bf16_t* __restrict__ gate_b,
                                               int gstride,
                                               bf16_t* __restrict__ yout) {
  __shared__ __align__(16) float cf[64 * 48];
  __shared__ __align__(16) float Lb[64 * 16];
  __shared__ __align__(16) bf16_t Km[64 * 64];
  __shared__ __align__(16) bf16_t Ut[128 * 64];
  __shared__ __align__(16) bf16_t Hb[128 * 32];
  int bgc = blockIdx.x;
  int bg = bgc >> 4, c = bgc & 15;
  int b = bg >> 4, g = bg & 15;
  int t0 = c * 64;
  int tid = threadIdx.x;
  int lane = tid & 63, wave = tid >> 6;
  {
    const float4* src = (const float4*)(ssmp + ((int64_t)bg * 1024 + t0) * 48);
    float4* dst = (float4*)cf;
#pragma unroll
    for (int i = 0; i < 3; ++i) dst[i * 256 + tid] = src[i * 256 + tid];
  }
  {
    int lt = tid >> 4;
    int c8 = (tid & 15) * 8;
#pragma unroll
    for (int p = 0; p < 4; ++p) {
      int t = p * 16 + lt;
      bf16x8 v = *(const bf16x8*)(u + ((int64_t)(b * 1024) + t0 + t) * 2048 + g * 128 + c8);
#pragma unroll
      for (int j = 0; j < 8; ++j)
        Ut[(c8 + j) * 64 + (((t >> 3) ^ j) << 3) + (t & 7)] = v[j];
    }
  }
  {
    int ch = tid >> 1, h8 = (tid & 1) * 8;
    const float* Hp = H + (int64_t)bgc * 2048 + ch;
#pragma unroll
    for (int j = 0; j < 8; ++j) {
      Hb[ch * 32 + h8 + j] = (bf16_t)Hp[(h8 + j) * 128];
      Hb[ch * 32 + 16 + h8 + j] = (bf16_t)0.f;
    }
  }
  __syncthreads();
  if (tid < 16) {
    float l = 0.f;
    for (int t = 0; t < 64; ++t) { l += cf[t * 48 + tid]; Lb[t * 16 + tid] = l; }
  }
  __syncthreads();
  {
    int s = tid & 15;
    (void)s;
  }
  // K[t][t'] = sum_s c[t,s] exp(L[t,s]-L[t',s]) fb[t',s]  (t>=t', else 0) -> bf16
  {
    int t = tid >> 2, tp0 = (tid & 3) * 16;
    float4 cv[4], lv[4];
#pragma unroll
    for (int i = 0; i < 4; ++i) {
      cv[i] = *(const float4*)&cf[t * 48 + 32 + i * 4];
      lv[i] = *(const float4*)&Lb[t * 16 + i * 4];
    }
    float kv[16];
#pragma unroll
    for (int i = 0; i < 16; ++i) {
      int tp = tp0 + i;
      float k = 0.f;
      if (tp <= t) {
#pragma unroll
        for (int q = 0; q < 4; ++q) {
          float4 lpv = *(const float4*)&Lb[tp * 16 + q * 4];
          float4 fbv = *(const float4*)&cf[tp * 48 + 16 + q * 4];
          k += cv[q].x * __expf(lv[q].x - lpv.x) * fbv.x
             + cv[q].y * __expf(lv[q].y - lpv.y) * fbv.y
             + cv[q].z * __expf(lv[q].z - lpv.z) * fbv.z
             + cv[q].w * __expf(lv[q].w - lpv.w) * fbv.w;
        }
      }
      kv[i] = k;
    }
    bf16x8 lo, hi;
#pragma unroll
    for (int i = 0; i < 8; ++i) { lo[i] = (bf16_t)kv[i]; hi[i] = (bf16_t)kv[8 + i]; }
    unsigned b0 = (unsigned)(t * 128 + tp0 * 2) ^ ((unsigned)(t & 7) << 4);
    unsigned b1 = (unsigned)(t * 128 + tp0 * 2 + 16) ^ ((unsigned)(t & 7) << 4);
    *(bf16x8*)((char*)Km + b0) = lo;
    *(bf16x8*)((char*)Km + b1) = hi;
  }
  __syncthreads();
  int fr = lane & 15, kq = lane >> 4;
  int trow = (wave >> 1) * 32, wc = (wave & 1) * 64;
  f32x4 acc[2][4] = {};
#pragma unroll
  for (int kk = 0; kk < 2; ++kk) {
    int kb = kk * 4 + kq;
    bf16x8 af[2];
#pragma unroll
    for (int mi = 0; mi < 2; ++mi) {
      int row = trow + mi * 16 + fr;
      af[mi] = *(const bf16x8*)((const char*)Km +
                 ((unsigned)(row * 128 + kb * 16) ^ ((unsigned)(row & 7) << 4)));
    }
#pragma unroll
    for (int ni = 0; ni < 4; ++ni) {
      int ch = wc + ni * 16 + fr;
      bf16x8 bfr = *(const bf16x8*)((const char*)Ut +
                     ((unsigned)(ch * 128 + kb * 16) ^ ((unsigned)(ch & 7) << 4)));
#pragma unroll
      for (int mi = 0; mi < 2; ++mi)
        acc[mi][ni] = __builtin_amdgcn_mfma_f32_16x16x32_bf16(af[mi], bfr, acc[mi][ni], 0, 0, 0);
    }
  }
  {
    int s0 = kq * 8;
    bf16x8 cef[2];
    if (s0 < 16) {
#pragma unroll
      for (int mi = 0; mi < 2; ++mi) {
        int t = trow + mi * 16 + fr;
#pragma unroll
        for (int j = 0; j < 8; ++j)
          cef[mi][j] = (bf16_t)(cf[t * 48 + 32 + s0 + j] * __expf(Lb[t * 16 + s0 + j]));
      }
    } else {
#pragma unroll
      for (int mi = 0; mi < 2; ++mi)
#pragma unroll
        for (int j = 0; j < 8; ++j) cef[mi][j] = (bf16_t)0.f;
    }
#pragma unroll
    for (int ni = 0; ni < 4; ++ni) {
      int ch = wc + ni * 16 + fr;
      bf16x8 bhf = *(const bf16x8*)((const char*)Hb + ch * 64 + s0 * 2);
#pragma unroll
      for (int mi = 0; mi < 2; ++mi)
        acc[mi][ni] = __builtin_amdgcn_mfma_f32_16x16x32_bf16(cef[mi], bhf, acc[mi][ni], 0, 0, 0);
    }
  }
  {
    int64_t rowbase = (int64_t)b * 1024 + t0;
    int colbase = g * 128;
#pragma unroll
    for (int mi = 0; mi < 2; ++mi) {
#pragma unroll
      for (int ni = 0; ni < 4; ++ni) {
        int col = colbase + wc + ni * 16 + fr;
#pragma unroll
        for (int j = 0; j < 4; ++j) {
          int t = trow + mi * 16 + kq * 4 + j;
          float sg;
          if (GM) {
            sg = (float)gate_b[(rowbase + t) * 2048 + col];
          } else {
            float gv = gate_f[(rowbase + t) * (int64_t)gstride + col];
            sg = gv / (1.f + __expf(-gv));
          }
          yout[(rowbase + t) * 2048 + col] = (bf16_t)(acc[mi][ni][j] * sg);
        }
      }
    }
  }
}

// ---------------- bf16 GEMM, double-buffered 2-phase K-loop -----------------
// C[M,N] = A[M,K] @ Bw[N,K]^T. grid (N/128, M/128, SK).
// EPI: bit0 bias, bit1 res, bit2 split-silu (xz bf16 | silu(gate) bf16),
//      bit3 bias+silu -> obf bf16, bit4 bf16 partial -> obf + z*ROWS*N.
template <int EPI>
__global__ __launch_bounds__(256) void gemm_bt(const bf16_t* __restrict__ A,
                                               const bf16_t* __restrict__ Bw,
                                               float* __restrict__ C,
                                               const float* __restrict__ bias,
                                               const float* __restrict__ res,
                                               bf16_t* __restrict__ obf,
                                               bf16_t* __restrict__ ogate,
                                               int N, int Kps) {
  __shared__ bf16_t As[2][128 * 64];
  __shared__ bf16_t Bs[2][128 * 64];
  const int tid = threadIdx.x;
  const int wave = tid >> 6;
  const int lane = tid & 63;
  const int64_t m0 = (int64_t)blockIdx.y * 128;
  const int64_t n0 = (int64_t)blockIdx.x * 128;
  const int K = Kps * gridDim.z;
  const int kbeg = blockIdx.z * Kps;
  float* Cz = C + (int64_t)blockIdx.z * ROWS * N;
  const int wm = (wave >> 1) * 64;
  const int wn = (wave & 1) * 64;
  f32x4 acc[4][4] = {};

  const int er = tid >> 3;        // row within 32-row stripe
  const int ec = (tid * 8) & 63;  // col (k) within tile
  const int fr = lane & 15;
  const int kq = (lane >> 4) * 8;

  auto stage = [&](int buf, int k0) {
#pragma unroll
    for (int i = 0; i < 4; ++i) {
      const bf16_t* ga = A + (m0 + er + i * 32) * K + k0 + ec;
      __builtin_amdgcn_global_load_lds((gvoid_t*)ga,
                                       (lvoid_t*)&As[buf][(i * 256 + wave * 64) * 8],
                                       16, 0, 0);
    }
#pragma unroll
    for (int i = 0; i < 4; ++i) {
      const bf16_t* gb = Bw + (n0 + er + i * 32) * K + k0 + ec;
      __builtin_amdgcn_global_load_lds((gvoid_t*)gb,
                                       (lvoid_t*)&Bs[buf][(i * 256 + wave * 64) * 8],
                                       16, 0, 0);
    }
  };
  auto compute = [&](int buf) {
#pragma unroll
    for (int kk = 0; kk < 2; ++kk) {
      bf16x8 af[4], bv[4];
#pragma unroll
      for (int mi = 0; mi < 4; ++mi)
        af[mi] = *reinterpret_cast<const bf16x8*>(&As[buf][(wm + mi * 16 + fr) * 64 + kk * 32 + kq]);
#pragma unroll
      for (int ni = 0; ni < 4; ++ni)
        bv[ni] = *reinterpret_cast<const bf16x8*>(&Bs[buf][(wn + ni * 16 + fr) * 64 + kk * 32 + kq]);
#pragma unroll
      for (int mi = 0; mi < 4; ++mi)
#pragma unroll
        for (int ni = 0; ni < 4; ++ni)
          acc[mi][ni] = __builtin_amdgcn_mfma_f32_16x16x32_bf16(af[mi], bv[ni], acc[mi][ni], 0, 0, 0);
    }
  };

  const int nk = Kps >> 6;  // assumed even
  stage(0, kbeg);
  asm volatile("s_waitcnt vmcnt(0)" ::: "memory");
  __builtin_amdgcn_s_barrier();
  int kc = kbeg;
  for (int t = 0; t < nk; t += 2) {
    stage(1, kc + 64);
    compute(0);
    asm volatile("s_waitcnt vmcnt(0)" ::: "memory");
    __builtin_amdgcn_s_barrier();
    if (t + 2 < nk) stage(0, kc + 128);
    compute(1);
    asm volatile("s_waitcnt vmcnt(0)" ::: "memory");
    __builtin_amdgcn_s_barrier();
    kc += 128;
  }

  const int crow = (lane >> 4) * 4;
  const int ccol = lane & 15;
#pragma unroll
  for (int mi = 0; mi < 4; ++mi) {
#pragma unroll
    for (int ni = 0; ni < 4; ++ni) {
#pragma unroll
      for (int j = 0; j < 4; ++j) {
        int64_t r = m0 + wm + mi * 16 + crow + j;
        int64_t cn = n0 + wn + ni * 16 + ccol;
        float v = acc[mi][ni][j];
        if (EPI & 1) v += bias[cn];
        if (EPI & 2) v += res[r * N + cn];
        if (EPI & 4) {
          float sv = v / (1.f + __expf(-v));
          if (cn < 2048) obf[r * 2048 + cn] = (bf16_t)sv;
          else ogate[r * 2048 + cn - 2048] = (bf16_t)sv;
        } else if (EPI & 8) {
          obf[r * N + cn] = (bf16_t)(v / (1.f + __expf(-v)));
        } else if (EPI & 16) {
          obf[(int64_t)blockIdx.z * ROWS * N + r * N + cn] = (bf16_t)v;
        } else {
          Cz[r * N + cn] = v;
        }
      }
    }
  }
}

extern "C" void kernel_launch(void* const* d_in, const int* in_sizes, int n_in,
                              void* d_out, int out_size, void* d_ws, size_t ws_size,
                              hipStream_t stream) {
  const float* x       = (const float*)d_in[0];
  const float* A_log   = (const float*)d_in[1];
  const float* g1      = (const float*)d_in[2];
  const float* g2      = (const float*)d_in[3];
  const float* W_in    = (const float*)d_in[4];
  const float* W_param = (const float*)d_in[5];
  const float* W_out   = (const float*)d_in[6];
  const float* W_ffn1  = (const float*)d_in[7];
  const float* b_ffn1  = (const float*)d_in[8];
  const float* W_ffn2  = (const float*)d_in[9];
  const float* b_ffn2  = (const float*)d_in[10];
  float* out = (float*)d_out;

  char* ws = (char*)d_ws;
  size_t off = 0;
  auto alloc = [&](size_t bytes) {
    char* p = ws + off;
    off += (bytes + 255) & ~(size_t)255;
    return p;
  };
  bf16_t* wb_in  = (bf16_t*)alloc(4096ull * 1024 * 2);
  bf16_t* wb_par = (bf16_t*)alloc((size_t)PPAD * 2048 * 2);
  bf16_t* wb_out = (bf16_t*)alloc(1024ull * 2048 * 2);
  bf16_t* wb_f1  = (bf16_t*)alloc(4096ull * 1024 * 2);
  bf16_t* wb_f2  = (bf16_t*)alloc(1024ull * 4096 * 2);
  bf16_t* zbuf   = (bf16_t*)alloc(2048ull * 1024 * 2);   // z, later h2
  float*  xzg    = (float*)alloc(2048ull * 4096 * 4);    // sgate bf16 (sk) / xz|gate fp32 (fallback)
  float*  params = (float*)alloc(2048ull * PPAD * 4);    // fallback only; S/Etot overlay
  float*  ssmp   = (float*)alloc(32ull * 1024 * 48 * 4);
  float*  xmid   = (float*)alloc(2048ull * 1024 * 4);
  char*   regA   = alloc(2048ull * 4096 * 2);            // 16MB union
  bf16_t* xz_act = (bf16_t*)regA;
  bf16_t* y_b16  = (bf16_t*)(regA + 2048ull * 2048 * 2);
  bf16_t* f_act  = (bf16_t*)regA;
  bf16_t* sgate  = (bf16_t*)xzg;                         // [2048][2048] bf16 (sk)
  float* Sbuf = params;
  float* Etot = params + 32ull * 16 * 16 * 128;
  float* Hbuf = xmid;
  float*  psum = (float*)alloc(4ull * ROWS * 1024 * 4);  // 33.6MB: fp32 param partials
  bf16_t* pb16 = (bf16_t*)psum;                          // bf16 partials overlay (16.8MB)
  const bool sk = (off <= ws_size);

  dim3 b256(256);
  cvt_all<<<15616, b256, 0, stream>>>(W_in, W_param, W_out, W_ffn1, W_ffn2,
                                      wb_in, wb_par, wb_out, wb_f1, wb_f2);
  rmsnorm_k<<<2048, b256, 0, stream>>>(x, g1, zbuf);

  if (sk) {
    // xz|gate = z @ W_in^T, fused: silu(xz)->xz_act bf16, silu(gate)->sgate bf16
    gemm_bt<4><<<dim3(32, 16), b256, 0, stream>>>(zbuf, wb_in, psum, nullptr, nullptr, xz_act, sgate, 4096, 1024);
    gemm_bt<0><<<dim3(PPAD / 128, 16, 4), b256, 0, stream>>>(xz_act, wb_par, psum, nullptr, nullptr, nullptr, nullptr, PPAD, 512);
    ssm_prep<<<128, b256, 0, stream>>>(psum, A_log, ssmp, 4);
    ssm_chunk<<<512, b256, 0, stream>>>(ssmp, xz_act, Sbuf, Etot);
    ssm_combine<<<256, b256, 0, stream>>>(Sbuf, Etot, Hbuf);
    ssm_out<1><<<512, b256, 0, stream>>>(ssmp, xz_act, Hbuf, nullptr, sgate, 2048, y_b16);
    // xmid = x + y @ W_out^T (SK=4, bf16 partials) fused reduce+rmsnorm
    gemm_bt<16><<<dim3(8, 16, 4), b256, 0, stream>>>(y_b16, wb_out, psum, nullptr, nullptr, pb16, nullptr, 1024, 512);
    reduce_rms<<<2048, b256, 0, stream>>>(pb16, x, g2, xmid, zbuf);
    // ffn1 + bias + silu -> f_act bf16 (fused)
    gemm_bt<9><<<dim3(32, 16), b256, 0, stream>>>(zbuf, wb_f1, psum, b_ffn1, nullptr, f_act, nullptr, 4096, 1024);
    // out = xmid + b_ffn2 + f_act @ W_ffn2^T (SK=4, bf16 partials)
    gemm_bt<16><<<dim3(8, 16, 4), b256, 0, stream>>>(f_act, wb_f2, psum, nullptr, nullptr, pb16, nullptr, 1024, 1024);
    reduce_bias<<<2048, b256, 0, stream>>>(pb16, xmid, b_ffn2, out);
  } else {
    gemm_bt<0><<<dim3(32, 16), b256, 0, stream>>>(zbuf, wb_in, xzg, nullptr, nullptr, nullptr, nullptr, 4096, 1024);
    silu_cvt<<<4096, b256, 0, stream>>>(xzg, xz_act, 4096, 2048);
    gemm_bt<0><<<dim3(PPAD / 128, 16), b256, 0, stream>>>(xz_act, wb_par, params, nullptr, nullptr, nullptr, nullptr, PPAD, 2048);
    ssm_prep<<<128, b256, 0, stream>>>(params, A_log, ssmp, 1);
    ssm_chunk<<<512, b256, 0, stream>>>(ssmp, xz_act, Sbuf, Etot);
    ssm_combine<<<256, b256, 0, stream>>>(Sbuf, Etot, Hbuf);
    ssm_out<0><<<512, b256, 0, stream>>>(ssmp, xz_act, Hbuf, xzg + 2048, nullptr, 4096, y_b16);
    gemm_bt<2><<<dim3(8, 16), b256, 0, stream>>>(y_b16, wb_out, xmid, nullptr, x, nullptr, nullptr, 1024, 2048);
    rmsnorm_k<<<2048, b256, 0, stream>>>(xmid, g2, zbuf);
    gemm_bt<1><<<dim3(32, 16), b256, 0, stream>>>(zbuf, wb_f1, xzg, b_ffn1, nullptr, nullptr, nullptr, 4096, 1024);
    silu_cvt<<<8192, b256, 0, stream>>>(xzg, f_act, 4096, 4096);
    gemm_bt<3><<<dim3(8, 16), b256, 0, stream>>>(f_act, wb_f2, out, b_ffn2, xmid, nullptr, nullptr, 1024, 4096);
  }
}

// Round 6
// 194.173 us; speedup vs baseline: 5.2074x; 1.0906x over previous
//
#include <hip/hip_runtime.h>
#include <hip/hip_bf16.h>
#include <stdint.h>

// MambaBlock: B=2, T=1024, D_MODEL=1024, D_INNER=2048, GROUPS=16, D_STATE=16
#define ROWS 2048      // B*T
#define DM   1024
#define DI   2048
#define PPAD 640       // 528 param rows padded to 5*128

typedef __bf16 bf16_t;
typedef __attribute__((ext_vector_type(8))) __bf16 bf16x8;
typedef __attribute__((ext_vector_type(4))) __bf16 bf16x4;
typedef __attribute__((ext_vector_type(4))) float f32x4;
typedef __attribute__((address_space(1))) void gvoid_t;
typedef __attribute__((address_space(3))) void lvoid_t;

// ---------------- all weights fp32 -> bf16, one launch ----------------------
#define G_IN   1048576ll
#define G_PAR  327680ll
#define G_OUT  524288ll
#define G_F1   1048576ll
#define G_F2   1048576ll
__global__ __launch_bounds__(256) void cvt_all(const float* __restrict__ W_in,
                                               const float* __restrict__ W_param,
                                               const float* __restrict__ W_out,
                                               const float* __restrict__ W_f1,
                                               const float* __restrict__ W_f2,
                                               bf16_t* o_in, bf16_t* o_par,
                                               bf16_t* o_out, bf16_t* o_f1,
                                               bf16_t* o_f2) {
  int64_t g4 = (int64_t)blockIdx.x * 256 + threadIdx.x;
  const float* src; bf16_t* dst; int64_t e;
  if (g4 < G_IN) { e = g4 * 4; src = W_in; dst = o_in; }
  else if (g4 < G_IN + G_PAR) {
    e = (g4 - G_IN) * 4;
    int row = (int)(e >> 11), col = (int)(e & 2047);
    float4 v = make_float4(0.f, 0.f, 0.f, 0.f);
    if (row < 528) v = *(const float4*)(W_param + (int64_t)row * 2048 + col);
    bf16_t* o = o_par + e;
    o[0] = (bf16_t)v.x; o[1] = (bf16_t)v.y; o[2] = (bf16_t)v.z; o[3] = (bf16_t)v.w;
    return;
  }
  else if (g4 < G_IN + G_PAR + G_OUT) { e = (g4 - G_IN - G_PAR) * 4; src = W_out; dst = o_out; }
  else if (g4 < G_IN + G_PAR + G_OUT + G_F1) { e = (g4 - G_IN - G_PAR - G_OUT) * 4; src = W_f1; dst = o_f1; }
  else { e = (g4 - G_IN - G_PAR - G_OUT - G_F1) * 4; src = W_f2; dst = o_f2; }
  float4 v = *(const float4*)(src + e);
  bf16_t* o = dst + e;
  o[0] = (bf16_t)v.x; o[1] = (bf16_t)v.y; o[2] = (bf16_t)v.z; o[3] = (bf16_t)v.w;
}

// ---------------- rmsnorm (D=1024), fp32 in -> bf16 out ----------------
__global__ __launch_bounds__(256) void rmsnorm_k(const float* __restrict__ x,
                                                 const float* __restrict__ g,
                                                 bf16_t* __restrict__ out) {
  int row = blockIdx.x;
  int tid = threadIdx.x;
  const float4 v = *(const float4*)(x + (int64_t)row * DM + tid * 4);
  float ss = v.x * v.x + v.y * v.y + v.z * v.z + v.w * v.w;
#pragma unroll
  for (int o = 32; o; o >>= 1) ss += __shfl_xor(ss, o, 64);
  __shared__ float red[4];
  if ((tid & 63) == 0) red[tid >> 6] = ss;
  __syncthreads();
  float tot = red[0] + red[1] + red[2] + red[3];
  float sc = rsqrtf(tot * (1.0f / DM) + 1e-6f);
  const float4 gv = *(const float4*)(g + tid * 4);
  bf16_t* o = out + (int64_t)row * DM + tid * 4;
  o[0] = (bf16_t)(v.x * sc * gv.x);
  o[1] = (bf16_t)(v.y * sc * gv.y);
  o[2] = (bf16_t)(v.z * sc * gv.z);
  o[3] = (bf16_t)(v.w * sc * gv.w);
}

// ---------------- silu + fp32 -> bf16 (fallback path only) ----------------
__global__ __launch_bounds__(256) void silu_cvt(const float* __restrict__ in,
                                                bf16_t* __restrict__ out,
                                                int in_stride, int ncols) {
  int64_t e = ((int64_t)blockIdx.x * 256 + threadIdx.x) * 4;
  int row = (int)(e / ncols);
  int col = (int)(e % ncols);
  const float4 v = *(const float4*)(in + (int64_t)row * in_stride + col);
  bf16_t* o = out + e;
  o[0] = (bf16_t)(v.x / (1.f + expf(-v.x)));
  o[1] = (bf16_t)(v.y / (1.f + expf(-v.y)));
  o[2] = (bf16_t)(v.z / (1.f + expf(-v.z)));
  o[3] = (bf16_t)(v.w / (1.f + expf(-v.w)));
}

// ---------------- SSM coefficient prep (sums nparts split-K fp32 partials) --
__global__ __launch_bounds__(256) void ssm_prep(const float* __restrict__ params,
                                                const float* __restrict__ A_log,
                                                float* __restrict__ ssmp, int nparts) {
  int gid = blockIdx.x * 256 + threadIdx.x;  // 32 * 1024
  int bg = gid >> 10, t = gid & 1023;
  int b = bg >> 4, g = bg & 15;
  float acc[33];
#pragma unroll
  for (int i = 0; i < 33; ++i) acc[i] = 0.f;
  for (int p = 0; p < nparts; ++p) {
    const float* pr = params + (int64_t)p * ROWS * PPAD + (int64_t)(b * 1024 + t) * PPAD + g * 33;
#pragma unroll
    for (int i = 0; i < 33; ++i) acc[i] += pr[i];
  }
  float raw = acc[0];
  float delta = raw > 0.f ? raw + log1pf(expf(-raw)) : log1pf(expf(raw));
  float* o = ssmp + (int64_t)gid * 48;
#pragma unroll
  for (int s = 0; s < 16; ++s) {
    float A = -expf(A_log[s]);
    float dA = delta * A;
    dA = fminf(10.f, fmaxf(-10.f, dA));
    float e = expf(dA);
    float frac = (fabsf(dA) < 1e-4f) ? delta : (e - 1.f) / (A + 1e-12f);
    o[s] = dA;
    o[16 + s] = frac * acc[1 + s];
    o[32 + s] = acc[17 + s];
  }
}

// ---------------- split-K reduce (bf16 partials) + residual + rmsnorm -------
__global__ __launch_bounds__(256) void reduce_rms(const bf16_t* __restrict__ P,
                                                  const float* __restrict__ x,
                                                  const float* __restrict__ g,
                                                  float* __restrict__ xmid,
                                                  bf16_t* __restrict__ zb) {
  int row = blockIdx.x;
  int tid = threadIdx.x;
  int64_t base = (int64_t)row * DM + tid * 4;
  float4 v = *(const float4*)(x + base);
#pragma unroll
  for (int p = 0; p < 4; ++p) {
    bf16x4 pv = *(const bf16x4*)(P + (int64_t)p * ROWS * DM + base);
    v.x += (float)pv[0]; v.y += (float)pv[1]; v.z += (float)pv[2]; v.w += (float)pv[3];
  }
  *(float4*)(xmid + base) = v;
  float ss = v.x * v.x + v.y * v.y + v.z * v.z + v.w * v.w;
#pragma unroll
  for (int o = 32; o; o >>= 1) ss += __shfl_xor(ss, o, 64);
  __shared__ float red[4];
  if ((tid & 63) == 0) red[tid >> 6] = ss;
  __syncthreads();
  float tot = red[0] + red[1] + red[2] + red[3];
  float sc = rsqrtf(tot * (1.0f / DM) + 1e-6f);
  const float4 gv = *(const float4*)(g + tid * 4);
  bf16_t* o = zb + base;
  o[0] = (bf16_t)(v.x * sc * gv.x);
  o[1] = (bf16_t)(v.y * sc * gv.y);
  o[2] = (bf16_t)(v.z * sc * gv.z);
  o[3] = (bf16_t)(v.w * sc * gv.w);
}

__global__ __launch_bounds__(256) void reduce_bias(const bf16_t* __restrict__ P,
                                                   const float* __restrict__ res,
                                                   const float* __restrict__ bias,
                                                   float* __restrict__ out) {
  int64_t e = ((int64_t)blockIdx.x * 256 + threadIdx.x) * 4;
  int col = (int)(e % DM);
  float4 v = *(const float4*)(res + e);
  const float4 bv = *(const float4*)(bias + col);
  v.x += bv.x; v.y += bv.y; v.z += bv.z; v.w += bv.w;
#pragma unroll
  for (int p = 0; p < 4; ++p) {
    bf16x4 pv = *(const bf16x4*)(P + (int64_t)p * ROWS * DM + e);
    v.x += (float)pv[0]; v.y += (float)pv[1]; v.z += (float)pv[2]; v.w += (float)pv[3];
  }
  *(float4*)(out + e) = v;
}

// Ut layout: element (ch, t) at byte ch*128 + ((t*2) ^ ((ch&7)<<4))

// ---------------- Phase A: per-chunk boundary operator (MFMA) ---------------
__global__ __launch_bounds__(256) void ssm_chunk(const float* __restrict__ ssmp,
                                                 const bf16_t* __restrict__ u,
                                                 float* __restrict__ S,
                                                 float* __restrict__ Etot) {
  __shared__ __align__(16) float cf[64 * 48];
  __shared__ __align__(16) float Lb[64 * 16];
  __shared__ __align__(16) bf16_t wl[16 * 64];
  __shared__ __align__(16) bf16_t Ut[128 * 64];
  int bgc = blockIdx.x;
  int bg = bgc >> 4, c = bgc & 15;
  int b = bg >> 4, g = bg & 15;
  int t0 = c * 64;
  int tid = threadIdx.x;
  {
    const float4* src = (const float4*)(ssmp + ((int64_t)bg * 1024 + t0) * 48);
    float4* dst = (float4*)cf;
#pragma unroll
    for (int i = 0; i < 3; ++i) dst[i * 256 + tid] = src[i * 256 + tid];
  }
  {
    int lt = tid >> 4;
    int c8 = (tid & 15) * 8;
#pragma unroll
    for (int p = 0; p < 4; ++p) {
      int t = p * 16 + lt;
      bf16x8 v = *(const bf16x8*)(u + ((int64_t)(b * 1024) + t0 + t) * 2048 + g * 128 + c8);
#pragma unroll
      for (int j = 0; j < 8; ++j)
        Ut[(c8 + j) * 64 + (((t >> 3) ^ j) << 3) + (t & 7)] = v[j];
    }
  }
  __syncthreads();
  if (tid < 16) {
    float l = 0.f;
    for (int t = 0; t < 64; ++t) { l += cf[t * 48 + tid]; Lb[t * 16 + tid] = l; }
  }
  __syncthreads();
  {
    int s = tid >> 4, tb4 = (tid & 15) * 4;
    float lend = Lb[63 * 16 + s];
    bf16x4 wv;
#pragma unroll
    for (int j = 0; j < 4; ++j) {
      int t = tb4 + j;
      wv[j] = (bf16_t)(__expf(lend - Lb[t * 16 + s]) * cf[t * 48 + 16 + s]);
    }
    unsigned byo = (unsigned)(s * 128 + tb4 * 2) ^ ((unsigned)(s & 7) << 4);
    *(bf16x4*)((char*)wl + byo) = wv;
    if (tid < 16) Etot[(int64_t)bgc * 16 + tid] = __expf(Lb[63 * 16 + tid]);
  }
  __syncthreads();
  {
    int lane = tid & 63, wave = tid >> 6;
    int fr = lane & 15, kq = lane >> 4;
    f32x4 acc2[2] = {};
#pragma unroll
    for (int kk = 0; kk < 2; ++kk) {
      int kb = kk * 4 + kq;
      bf16x8 af = *(const bf16x8*)((const char*)wl +
                    ((unsigned)(fr * 128 + kb * 16) ^ ((unsigned)(fr & 7) << 4)));
#pragma unroll
      for (int q = 0; q < 2; ++q) {
        int ch = (wave * 2 + q) * 16 + fr;
        bf16x8 bfr = *(const bf16x8*)((const char*)Ut +
                       ((unsigned)(ch * 128 + kb * 16) ^ ((unsigned)(ch & 7) << 4)));
        acc2[q] = __builtin_amdgcn_mfma_f32_16x16x32_bf16(af, bfr, acc2[q], 0, 0, 0);
      }
    }
    float* Sp = S + (int64_t)bgc * 2048;
#pragma unroll
    for (int q = 0; q < 2; ++q) {
      int ch = (wave * 2 + q) * 16 + fr;
#pragma unroll
      for (int j = 0; j < 4; ++j) Sp[(kq * 4 + j) * 128 + ch] = acc2[q][j];
    }
  }
}

// ---------------- Phase B: sequential combine over 16 chunks ----------------
__global__ __launch_bounds__(256) void ssm_combine(const float* __restrict__ S,
                                                   const float* __restrict__ Etot,
                                                   float* __restrict__ H) {
  int gid = blockIdx.x * 256 + threadIdx.x;
  int bg = gid >> 11;
  int s = (gid >> 7) & 15;
  int ch = gid & 127;
  float h = 0.f;
  for (int c = 0; c < 16; ++c) {
    int bgc = bg * 16 + c;
    int64_t idx = ((int64_t)bgc * 16 + s) * 128 + ch;
    H[idx] = h;
    h = Etot[(int64_t)bgc * 16 + s] * h + S[idx];
  }
}

// ---------------- Phase C: y = tril(K)@U + ce@H, fused gate (MFMA) ----------
template <int GM>
__global__ __launch_bounds__(256) void ssm_out(const float* __restrict__ ssmp,
                                               const bf16_t* __restrict__ u,
                                               const float* __restrict__ H,
                                               const float* __restrict__ gate_f,
                                               const bf16_t* __restrict__ gate_b,
                                               int gstride,
                                               bf16_t* __restrict__ yout) {
  __shared__ __align__(16) float cf[64 * 48];
  __shared__ __align__(16) float Lb[64 * 16];
  __shared__ __align__(16) bf16_t Km[64 * 64];
  __shared__ __align__(16) bf16_t Ut[128 * 64];
  __shared__ __align__(16) bf16_t Hb[128 * 32];
  int bgc = blockIdx.x;
  int bg = bgc >> 4, c = bgc & 15;
  int b = bg >> 4, g = bg & 15;
  int t0 = c * 64;
  int tid = threadIdx.x;
  int lane = tid & 63, wave = tid >> 6;
  {
    const float4* src = (const float4*)(ssmp + ((int64_t)bg * 1024 + t0) * 48);
    float4* dst = (float4*)cf;
#pragma unroll
    for (int i = 0; i < 3; ++i) dst[i * 256 + tid] = src[i * 256 + tid];
  }
  {
    int lt = tid >> 4;
    int c8 = (tid & 15) * 8;
#pragma unroll
    for (int p = 0; p < 4; ++p) {
      int t = p * 16 + lt;
      bf16x8 v = *(const bf16x8*)(u + ((int64_t)(b * 1024) + t0 + t) * 2048 + g * 128 + c8);
#pragma unroll
      for (int j = 0; j < 8; ++j)
        Ut[(c8 + j) * 64 + (((t >> 3) ^ j) << 3) + (t & 7)] = v[j];
    }
  }
  {
    int ch = tid >> 1, h8 = (tid & 1) * 8;
    const float* Hp = H + (int64_t)bgc * 2048 + ch;
#pragma unroll
    for (int j = 0; j < 8; ++j) {
      Hb[ch * 32 + h8 + j] = (bf16_t)Hp[(h8 + j) * 128];
      Hb[ch * 32 + 16 + h8 + j] = (bf16_t)0.f;
    }
  }
  __syncthreads();
  if (tid < 16) {
    float l = 0.f;
    for (int t = 0; t < 64; ++t) { l += cf[t * 48 + tid]; Lb[t * 16 + tid] = l; }
  }
  __syncthreads();
  {
    int t = tid >> 2, tp0 = (tid & 3) * 16;
    float4 cv[4], lv[4];
#pragma unroll
    for (int i = 0; i < 4; ++i) {
      cv[i] = *(const float4*)&cf[t * 48 + 32 + i * 4];
      lv[i] = *(const float4*)&Lb[t * 16 + i * 4];
    }
    float kv[16];
#pragma unroll
    for (int i = 0; i < 16; ++i) {
      int tp = tp0 + i;
      float k = 0.f;
      if (tp <= t) {
#pragma unroll
        for (int q = 0; q < 4; ++q) {
          float4 lpv = *(const float4*)&Lb[tp * 16 + q * 4];
          float4 fbv = *(const float4*)&cf[tp * 48 + 16 + q * 4];
          k += cv[q].x * __expf(lv[q].x - lpv.x) * fbv.x
             + cv[q].y * __expf(lv[q].y - lpv.y) * fbv.y
             + cv[q].z * __expf(lv[q].z - lpv.z) * fbv.z
             + cv[q].w * __expf(lv[q].w - lpv.w) * fbv.w;
        }
      }
      kv[i] = k;
    }
    bf16x8 lo, hi;
#pragma unroll
    for (int i = 0; i < 8; ++i) { lo[i] = (bf16_t)kv[i]; hi[i] = (bf16_t)kv[8 + i]; }
    unsigned b0 = (unsigned)(t * 128 + tp0 * 2) ^ ((unsigned)(t & 7) << 4);
    unsigned b1 = (unsigned)(t * 128 + tp0 * 2 + 16) ^ ((unsigned)(t & 7) << 4);
    *(bf16x8*)((char*)Km + b0) = lo;
    *(bf16x8*)((char*)Km + b1) = hi;
  }
  __syncthreads();
  int fr = lane & 15, kq = lane >> 4;
  int trow = (wave >> 1) * 32, wc = (wave & 1) * 64;
  f32x4 acc[2][4] = {};
#pragma unroll
  for (int kk = 0; kk < 2; ++kk) {
    int kb = kk * 4 + kq;
    bf16x8 af[2];
#pragma unroll
    for (int mi = 0; mi < 2; ++mi) {
      int row = trow + mi * 16 + fr;
      af[mi] = *(const bf16x8*)((const char*)Km +
                 ((unsigned)(row * 128 + kb * 16) ^ ((unsigned)(row & 7) << 4)));
    }
#pragma unroll
    for (int ni = 0; ni < 4; ++ni) {
      int ch = wc + ni * 16 + fr;
      bf16x8 bfr = *(const bf16x8*)((const char*)Ut +
                     ((unsigned)(ch * 128 + kb * 16) ^ ((unsigned)(ch & 7) << 4)));
#pragma unroll
      for (int mi = 0; mi < 2; ++mi)
        acc[mi][ni] = __builtin_amdgcn_mfma_f32_16x16x32_bf16(af[mi], bfr, acc[mi][ni], 0, 0, 0);
    }
  }
  {
    int s0 = kq * 8;
    bf16x8 cef[2];
    if (s0 < 16) {
#pragma unroll
      for (int mi = 0; mi < 2; ++mi) {
        int t = trow + mi * 16 + fr;
#pragma unroll
        for (int j = 0; j < 8; ++j)
          cef[mi][j] = (bf16_t)(cf[t * 48 + 32 + s0 + j] * __expf(Lb[t * 16 + s0 + j]));
      }
    } else {
#pragma unroll
      for (int mi = 0; mi < 2; ++mi)
#pragma unroll
        for (int j = 0; j < 8; ++j) cef[mi][j] = (bf16_t)0.f;
    }
#pragma unroll
    for (int ni = 0; ni < 4; ++ni) {
      int ch = wc + ni * 16 + fr;
      bf16x8 bhf = *(const bf16x8*)((const char*)Hb + ch * 64 + s0 * 2);
#pragma unroll
      for (int mi = 0; mi < 2; ++mi)
        acc[mi][ni] = __builtin_amdgcn_mfma_f32_16x16x32_bf16(cef[mi], bhf, acc[mi][ni], 0, 0, 0);
    }
  }
  {
    int64_t rowbase = (int64_t)b * 1024 + t0;
    int colbase = g * 128;
#pragma unroll
    for (int mi = 0; mi < 2; ++mi) {
#pragma unroll
      for (int ni = 0; ni < 4; ++ni) {
        int col = colbase + wc + ni * 16 + fr;
#pragma unroll
        for (int j = 0; j < 4; ++j) {
          int t = trow + mi * 16 + kq * 4 + j;
          float sg;
          if (GM) {
            sg = (float)gate_b[(rowbase + t) * 2048 + col];
          } else {
            float gv = gate_f[(rowbase + t) * (int64_t)gstride + col];
            sg = gv / (1.f + __expf(-gv));
          }
          yout[(rowbase + t) * 2048 + col] = (bf16_t)(acc[mi][ni][j] * sg);
        }
      }
    }
  }
}

// ======== epilogue helper shared by both GEMM kernels ========
template <int EPI>
__device__ __forceinline__ void epi_store(float v, int64_t r, int64_t cn, int N,
                                          float* Cz, const float* bias,
                                          const float* res, bf16_t* obf,
                                          bf16_t* ogate, int z) {
  if (EPI & 1) v += bias[cn];
  if (EPI & 2) v += res[r * N + cn];
  if (EPI & 4) {
    float sv = v / (1.f + __expf(-v));
    if (cn < 2048) obf[r * 2048 + cn] = (bf16_t)sv;
    else ogate[r * 2048 + cn - 2048] = (bf16_t)sv;
  } else if (EPI & 8) {
    obf[r * N + cn] = (bf16_t)(v / (1.f + __expf(-v)));
  } else if (EPI & 16) {
    obf[(int64_t)z * ROWS * N + r * N + cn] = (bf16_t)v;
  } else {
    Cz[r * N + cn] = v;
  }
}

// ---------------- bf16 GEMM 128x128, double-buffered 2-phase (param GEMM) ---
template <int EPI>
__global__ __launch_bounds__(256) void gemm_bt(const bf16_t* __restrict__ A,
                                               const bf16_t* __restrict__ Bw,
                                               float* __restrict__ C,
                                               const float* __restrict__ bias,
                                               const float* __restrict__ res,
                                               bf16_t* __restrict__ obf,
                                               bf16_t* __restrict__ ogate,
                                               int N, int Kps) {
  __shared__ bf16_t As[2][128 * 64];
  __shared__ bf16_t Bs[2][128 * 64];
  const int tid = threadIdx.x;
  const int wave = tid >> 6;
  const int lane = tid & 63;
  const int64_t m0 = (int64_t)blockIdx.y * 128;
  const int64_t n0 = (int64_t)blockIdx.x * 128;
  const int K = Kps * gridDim.z;
  const int kbeg = blockIdx.z * Kps;
  float* Cz = C + (int64_t)blockIdx.z * ROWS * N;
  const int wm = (wave >> 1) * 64;
  const int wn = (wave & 1) * 64;
  f32x4 acc[4][4] = {};

  const int er = tid >> 3;
  const int ec = (tid * 8) & 63;
  const int fr = lane & 15;
  const int kq = (lane >> 4) * 8;

  auto stage = [&](int buf, int k0) {
#pragma unroll
    for (int i = 0; i < 4; ++i) {
      const bf16_t* ga = A + (m0 + er + i * 32) * K + k0 + ec;
      __builtin_amdgcn_global_load_lds((gvoid_t*)ga,
                                       (lvoid_t*)&As[buf][(i * 256 + wave * 64) * 8],
                                       16, 0, 0);
    }
#pragma unroll
    for (int i = 0; i < 4; ++i) {
      const bf16_t* gb = Bw + (n0 + er + i * 32) * K + k0 + ec;
      __builtin_amdgcn_global_load_lds((gvoid_t*)gb,
                                       (lvoid_t*)&Bs[buf][(i * 256 + wave * 64) * 8],
                                       16, 0, 0);
    }
  };
  auto compute = [&](int buf) {
#pragma unroll
    for (int kk = 0; kk < 2; ++kk) {
      bf16x8 af[4], bv[4];
#pragma unroll
      for (int mi = 0; mi < 4; ++mi)
        af[mi] = *reinterpret_cast<const bf16x8*>(&As[buf][(wm + mi * 16 + fr) * 64 + kk * 32 + kq]);
#pragma unroll
      for (int ni = 0; ni < 4; ++ni)
        bv[ni] = *reinterpret_cast<const bf16x8*>(&Bs[buf][(wn + ni * 16 + fr) * 64 + kk * 32 + kq]);
#pragma unroll
      for (int mi = 0; mi < 4; ++mi)
#pragma unroll
        for (int ni = 0; ni < 4; ++ni)
          acc[mi][ni] = __builtin_amdgcn_mfma_f32_16x16x32_bf16(af[mi], bv[ni], acc[mi][ni], 0, 0, 0);
    }
  };

  const int nk = Kps >> 6;  // assumed even
  stage(0, kbeg);
  asm volatile("s_waitcnt vmcnt(0)" ::: "memory");
  __builtin_amdgcn_s_barrier();
  int kc = kbeg;
  for (int t = 0; t < nk; t += 2) {
    stage(1, kc + 64);
    compute(0);
    asm volatile("s_waitcnt vmcnt(0)" ::: "memory");
    __builtin_amdgcn_s_barrier();
    if (t + 2 < nk) stage(0, kc + 128);
    compute(1);
    asm volatile("s_waitcnt vmcnt(0)" ::: "memory");
    __builtin_amdgcn_s_barrier();
    kc += 128;
  }

  const int crow = (lane >> 4) * 4;
  const int ccol = lane & 15;
#pragma unroll
  for (int mi = 0; mi < 4; ++mi)
#pragma unroll
    for (int ni = 0; ni < 4; ++ni)
#pragma unroll
      for (int j = 0; j < 4; ++j)
        epi_store<EPI>(acc[mi][ni][j], m0 + wm + mi * 16 + crow + j,
                       n0 + wn + ni * 16 + ccol, N, Cz, bias, res, obf, ogate,
                       blockIdx.z);
}

// ---------------- bf16 GEMM 128x256, 8-wave, depth-2 counted-vmcnt pipeline --
// T3+T4 structure: ds_read all frags -> lgkmcnt(0)+barrier -> restage read buf
// 2 K-tiles ahead -> MFMA under setprio -> vmcnt(6) (never 0 mid-loop)+barrier.
// T2 swizzle: LDS byte col ^= (row&7)<<4, applied on global SOURCE (linear LDS
// dest per gload_lds semantics) and on ds_read address.
template <int EPI>
__global__ __launch_bounds__(512, 2) void gemm_big(const bf16_t* __restrict__ A,
                                                   const bf16_t* __restrict__ Bw,
                                                   float* __restrict__ C,
                                                   const float* __restrict__ bias,
                                                   const float* __restrict__ res,
                                                   bf16_t* __restrict__ obf,
                                                   bf16_t* __restrict__ ogate,
                                                   int N, int Kps) {
  __shared__ bf16_t As[2][128 * 64];
  __shared__ bf16_t Bs[2][256 * 64];
  const int tid = threadIdx.x;
  const int wave = tid >> 6;
  const int lane = tid & 63;
  const int64_t m0 = (int64_t)blockIdx.y * 128;
  const int64_t n0 = (int64_t)blockIdx.x * 256;
  const int K = Kps * gridDim.z;
  const int kbeg = blockIdx.z * Kps;
  float* Cz = C + (int64_t)blockIdx.z * ROWS * N;
  const int wm = (wave >> 2) * 64;   // 2 M-wave rows
  const int wc = (wave & 3) * 64;    // 4 N-wave cols
  const int fr = lane & 15;
  const int kq16 = (lane >> 4) * 16;  // byte col of k-quad
  const int er = tid >> 3;                              // staging row 0..63
  const int ec_sw = ((tid & 7) * 8) ^ ((er & 7) << 3);  // swizzled src col (elems)
  f32x4 acc[4][4] = {};

  auto stage = [&](int buf, int k0) {
#pragma unroll
    for (int i = 0; i < 2; ++i) {
      const bf16_t* ga = A + (m0 + er + i * 64) * K + k0 + ec_sw;
      __builtin_amdgcn_global_load_lds((gvoid_t*)ga,
          (lvoid_t*)((char*)&As[buf][0] + i * 8192 + wave * 1024), 16, 0, 0);
    }
#pragma unroll
    for (int i = 0; i < 4; ++i) {
      const bf16_t* gb = Bw + (n0 + er + i * 64) * K + k0 + ec_sw;
      __builtin_amdgcn_global_load_lds((gvoid_t*)gb,
          (lvoid_t*)((char*)&Bs[buf][0] + i * 8192 + wave * 1024), 16, 0, 0);
    }
  };

  const int nk = Kps >> 6;
  stage(0, kbeg);
  if (nk > 1) {
    stage(1, kbeg + 64);
    asm volatile("s_waitcnt vmcnt(6)" ::: "memory");
  } else {
    asm volatile("s_waitcnt vmcnt(0)" ::: "memory");
  }
  __builtin_amdgcn_s_barrier();
  __builtin_amdgcn_sched_barrier(0);

  for (int t = 0; t < nk; ++t) {
    const int buf = t & 1;
    // ds-read all fragments of buf into registers (swizzled)
    bf16x8 af[2][4], bf[2][4];
#pragma unroll
    for (int kk = 0; kk < 2; ++kk) {
#pragma unroll
      for (int mi = 0; mi < 4; ++mi) {
        int r = wm + mi * 16 + fr;
        af[kk][mi] = *(const bf16x8*)((const char*)&As[buf][0] + r * 128 +
                       ((kk * 64 + kq16) ^ ((r & 7) << 4)));
      }
#pragma unroll
      for (int ni = 0; ni < 4; ++ni) {
        int r = wc + ni * 16 + fr;
        bf[kk][ni] = *(const bf16x8*)((const char*)&Bs[buf][0] + r * 128 +
                       ((kk * 64 + kq16) ^ ((r & 7) << 4)));
      }
    }
    asm volatile("s_waitcnt lgkmcnt(0)" ::: "memory");
    __builtin_amdgcn_sched_barrier(0);
    __builtin_amdgcn_s_barrier();          // all waves done reading buf
    __builtin_amdgcn_sched_barrier(0);
    if (t + 2 < nk) stage(buf, kbeg + (t + 2) * 64);  // overwrite buf, 2 ahead
    __builtin_amdgcn_s_setprio(1);
#pragma unroll
    for (int kk = 0; kk < 2; ++kk)
#pragma unroll
      for (int mi = 0; mi < 4; ++mi)
#pragma unroll
        for (int ni = 0; ni < 4; ++ni)
          acc[mi][ni] = __builtin_amdgcn_mfma_f32_16x16x32_bf16(
              af[kk][mi], bf[kk][ni], acc[mi][ni], 0, 0, 0);
    __builtin_amdgcn_s_setprio(0);
    if (t + 1 < nk) {
      if (t + 2 < nk) asm volatile("s_waitcnt vmcnt(6)" ::: "memory");
      else            asm volatile("s_waitcnt vmcnt(0)" ::: "memory");
      __builtin_amdgcn_s_barrier();        // buf^1 staged & landed for t+1
      __builtin_amdgcn_sched_barrier(0);
    }
  }

  const int crow = (lane >> 4) * 4;
  const int ccol = lane & 15;
#pragma unroll
  for (int mi = 0; mi < 4; ++mi)
#pragma unroll
    for (int ni = 0; ni < 4; ++ni)
#pragma unroll
      for (int j = 0; j < 4; ++j)
        epi_store<EPI>(acc[mi][ni][j], m0 + wm + mi * 16 + crow + j,
                       n0 + wc + ni * 16 + ccol, N, Cz, bias, res, obf, ogate,
                       blockIdx.z);
}

extern "C" void kernel_launch(void* const* d_in, const int* in_sizes, int n_in,
                              void* d_out, int out_size, void* d_ws, size_t ws_size,
                              hipStream_t stream) {
  const float* x       = (const float*)d_in[0];
  const float* A_log   = (const float*)d_in[1];
  const float* g1      = (const float*)d_in[2];
  const float* g2      = (const float*)d_in[3];
  const float* W_in    = (const float*)d_in[4];
  const float* W_param = (const float*)d_in[5];
  const float* W_out   = (const float*)d_in[6];
  const float* W_ffn1  = (const float*)d_in[7];
  const float* b_ffn1  = (const float*)d_in[8];
  const float* W_ffn2  = (const float*)d_in[9];
  const float* b_ffn2  = (const float*)d_in[10];
  float* out = (float*)d_out;

  char* ws = (char*)d_ws;
  size_t off = 0;
  auto alloc = [&](size_t bytes) {
    char* p = ws + off;
    off += (bytes + 255) & ~(size_t)255;
    return p;
  };
  bf16_t* wb_in  = (bf16_t*)alloc(4096ull * 1024 * 2);
  bf16_t* wb_par = (bf16_t*)alloc((size_t)PPAD * 2048 * 2);
  bf16_t* wb_out = (bf16_t*)alloc(1024ull * 2048 * 2);
  bf16_t* wb_f1  = (bf16_t*)alloc(4096ull * 1024 * 2);
  bf16_t* wb_f2  = (bf16_t*)alloc(1024ull * 4096 * 2);
  bf16_t* zbuf   = (bf16_t*)alloc(2048ull * 1024 * 2);   // z, later h2
  float*  xzg    = (float*)alloc(2048ull * 4096 * 4);    // sgate bf16 (sk) / fp32 (fallback)
  float*  params = (float*)alloc(2048ull * PPAD * 4);    // fallback only; S/Etot overlay
  float*  ssmp   = (float*)alloc(32ull * 1024 * 48 * 4);
  float*  xmid   = (float*)alloc(2048ull * 1024 * 4);
  char*   regA   = alloc(2048ull * 4096 * 2);            // 16MB union
  bf16_t* xz_act = (bf16_t*)regA;
  bf16_t* y_b16  = (bf16_t*)(regA + 2048ull * 2048 * 2);
  bf16_t* f_act  = (bf16_t*)regA;
  bf16_t* sgate  = (bf16_t*)xzg;                         // [2048][2048] bf16 (sk)
  float* Sbuf = params;
  float* Etot = params + 32ull * 16 * 16 * 128;
  float* Hbuf = xmid;
  float*  psum = (float*)alloc(4ull * ROWS * 1024 * 4);  // 33.6MB fp32 param partials
  bf16_t* pb16 = (bf16_t*)psum;                          // bf16 partials overlay
  const bool sk = (off <= ws_size);

  dim3 b256(256), b512(512);
  cvt_all<<<15616, b256, 0, stream>>>(W_in, W_param, W_out, W_ffn1, W_ffn2,
                                      wb_in, wb_par, wb_out, wb_f1, wb_f2);
  rmsnorm_k<<<2048, b256, 0, stream>>>(x, g1, zbuf);

  if (sk) {
    // xz|gate = z @ W_in^T, fused: silu(xz)->xz_act, silu(gate)->sgate (bf16)
    gemm_big<4><<<dim3(16, 16), b512, 0, stream>>>(zbuf, wb_in, psum, nullptr, nullptr, xz_act, sgate, 4096, 1024);
    gemm_bt<0><<<dim3(PPAD / 128, 16, 4), b256, 0, stream>>>(xz_act, wb_par, psum, nullptr, nullptr, nullptr, nullptr, PPAD, 512);
    ssm_prep<<<128, b256, 0, stream>>>(psum, A_log, ssmp, 4);
    ssm_chunk<<<512, b256, 0, stream>>>(ssmp, xz_act, Sbuf, Etot);
    ssm_combine<<<256, b256, 0, stream>>>(Sbuf, Etot, Hbuf);
    ssm_out<1><<<512, b256, 0, stream>>>(ssmp, xz_act, Hbuf, nullptr, sgate, 2048, y_b16);
    // xmid = x + y @ W_out^T (SK=4, bf16 partials) fused reduce+rmsnorm
    gemm_big<16><<<dim3(4, 16, 4), b512, 0, stream>>>(y_b16, wb_out, psum, nullptr, nullptr, pb16, nullptr, 1024, 512);
    reduce_rms<<<2048, b256, 0, stream>>>(pb16, x, g2, xmid, zbuf);
    // ffn1 + bias + silu -> f_act bf16 (fused)
    gemm_big<9><<<dim3(16, 16), b512, 0, stream>>>(zbuf, wb_f1, psum, b_ffn1, nullptr, f_act, nullptr, 4096, 1024);
    // out = xmid + b_ffn2 + f_act @ W_ffn2^T (SK=4, bf16 partials)
    gemm_big<16><<<dim3(4, 16, 4), b512, 0, stream>>>(f_act, wb_f2, psum, nullptr, nullptr, pb16, nullptr, 1024, 1024);
    reduce_bias<<<2048, b256, 0, stream>>>(pb16, xmid, b_ffn2, out);
  } else {
    gemm_bt<0><<<dim3(32, 16), b256, 0, stream>>>(zbuf, wb_in, xzg, nullptr, nullptr, nullptr, nullptr, 4096, 1024);
    silu_cvt<<<4096, b256, 0, stream>>>(xzg, xz_act, 4096, 2048);
    gemm_bt<0><<<dim3(PPAD / 128, 16), b256, 0, stream>>>(xz_act, wb_par, params, nullptr, nullptr, nullptr, nullptr, PPAD, 2048);
    ssm_prep<<<128, b256, 0, stream>>>(params, A_log, ssmp, 1);
    ssm_chunk<<<512, b256, 0, stream>>>(ssmp, xz_act, Sbuf, Etot);
    ssm_combine<<<256, b256, 0, stream>>>(Sbuf, Etot, Hbuf);
    ssm_out<0><<<512, b256, 0, stream>>>(ssmp, xz_act, Hbuf, xzg + 2048, nullptr, 4096, y_b16);
    gemm_bt<2><<<dim3(8, 16), b256, 0, stream>>>(y_b16, wb_out, xmid, nullptr, x, nullptr, nullptr, 1024, 2048);
    rmsnorm_k<<<2048, b256, 0, stream>>>(xmid, g2, zbuf);
    gemm_bt<1><<<dim3(32, 16), b256, 0, stream>>>(zbuf, wb_f1, xzg, b_ffn1, nullptr, nullptr, nullptr, 4096, 1024);
    silu_cvt<<<8192, b256, 0, stream>>>(xzg, f_act, 4096, 4096);
    gemm_bt<3><<<dim3(8, 16), b256, 0, stream>>>(f_act, wb_f2, out, b_ffn2, xmid, nullptr, nullptr, 1024, 4096);
  }
}

// Round 7
// 188.582 us; speedup vs baseline: 5.3618x; 1.0296x over previous
//
#include <hip/hip_runtime.h>
#include <hip/hip_bf16.h>
#include <stdint.h>

// MambaBlock: B=2, T=1024, D_MODEL=1024, D_INNER=2048, GROUPS=16, D_STATE=16
#define ROWS 2048      // B*T
#define DM   1024
#define DI   2048
#define PPAD 640       // 528 param rows padded to 5*128

typedef __bf16 bf16_t;
typedef __attribute__((ext_vector_type(8))) __bf16 bf16x8;
typedef __attribute__((ext_vector_type(4))) __bf16 bf16x4;
typedef __attribute__((ext_vector_type(4))) float f32x4;
typedef __attribute__((address_space(1))) void gvoid_t;
typedef __attribute__((address_space(3))) void lvoid_t;

// ---------------- fused: all weights fp32->bf16 + first rmsnorm -------------
#define G_IN   1048576ll
#define G_PAR  327680ll
#define G_OUT  524288ll
#define G_F1   1048576ll
#define G_F2   1048576ll
#define CVT_BLOCKS 15616
__global__ __launch_bounds__(256) void prep0(const float* __restrict__ W_in,
                                             const float* __restrict__ W_param,
                                             const float* __restrict__ W_out,
                                             const float* __restrict__ W_f1,
                                             const float* __restrict__ W_f2,
                                             bf16_t* o_in, bf16_t* o_par,
                                             bf16_t* o_out, bf16_t* o_f1,
                                             bf16_t* o_f2,
                                             const float* __restrict__ x,
                                             const float* __restrict__ g1,
                                             bf16_t* __restrict__ zb) {
  if (blockIdx.x >= CVT_BLOCKS) {  // rmsnorm part
    int row = blockIdx.x - CVT_BLOCKS;
    int tid = threadIdx.x;
    const float4 v = *(const float4*)(x + (int64_t)row * DM + tid * 4);
    float ss = v.x * v.x + v.y * v.y + v.z * v.z + v.w * v.w;
#pragma unroll
    for (int o = 32; o; o >>= 1) ss += __shfl_xor(ss, o, 64);
    __shared__ float red[4];
    if ((tid & 63) == 0) red[tid >> 6] = ss;
    __syncthreads();
    float tot = red[0] + red[1] + red[2] + red[3];
    float sc = rsqrtf(tot * (1.0f / DM) + 1e-6f);
    const float4 gv = *(const float4*)(g1 + tid * 4);
    bf16_t* o = zb + (int64_t)row * DM + tid * 4;
    o[0] = (bf16_t)(v.x * sc * gv.x);
    o[1] = (bf16_t)(v.y * sc * gv.y);
    o[2] = (bf16_t)(v.z * sc * gv.z);
    o[3] = (bf16_t)(v.w * sc * gv.w);
    return;
  }
  int64_t g4 = (int64_t)blockIdx.x * 256 + threadIdx.x;
  const float* src; bf16_t* dst; int64_t e;
  if (g4 < G_IN) { e = g4 * 4; src = W_in; dst = o_in; }
  else if (g4 < G_IN + G_PAR) {
    e = (g4 - G_IN) * 4;
    int row = (int)(e >> 11), col = (int)(e & 2047);
    float4 v = make_float4(0.f, 0.f, 0.f, 0.f);
    if (row < 528) v = *(const float4*)(W_param + (int64_t)row * 2048 + col);
    bf16_t* o = o_par + e;
    o[0] = (bf16_t)v.x; o[1] = (bf16_t)v.y; o[2] = (bf16_t)v.z; o[3] = (bf16_t)v.w;
    return;
  }
  else if (g4 < G_IN + G_PAR + G_OUT) { e = (g4 - G_IN - G_PAR) * 4; src = W_out; dst = o_out; }
  else if (g4 < G_IN + G_PAR + G_OUT + G_F1) { e = (g4 - G_IN - G_PAR - G_OUT) * 4; src = W_f1; dst = o_f1; }
  else { e = (g4 - G_IN - G_PAR - G_OUT - G_F1) * 4; src = W_f2; dst = o_f2; }
  float4 v = *(const float4*)(src + e);
  bf16_t* o = dst + e;
  o[0] = (bf16_t)v.x; o[1] = (bf16_t)v.y; o[2] = (bf16_t)v.z; o[3] = (bf16_t)v.w;
}

// ---------------- rmsnorm (D=1024), fp32 in -> bf16 out (fallback mid) ------
__global__ __launch_bounds__(256) void rmsnorm_k(const float* __restrict__ x,
                                                 const float* __restrict__ g,
                                                 bf16_t* __restrict__ out) {
  int row = blockIdx.x;
  int tid = threadIdx.x;
  const float4 v = *(const float4*)(x + (int64_t)row * DM + tid * 4);
  float ss = v.x * v.x + v.y * v.y + v.z * v.z + v.w * v.w;
#pragma unroll
  for (int o = 32; o; o >>= 1) ss += __shfl_xor(ss, o, 64);
  __shared__ float red[4];
  if ((tid & 63) == 0) red[tid >> 6] = ss;
  __syncthreads();
  float tot = red[0] + red[1] + red[2] + red[3];
  float sc = rsqrtf(tot * (1.0f / DM) + 1e-6f);
  const float4 gv = *(const float4*)(g + tid * 4);
  bf16_t* o = out + (int64_t)row * DM + tid * 4;
  o[0] = (bf16_t)(v.x * sc * gv.x);
  o[1] = (bf16_t)(v.y * sc * gv.y);
  o[2] = (bf16_t)(v.z * sc * gv.z);
  o[3] = (bf16_t)(v.w * sc * gv.w);
}

// ---------------- silu + fp32 -> bf16 (fallback path only) ----------------
__global__ __launch_bounds__(256) void silu_cvt(const float* __restrict__ in,
                                                bf16_t* __restrict__ out,
                                                int in_stride, int ncols) {
  int64_t e = ((int64_t)blockIdx.x * 256 + threadIdx.x) * 4;
  int row = (int)(e / ncols);
  int col = (int)(e % ncols);
  const float4 v = *(const float4*)(in + (int64_t)row * in_stride + col);
  bf16_t* o = out + e;
  o[0] = (bf16_t)(v.x / (1.f + expf(-v.x)));
  o[1] = (bf16_t)(v.y / (1.f + expf(-v.y)));
  o[2] = (bf16_t)(v.z / (1.f + expf(-v.z)));
  o[3] = (bf16_t)(v.w / (1.f + expf(-v.w)));
}

// ---------------- SSM coefficient prep (sums nparts split-K partials) -------
template <typename T>
__global__ __launch_bounds__(256) void ssm_prep(const T* __restrict__ params,
                                                const float* __restrict__ A_log,
                                                float* __restrict__ ssmp, int nparts) {
  int gid = blockIdx.x * 256 + threadIdx.x;  // 32 * 1024
  int bg = gid >> 10, t = gid & 1023;
  int b = bg >> 4, g = bg & 15;
  float acc[33];
#pragma unroll
  for (int i = 0; i < 33; ++i) acc[i] = 0.f;
  for (int p = 0; p < nparts; ++p) {
    const T* pr = params + (int64_t)p * ROWS * PPAD + (int64_t)(b * 1024 + t) * PPAD + g * 33;
#pragma unroll
    for (int i = 0; i < 33; ++i) acc[i] += (float)pr[i];
  }
  float raw = acc[0];
  float delta = raw > 0.f ? raw + log1pf(expf(-raw)) : log1pf(expf(raw));
  float* o = ssmp + (int64_t)gid * 48;
#pragma unroll
  for (int s = 0; s < 16; ++s) {
    float A = -expf(A_log[s]);
    float dA = delta * A;
    dA = fminf(10.f, fmaxf(-10.f, dA));
    float e = expf(dA);
    float frac = (fabsf(dA) < 1e-4f) ? delta : (e - 1.f) / (A + 1e-12f);
    o[s] = dA;
    o[16 + s] = frac * acc[1 + s];
    o[32 + s] = acc[17 + s];
  }
}

// ---------------- split-K reduce (bf16 partials) + residual + rmsnorm -------
__global__ __launch_bounds__(256) void reduce_rms(const bf16_t* __restrict__ P,
                                                  const float* __restrict__ x,
                                                  const float* __restrict__ g,
                                                  float* __restrict__ xmid,
                                                  bf16_t* __restrict__ zb) {
  int row = blockIdx.x;
  int tid = threadIdx.x;
  int64_t base = (int64_t)row * DM + tid * 4;
  float4 v = *(const float4*)(x + base);
#pragma unroll
  for (int p = 0; p < 4; ++p) {
    bf16x4 pv = *(const bf16x4*)(P + (int64_t)p * ROWS * DM + base);
    v.x += (float)pv[0]; v.y += (float)pv[1]; v.z += (float)pv[2]; v.w += (float)pv[3];
  }
  *(float4*)(xmid + base) = v;
  float ss = v.x * v.x + v.y * v.y + v.z * v.z + v.w * v.w;
#pragma unroll
  for (int o = 32; o; o >>= 1) ss += __shfl_xor(ss, o, 64);
  __shared__ float red[4];
  if ((tid & 63) == 0) red[tid >> 6] = ss;
  __syncthreads();
  float tot = red[0] + red[1] + red[2] + red[3];
  float sc = rsqrtf(tot * (1.0f / DM) + 1e-6f);
  const float4 gv = *(const float4*)(g + tid * 4);
  bf16_t* o = zb + base;
  o[0] = (bf16_t)(v.x * sc * gv.x);
  o[1] = (bf16_t)(v.y * sc * gv.y);
  o[2] = (bf16_t)(v.z * sc * gv.z);
  o[3] = (bf16_t)(v.w * sc * gv.w);
}

__global__ __launch_bounds__(256) void reduce_bias(const bf16_t* __restrict__ P,
                                                   const float* __restrict__ res,
                                                   const float* __restrict__ bias,
                                                   float* __restrict__ out) {
  int64_t e = ((int64_t)blockIdx.x * 256 + threadIdx.x) * 4;
  int col = (int)(e % DM);
  float4 v = *(const float4*)(res + e);
  const float4 bv = *(const float4*)(bias + col);
  v.x += bv.x; v.y += bv.y; v.z += bv.z; v.w += bv.w;
#pragma unroll
  for (int p = 0; p < 4; ++p) {
    bf16x4 pv = *(const bf16x4*)(P + (int64_t)p * ROWS * DM + e);
    v.x += (float)pv[0]; v.y += (float)pv[1]; v.z += (float)pv[2]; v.w += (float)pv[3];
  }
  *(float4*)(out + e) = v;
}

// Ut layout: element (ch, t) at byte ch*128 + ((t*2) ^ ((ch&7)<<4))

// ---------------- Phase A: per-chunk boundary operator (MFMA) ---------------
__global__ __launch_bounds__(256) void ssm_chunk(const float* __restrict__ ssmp,
                                                 const bf16_t* __restrict__ u,
                                                 float* __restrict__ S,
                                                 float* __restrict__ Etot) {
  __shared__ __align__(16) float cf[64 * 48];
  __shared__ __align__(16) float Lb[64 * 16];
  __shared__ __align__(16) bf16_t wl[16 * 64];
  __shared__ __align__(16) bf16_t Ut[128 * 64];
  int bgc = blockIdx.x;
  int bg = bgc >> 4, c = bgc & 15;
  int b = bg >> 4, g = bg & 15;
  int t0 = c * 64;
  int tid = threadIdx.x;
  {
    const float4* src = (const float4*)(ssmp + ((int64_t)bg * 1024 + t0) * 48);
    float4* dst = (float4*)cf;
#pragma unroll
    for (int i = 0; i < 3; ++i) dst[i * 256 + tid] = src[i * 256 + tid];
  }
  {
    int lt = tid >> 4;
    int c8 = (tid & 15) * 8;
#pragma unroll
    for (int p = 0; p < 4; ++p) {
      int t = p * 16 + lt;
      bf16x8 v = *(const bf16x8*)(u + ((int64_t)(b * 1024) + t0 + t) * 2048 + g * 128 + c8);
#pragma unroll
      for (int j = 0; j < 8; ++j)
        Ut[(c8 + j) * 64 + (((t >> 3) ^ j) << 3) + (t & 7)] = v[j];
    }
  }
  __syncthreads();
  if (tid < 16) {
    float l = 0.f;
    for (int t = 0; t < 64; ++t) { l += cf[t * 48 + tid]; Lb[t * 16 + tid] = l; }
  }
  __syncthreads();
  {
    int s = tid >> 4, tb4 = (tid & 15) * 4;
    float lend = Lb[63 * 16 + s];
    bf16x4 wv;
#pragma unroll
    for (int j = 0; j < 4; ++j) {
      int t = tb4 + j;
      wv[j] = (bf16_t)(__expf(lend - Lb[t * 16 + s]) * cf[t * 48 + 16 + s]);
    }
    unsigned byo = (unsigned)(s * 128 + tb4 * 2) ^ ((unsigned)(s & 7) << 4);
    *(bf16x4*)((char*)wl + byo) = wv;
    if (tid < 16) Etot[(int64_t)bgc * 16 + tid] = __expf(Lb[63 * 16 + tid]);
  }
  __syncthreads();
  {
    int lane = tid & 63, wave = tid >> 6;
    int fr = lane & 15, kq = lane >> 4;
    f32x4 acc2[2] = {};
#pragma unroll
    for (int kk = 0; kk < 2; ++kk) {
      int kb = kk * 4 + kq;
      bf16x8 af = *(const bf16x8*)((const char*)wl +
                    ((unsigned)(fr * 128 + kb * 16) ^ ((unsigned)(fr & 7) << 4)));
#pragma unroll
      for (int q = 0; q < 2; ++q) {
        int ch = (wave * 2 + q) * 16 + fr;
        bf16x8 bfr = *(const bf16x8*)((const char*)Ut +
                       ((unsigned)(ch * 128 + kb * 16) ^ ((unsigned)(ch & 7) << 4)));
        acc2[q] = __builtin_amdgcn_mfma_f32_16x16x32_bf16(af, bfr, acc2[q], 0, 0, 0);
      }
    }
    float* Sp = S + (int64_t)bgc * 2048;
#pragma unroll
    for (int q = 0; q < 2; ++q) {
      int ch = (wave * 2 + q) * 16 + fr;
#pragma unroll
      for (int j = 0; j < 4; ++j) Sp[(kq * 4 + j) * 128 + ch] = acc2[q][j];
    }
  }
}

// ---------------- Phase B: sequential combine over 16 chunks ----------------
__global__ __launch_bounds__(256) void ssm_combine(const float* __restrict__ S,
                                                   const float* __restrict__ Etot,
                                                   float* __restrict__ H) {
  int gid = blockIdx.x * 256 + threadIdx.x;
  int bg = gid >> 11;
  int s = (gid >> 7) & 15;
  int ch = gid & 127;
  float h = 0.f;
  for (int c = 0; c < 16; ++c) {
    int bgc = bg * 16 + c;
    int64_t idx = ((int64_t)bgc * 16 + s) * 128 + ch;
    H[idx] = h;
    h = Etot[(int64_t)bgc * 16 + s] * h + S[idx];
  }
}

// ---------------- Phase C: y = tril(K)@U + ce@H, fused gate (MFMA) ----------
template <int GM>
__global__ __launch_bounds__(256) void ssm_out(const float* __restrict__ ssmp,
                                               const bf16_t* __restrict__ u,
                                               const float* __restrict__ H,
                                               const float* __restrict__ gate_f,
                                               const bf16_t* __restrict__ gate_b,
                                               int gstride,
                                               bf16_t* __restrict__ yout) {
  __shared__ __align__(16) float cf[64 * 48];
  __shared__ __align__(16) float Lb[64 * 16];
  __shared__ __align__(16) bf16_t Km[64 * 64];
  __shared__ __align__(16) bf16_t Ut[128 * 64];
  __shared__ __align__(16) bf16_t Hb[128 * 32];
  int bgc = blockIdx.x;
  int bg = bgc >> 4, c = bgc & 15;
  int b = bg >> 4, g = bg & 15;
  int t0 = c * 64;
  int tid = threadIdx.x;
  int lane = tid & 63, wave = tid >> 6;
  {
    const float4* src = (const float4*)(ssmp + ((int64_t)bg * 1024 + t0) * 48);
    float4* dst = (float4*)cf;
#pragma unroll
    for (int i = 0; i < 3; ++i) dst[i * 256 + tid] = src[i * 256 + tid];
  }
  {
    int lt = tid >> 4;
    int c8 = (tid & 15) * 8;
#pragma unroll
    for (int p = 0; p < 4; ++p) {
      int t = p * 16 + lt;
      bf16x8 v = *(const bf16x8*)(u + ((int64_t)(b * 1024) + t0 + t) * 2048 + g * 128 + c8);
#pragma unroll
      for (int j = 0; j < 8; ++j)
        Ut[(c8 + j) * 64 + (((t >> 3) ^ j) << 3) + (t & 7)] = v[j];
    }
  }
  {
    int ch = tid >> 1, h8 = (tid & 1) * 8;
    const float* Hp = H + (int64_t)bgc * 2048 + ch;
#pragma unroll
    for (int j = 0; j < 8; ++j) {
      Hb[ch * 32 + h8 + j] = (bf16_t)Hp[(h8 + j) * 128];
      Hb[ch * 32 + 16 + h8 + j] = (bf16_t)0.f;
    }
  }
  __syncthreads();
  if (tid < 16) {
    float l = 0.f;
    for (int t = 0; t < 64; ++t) { l += cf[t * 48 + tid]; Lb[t * 16 + tid] = l; }
  }
  __syncthreads();
  {
    int t = tid >> 2, tp0 = (tid & 3) * 16;
    float4 cv[4], lv[4];
#pragma unroll
    for (int i = 0; i < 4; ++i) {
      cv[i] = *(const float4*)&cf[t * 48 + 32 + i * 4];
      lv[i] = *(const float4*)&Lb[t * 16 + i * 4];
    }
    float kv[16];
#pragma unroll
    for (int i = 0; i < 16; ++i) {
      int tp = tp0 + i;
      float k = 0.f;
      if (tp <= t) {
#pragma unroll
        for (int q = 0; q < 4; ++q) {
          float4 lpv = *(const float4*)&Lb[tp * 16 + q * 4];
          float4 fbv = *(const float4*)&cf[tp * 48 + 16 + q * 4];
          k += cv[q].x * __expf(lv[q].x - lpv.x) * fbv.x
             + cv[q].y * __expf(lv[q].y - lpv.y) * fbv.y
             + cv[q].z * __expf(lv[q].z - lpv.z) * fbv.z
             + cv[q].w * __expf(lv[q].w - lpv.w) * fbv.w;
        }
      }
      kv[i] = k;
    }
    bf16x8 lo, hi;
#pragma unroll
    for (int i = 0; i < 8; ++i) { lo[i] = (bf16_t)kv[i]; hi[i] = (bf16_t)kv[8 + i]; }
    unsigned b0 = (unsigned)(t * 128 + tp0 * 2) ^ ((unsigned)(t & 7) << 4);
    unsigned b1 = (unsigned)(t * 128 + tp0 * 2 + 16) ^ ((unsigned)(t & 7) << 4);
    *(bf16x8*)((char*)Km + b0) = lo;
    *(bf16x8*)((char*)Km + b1) = hi;
  }
  __syncthreads();
  int fr = lane & 15, kq = lane >> 4;
  int trow = (wave >> 1) * 32, wc = (wave & 1) * 64;
  f32x4 acc[2][4] = {};
#pragma unroll
  for (int kk = 0; kk < 2; ++kk) {
    int kb = kk * 4 + kq;
    bf16x8 af[2];
#pragma unroll
    for (int mi = 0; mi < 2; ++mi) {
      int row = trow + mi * 16 + fr;
      af[mi] = *(const bf16x8*)((const char*)Km +
                 ((unsigned)(row * 128 + kb * 16) ^ ((unsigned)(row & 7) << 4)));
    }
#pragma unroll
    for (int ni = 0; ni < 4; ++ni) {
      int ch = wc + ni * 16 + fr;
      bf16x8 bfr = *(const bf16x8*)((const char*)Ut +
                     ((unsigned)(ch * 128 + kb * 16) ^ ((unsigned)(ch & 7) << 4)));
#pragma unroll
      for (int mi = 0; mi < 2; ++mi)
        acc[mi][ni] = __builtin_amdgcn_mfma_f32_16x16x32_bf16(af[mi], bfr, acc[mi][ni], 0, 0, 0);
    }
  }
  {
    int s0 = kq * 8;
    bf16x8 cef[2];
    if (s0 < 16) {
#pragma unroll
      for (int mi = 0; mi < 2; ++mi) {
        int t = trow + mi * 16 + fr;
#pragma unroll
        for (int j = 0; j < 8; ++j)
          cef[mi][j] = (bf16_t)(cf[t * 48 + 32 + s0 + j] * __expf(Lb[t * 16 + s0 + j]));
      }
    } else {
#pragma unroll
      for (int mi = 0; mi < 2; ++mi)
#pragma unroll
        for (int j = 0; j < 8; ++j) cef[mi][j] = (bf16_t)0.f;
    }
#pragma unroll
    for (int ni = 0; ni < 4; ++ni) {
      int ch = wc + ni * 16 + fr;
      bf16x8 bhf = *(const bf16x8*)((const char*)Hb + ch * 64 + s0 * 2);
#pragma unroll
      for (int mi = 0; mi < 2; ++mi)
        acc[mi][ni] = __builtin_amdgcn_mfma_f32_16x16x32_bf16(cef[mi], bhf, acc[mi][ni], 0, 0, 0);
    }
  }
  {
    int64_t rowbase = (int64_t)b * 1024 + t0;
    int colbase = g * 128;
#pragma unroll
    for (int mi = 0; mi < 2; ++mi) {
#pragma unroll
      for (int ni = 0; ni < 4; ++ni) {
        int col = colbase + wc + ni * 16 + fr;
#pragma unroll
        for (int j = 0; j < 4; ++j) {
          int t = trow + mi * 16 + kq * 4 + j;
          float sg;
          if (GM) {
            sg = (float)gate_b[(rowbase + t) * 2048 + col];
          } else {
            float gv = gate_f[(rowbase + t) * (int64_t)gstride + col];
            sg = gv / (1.f + __expf(-gv));
          }
          yout[(rowbase + t) * 2048 + col] = (bf16_t)(acc[mi][ni][j] * sg);
        }
      }
    }
  }
}

// ======== epilogue helper shared by both GEMM kernels ========
template <int EPI>
__device__ __forceinline__ void epi_store(float v, int64_t r, int64_t cn, int N,
                                          float* Cz, const float* bias,
                                          const float* res, bf16_t* obf,
                                          bf16_t* ogate, int z) {
  if (EPI & 1) v += bias[cn];
  if (EPI & 2) v += res[r * N + cn];
  if (EPI & 4) {
    float sv = v / (1.f + __expf(-v));
    if (cn < 2048) obf[r * 2048 + cn] = (bf16_t)sv;
    else ogate[r * 2048 + cn - 2048] = (bf16_t)sv;
  } else if (EPI & 8) {
    obf[r * N + cn] = (bf16_t)(v / (1.f + __expf(-v)));
  } else if (EPI & 16) {
    obf[(int64_t)z * ROWS * N + r * N + cn] = (bf16_t)v;
  } else {
    Cz[r * N + cn] = v;
  }
}

// bijective XCD swizzle over flattened grid (identity if nwg%8 != 0)
__device__ __forceinline__ void xcd_swz(int& bx, int& by, int& bz) {
  int gx = gridDim.x, gy = gridDim.y, gz = gridDim.z;
  int flat = blockIdx.x + gx * (blockIdx.y + gy * blockIdx.z);
  int nwg = gx * gy * gz;
  int swz = flat;
  if ((nwg & 7) == 0) swz = (flat & 7) * (nwg >> 3) + (flat >> 3);
  bx = swz % gx;
  int rem = swz / gx;
  by = rem % gy;
  bz = rem / gy;
}

// ---------------- bf16 GEMM 128x128, double-buffered 2-phase (param GEMM) ---
template <int EPI>
__global__ __launch_bounds__(256) void gemm_bt(const bf16_t* __restrict__ A,
                                               const bf16_t* __restrict__ Bw,
                                               float* __restrict__ C,
                                               const float* __restrict__ bias,
                                               const float* __restrict__ res,
                                               bf16_t* __restrict__ obf,
                                               bf16_t* __restrict__ ogate,
                                               int N, int Kps) {
  __shared__ bf16_t As[2][128 * 64];
  __shared__ bf16_t Bs[2][128 * 64];
  const int tid = threadIdx.x;
  const int wave = tid >> 6;
  const int lane = tid & 63;
  int bxi, byi, bzi;
  xcd_swz(bxi, byi, bzi);
  const int64_t m0 = (int64_t)byi * 128;
  const int64_t n0 = (int64_t)bxi * 128;
  const int K = Kps * gridDim.z;
  const int kbeg = bzi * Kps;
  float* Cz = C + (int64_t)bzi * ROWS * N;
  const int wm = (wave >> 1) * 64;
  const int wn = (wave & 1) * 64;
  f32x4 acc[4][4] = {};

  const int er = tid >> 3;
  const int ec = (tid * 8) & 63;
  const int fr = lane & 15;
  const int kq = (lane >> 4) * 8;

  auto stage = [&](int buf, int k0) {
#pragma unroll
    for (int i = 0; i < 4; ++i) {
      const bf16_t* ga = A + (m0 + er + i * 32) * K + k0 + ec;
      __builtin_amdgcn_global_load_lds((gvoid_t*)ga,
                                       (lvoid_t*)&As[buf][(i * 256 + wave * 64) * 8],
                                       16, 0, 0);
    }
#pragma unroll
    for (int i = 0; i < 4; ++i) {
      const bf16_t* gb = Bw + (n0 + er + i * 32) * K + k0 + ec;
      __builtin_amdgcn_global_load_lds((gvoid_t*)gb,
                                       (lvoid_t*)&Bs[buf][(i * 256 + wave * 64) * 8],
                                       16, 0, 0);
    }
  };
  auto compute = [&](int buf) {
#pragma unroll
    for (int kk = 0; kk < 2; ++kk) {
      bf16x8 af[4], bv[4];
#pragma unroll
      for (int mi = 0; mi < 4; ++mi)
        af[mi] = *reinterpret_cast<const bf16x8*>(&As[buf][(wm + mi * 16 + fr) * 64 + kk * 32 + kq]);
#pragma unroll
      for (int ni = 0; ni < 4; ++ni)
        bv[ni] = *reinterpret_cast<const bf16x8*>(&Bs[buf][(wn + ni * 16 + fr) * 64 + kk * 32 + kq]);
#pragma unroll
      for (int mi = 0; mi < 4; ++mi)
#pragma unroll
        for (int ni = 0; ni < 4; ++ni)
          acc[mi][ni] = __builtin_amdgcn_mfma_f32_16x16x32_bf16(af[mi], bv[ni], acc[mi][ni], 0, 0, 0);
    }
  };

  const int nk = Kps >> 6;  // assumed even
  stage(0, kbeg);
  asm volatile("s_waitcnt vmcnt(0)" ::: "memory");
  __builtin_amdgcn_s_barrier();
  int kc = kbeg;
  for (int t = 0; t < nk; t += 2) {
    stage(1, kc + 64);
    compute(0);
    asm volatile("s_waitcnt vmcnt(0)" ::: "memory");
    __builtin_amdgcn_s_barrier();
    if (t + 2 < nk) stage(0, kc + 128);
    compute(1);
    asm volatile("s_waitcnt vmcnt(0)" ::: "memory");
    __builtin_amdgcn_s_barrier();
    kc += 128;
  }

  const int crow = (lane >> 4) * 4;
  const int ccol = lane & 15;
#pragma unroll
  for (int mi = 0; mi < 4; ++mi)
#pragma unroll
    for (int ni = 0; ni < 4; ++ni)
#pragma unroll
      for (int j = 0; j < 4; ++j)
        epi_store<EPI>(acc[mi][ni][j], m0 + wm + mi * 16 + crow + j,
                       n0 + wn + ni * 16 + ccol, N, Cz, bias, res, obf, ogate,
                       bzi);
}

// ---------------- bf16 GEMM 128x256, 8-wave, depth-2 counted-vmcnt pipeline --
// Per K-tile: read Q0+Q1 -> lgkmcnt(8) -> MFMA Q0 (covers Q1 reads) ->
// lgkmcnt(0)+barrier -> stage(t+2) -> MFMA Q1 (covers stage) -> vmcnt(6)+barrier.
template <int EPI>
__global__ __launch_bounds__(512, 2) void gemm_big(const bf16_t* __restrict__ A,
                                                   const bf16_t* __restrict__ Bw,
                                                   float* __restrict__ C,
                                                   const float* __restrict__ bias,
                                                   const float* __restrict__ res,
                                                   bf16_t* __restrict__ obf,
                                                   bf16_t* __restrict__ ogate,
                                                   int N, int Kps) {
  __shared__ bf16_t As[2][128 * 64];
  __shared__ bf16_t Bs[2][256 * 64];
  const int tid = threadIdx.x;
  const int wave = tid >> 6;
  const int lane = tid & 63;
  int bxi, byi, bzi;
  xcd_swz(bxi, byi, bzi);
  const int64_t m0 = (int64_t)byi * 128;
  const int64_t n0 = (int64_t)bxi * 256;
  const int K = Kps * gridDim.z;
  const int kbeg = bzi * Kps;
  float* Cz = C + (int64_t)bzi * ROWS * N;
  const int wm = (wave >> 2) * 64;   // 2 M-wave rows
  const int wc = (wave & 3) * 64;    // 4 N-wave cols
  const int fr = lane & 15;
  const int kq16 = (lane >> 4) * 16;  // byte col of k-quad
  const int er = tid >> 3;                              // staging row 0..63
  const int ec_sw = ((tid & 7) * 8) ^ ((er & 7) << 3);  // swizzled src col (elems)
  f32x4 acc[4][4] = {};

  auto stage = [&](int buf, int k0) {
#pragma unroll
    for (int i = 0; i < 2; ++i) {
      const bf16_t* ga = A + (m0 + er + i * 64) * K + k0 + ec_sw;
      __builtin_amdgcn_global_load_lds((gvoid_t*)ga,
          (lvoid_t*)((char*)&As[buf][0] + i * 8192 + wave * 1024), 16, 0, 0);
    }
#pragma unroll
    for (int i = 0; i < 4; ++i) {
      const bf16_t* gb = Bw + (n0 + er + i * 64) * K + k0 + ec_sw;
      __builtin_amdgcn_global_load_lds((gvoid_t*)gb,
          (lvoid_t*)((char*)&Bs[buf][0] + i * 8192 + wave * 1024), 16, 0, 0);
    }
  };

  const int nk = Kps >> 6;
  stage(0, kbeg);
  if (nk > 1) {
    stage(1, kbeg + 64);
    asm volatile("s_waitcnt vmcnt(6)" ::: "memory");
  } else {
    asm volatile("s_waitcnt vmcnt(0)" ::: "memory");
  }
  __builtin_amdgcn_s_barrier();
  __builtin_amdgcn_sched_barrier(0);

  for (int t = 0; t < nk; ++t) {
    const int buf = t & 1;
    bf16x8 af[2][4], bf[2][4];
#pragma unroll
    for (int kk = 0; kk < 2; ++kk) {
#pragma unroll
      for (int mi = 0; mi < 4; ++mi) {
        int r = wm + mi * 16 + fr;
        af[kk][mi] = *(const bf16x8*)((const char*)&As[buf][0] + r * 128 +
                       ((kk * 64 + kq16) ^ ((r & 7) << 4)));
      }
#pragma unroll
      for (int ni = 0; ni < 4; ++ni) {
        int r = wc + ni * 16 + fr;
        bf[kk][ni] = *(const bf16x8*)((const char*)&Bs[buf][0] + r * 128 +
                       ((kk * 64 + kq16) ^ ((r & 7) << 4)));
      }
    }
    asm volatile("s_waitcnt lgkmcnt(8)" ::: "memory");
    __builtin_amdgcn_sched_barrier(0);
    __builtin_amdgcn_s_setprio(1);
#pragma unroll
    for (int mi = 0; mi < 4; ++mi)
#pragma unroll
      for (int ni = 0; ni < 4; ++ni)
        acc[mi][ni] = __builtin_amdgcn_mfma_f32_16x16x32_bf16(
            af[0][mi], bf[0][ni], acc[mi][ni], 0, 0, 0);
    __builtin_amdgcn_s_setprio(0);
    __builtin_amdgcn_sched_barrier(0);
    asm volatile("s_waitcnt lgkmcnt(0)" ::: "memory");
    __builtin_amdgcn_sched_barrier(0);
    __builtin_amdgcn_s_barrier();          // all waves done reading buf
    __builtin_amdgcn_sched_barrier(0);
    if (t + 2 < nk) stage(buf, kbeg + (t + 2) * 64);  // overwrite buf, 2 ahead
    __builtin_amdgcn_s_setprio(1);
#pragma unroll
    for (int mi = 0; mi < 4; ++mi)
#pragma unroll
      for (int ni = 0; ni < 4; ++ni)
        acc[mi][ni] = __builtin_amdgcn_mfma_f32_16x16x32_bf16(
            af[1][mi], bf[1][ni], acc[mi][ni], 0, 0, 0);
    __builtin_amdgcn_s_setprio(0);
    if (t + 1 < nk) {
      if (t + 2 < nk) asm volatile("s_waitcnt vmcnt(6)" ::: "memory");
      else            asm volatile("s_waitcnt vmcnt(0)" ::: "memory");
      __builtin_amdgcn_s_barrier();        // buf^1 staged & landed for t+1
      __builtin_amdgcn_sched_barrier(0);
    }
  }

  const int crow = (lane >> 4) * 4;
  const int ccol = lane & 15;
#pragma unroll
  for (int mi = 0; mi < 4; ++mi)
#pragma unroll
    for (int ni = 0; ni < 4; ++ni)
#pragma unroll
      for (int j = 0; j < 4; ++j)
        epi_store<EPI>(acc[mi][ni][j], m0 + wm + mi * 16 + crow + j,
                       n0 + wc + ni * 16 + ccol, N, Cz, bias, res, obf, ogate,
                       bzi);
}

extern "C" void kernel_launch(void* const* d_in, const int* in_sizes, int n_in,
                              void* d_out, int out_size, void* d_ws, size_t ws_size,
                              hipStream_t stream) {
  const float* x       = (const float*)d_in[0];
  const float* A_log   = (const float*)d_in[1];
  const float* g1      = (const float*)d_in[2];
  const float* g2      = (const float*)d_in[3];
  const float* W_in    = (const float*)d_in[4];
  const float* W_param = (const float*)d_in[5];
  const float* W_out   = (const float*)d_in[6];
  const float* W_ffn1  = (const float*)d_in[7];
  const float* b_ffn1  = (const float*)d_in[8];
  const float* W_ffn2  = (const float*)d_in[9];
  const float* b_ffn2  = (const float*)d_in[10];
  float* out = (float*)d_out;

  char* ws = (char*)d_ws;
  size_t off = 0;
  auto alloc = [&](size_t bytes) {
    char* p = ws + off;
    off += (bytes + 255) & ~(size_t)255;
    return p;
  };
  bf16_t* wb_in  = (bf16_t*)alloc(4096ull * 1024 * 2);
  bf16_t* wb_par = (bf16_t*)alloc((size_t)PPAD * 2048 * 2);
  bf16_t* wb_out = (bf16_t*)alloc(1024ull * 2048 * 2);
  bf16_t* wb_f1  = (bf16_t*)alloc(4096ull * 1024 * 2);
  bf16_t* wb_f2  = (bf16_t*)alloc(1024ull * 4096 * 2);
  bf16_t* zbuf   = (bf16_t*)alloc(2048ull * 1024 * 2);   // z, later h2
  float*  xzg    = (float*)alloc(2048ull * 4096 * 4);    // sgate bf16 (sk) / fp32 (fallback)
  float*  params = (float*)alloc(2048ull * PPAD * 4);    // fallback only; S/Etot overlay
  float*  ssmp   = (float*)alloc(32ull * 1024 * 48 * 4);
  float*  xmid   = (float*)alloc(2048ull * 1024 * 4);
  char*   regA   = alloc(2048ull * 4096 * 2);            // 16MB union
  bf16_t* xz_act = (bf16_t*)regA;
  bf16_t* y_b16  = (bf16_t*)(regA + 2048ull * 2048 * 2);
  bf16_t* f_act  = (bf16_t*)regA;
  bf16_t* sgate  = (bf16_t*)xzg;                         // [2048][2048] bf16 (sk)
  float* Sbuf = params;
  float* Etot = params + 32ull * 16 * 16 * 128;
  float* Hbuf = xmid;
  float*  psum = (float*)alloc(4ull * ROWS * 1024 * 4);  // fp32 partials (fallback)
  bf16_t* pb16 = (bf16_t*)psum;                          // bf16 partials overlay
  const bool sk = (off <= ws_size);

  dim3 b256(256), b512(512);
  // weights->bf16 + z=rmsnorm(x,g1), one launch
  prep0<<<CVT_BLOCKS + 2048, b256, 0, stream>>>(W_in, W_param, W_out, W_ffn1, W_ffn2,
                                                wb_in, wb_par, wb_out, wb_f1, wb_f2,
                                                x, g1, zbuf);

  if (sk) {
    // xz|gate = z @ W_in^T, fused: silu(xz)->xz_act, silu(gate)->sgate (bf16)
    gemm_big<4><<<dim3(16, 16), b512, 0, stream>>>(zbuf, wb_in, psum, nullptr, nullptr, xz_act, sgate, 4096, 1024);
    // params partials (bf16, SK=4)
    gemm_bt<16><<<dim3(PPAD / 128, 16, 4), b256, 0, stream>>>(xz_act, wb_par, psum, nullptr, nullptr, pb16, nullptr, PPAD, 512);
    ssm_prep<bf16_t><<<128, b256, 0, stream>>>(pb16, A_log, ssmp, 4);
    ssm_chunk<<<512, b256, 0, stream>>>(ssmp, xz_act, Sbuf, Etot);
    ssm_combine<<<256, b256, 0, stream>>>(Sbuf, Etot, Hbuf);
    ssm_out<1><<<512, b256, 0, stream>>>(ssmp, xz_act, Hbuf, nullptr, sgate, 2048, y_b16);
    // xmid = x + y @ W_out^T (SK=4, bf16 partials) fused reduce+rmsnorm
    gemm_big<16><<<dim3(4, 16, 4), b512, 0, stream>>>(y_b16, wb_out, psum, nullptr, nullptr, pb16, nullptr, 1024, 512);
    reduce_rms<<<2048, b256, 0, stream>>>(pb16, x, g2, xmid, zbuf);
    // ffn1 + bias + silu -> f_act bf16 (fused)
    gemm_big<9><<<dim3(16, 16), b512, 0, stream>>>(zbuf, wb_f1, psum, b_ffn1, nullptr, f_act, nullptr, 4096, 1024);
    // out = xmid + b_ffn2 + f_act @ W_ffn2^T (SK=4, bf16 partials)
    gemm_big<16><<<dim3(4, 16, 4), b512, 0, stream>>>(f_act, wb_f2, psum, nullptr, nullptr, pb16, nullptr, 1024, 1024);
    reduce_bias<<<2048, b256, 0, stream>>>(pb16, xmid, b_ffn2, out);
  } else {
    gemm_bt<0><<<dim3(32, 16), b256, 0, stream>>>(zbuf, wb_in, xzg, nullptr, nullptr, nullptr, nullptr, 4096, 1024);
    silu_cvt<<<4096, b256, 0, stream>>>(xzg, xz_act, 4096, 2048);
    gemm_bt<0><<<dim3(PPAD / 128, 16), b256, 0, stream>>>(xz_act, wb_par, params, nullptr, nullptr, nullptr, nullptr, PPAD, 2048);
    ssm_prep<float><<<128, b256, 0, stream>>>(params, A_log, ssmp, 1);
    ssm_chunk<<<512, b256, 0, stream>>>(ssmp, xz_act, Sbuf, Etot);
    ssm_combine<<<256, b256, 0, stream>>>(Sbuf, Etot, Hbuf);
    ssm_out<0><<<512, b256, 0, stream>>>(ssmp, xz_act, Hbuf, xzg + 2048, nullptr, 4096, y_b16);
    gemm_bt<2><<<dim3(8, 16), b256, 0, stream>>>(y_b16, wb_out, xmid, nullptr, x, nullptr, nullptr, 1024, 2048);
    rmsnorm_k<<<2048, b256, 0, stream>>>(xmid, g2, zbuf);
    gemm_bt<1><<<dim3(32, 16), b256, 0, stream>>>(zbuf, wb_f1, xzg, b_ffn1, nullptr, nullptr, nullptr, 4096, 1024);
    silu_cvt<<<8192, b256, 0, stream>>>(xzg, f_act, 4096, 4096);
    gemm_bt<3><<<dim3(8, 16), b256, 0, stream>>>(f_act, wb_f2, out, b_ffn2, xmid, nullptr, nullptr, 1024, 4096);
  }
}

// Round 8
// 176.790 us; speedup vs baseline: 5.7194x; 1.0667x over previous
//
#include <hip/hip_runtime.h>
#include <hip/hip_bf16.h>
#include <stdint.h>

// MambaBlock: B=2, T=1024, D_MODEL=1024, D_INNER=2048, GROUPS=16, D_STATE=16
#define ROWS 2048      // B*T
#define DM   1024
#define DI   2048
#define PPAD 640       // 528 param rows padded to 5*128

typedef __bf16 bf16_t;
typedef __attribute__((ext_vector_type(8))) __bf16 bf16x8;
typedef __attribute__((ext_vector_type(4))) __bf16 bf16x4;
typedef __attribute__((ext_vector_type(4))) float f32x4;
typedef __attribute__((address_space(1))) void gvoid_t;
typedef __attribute__((address_space(3))) void lvoid_t;

// ---------------- prep0: W_in + W_param -> bf16, z = rmsnorm(x,g1) ----------
// blocks: [0,4096) W_in | [4096,5376) W_param pad | [5376,7424) rmsnorm rows
__global__ __launch_bounds__(256) void prep0(const float* __restrict__ W_in,
                                             const float* __restrict__ W_param,
                                             bf16_t* o_in, bf16_t* o_par,
                                             const float* __restrict__ x,
                                             const float* __restrict__ g1,
                                             bf16_t* __restrict__ zb) {
  int tid = threadIdx.x;
  if (blockIdx.x >= 5376) {  // rmsnorm
    int row = blockIdx.x - 5376;
    const float4 v = *(const float4*)(x + (int64_t)row * DM + tid * 4);
    float ss = v.x * v.x + v.y * v.y + v.z * v.z + v.w * v.w;
#pragma unroll
    for (int o = 32; o; o >>= 1) ss += __shfl_xor(ss, o, 64);
    __shared__ float red[4];
    if ((tid & 63) == 0) red[tid >> 6] = ss;
    __syncthreads();
    float tot = red[0] + red[1] + red[2] + red[3];
    float sc = rsqrtf(tot * (1.0f / DM) + 1e-6f);
    const float4 gv = *(const float4*)(g1 + tid * 4);
    bf16_t* o = zb + (int64_t)row * DM + tid * 4;
    o[0] = (bf16_t)(v.x * sc * gv.x);
    o[1] = (bf16_t)(v.y * sc * gv.y);
    o[2] = (bf16_t)(v.z * sc * gv.z);
    o[3] = (bf16_t)(v.w * sc * gv.w);
    return;
  }
  if (blockIdx.x >= 4096) {  // W_param, zero-padded 528 -> 640 rows
    int64_t e = (((int64_t)(blockIdx.x - 4096)) * 256 + tid) * 4;
    int row = (int)(e >> 11), col = (int)(e & 2047);
    float4 v = make_float4(0.f, 0.f, 0.f, 0.f);
    if (row < 528) v = *(const float4*)(W_param + (int64_t)row * 2048 + col);
    bf16_t* o = o_par + e;
    o[0] = (bf16_t)v.x; o[1] = (bf16_t)v.y; o[2] = (bf16_t)v.z; o[3] = (bf16_t)v.w;
    return;
  }
  int64_t e = ((int64_t)blockIdx.x * 256 + tid) * 4;
  float4 v = *(const float4*)(W_in + e);
  bf16_t* o = o_in + e;
  o[0] = (bf16_t)v.x; o[1] = (bf16_t)v.y; o[2] = (bf16_t)v.z; o[3] = (bf16_t)v.w;
}

// ---------------- conversion of W_out/W_f1/W_f2 (10240 blocks) --------------
__device__ __forceinline__ void conv3(int64_t c, int tid,
                                      const float* __restrict__ W_out,
                                      const float* __restrict__ W_f1,
                                      const float* __restrict__ W_f2,
                                      bf16_t* o_out, bf16_t* o_f1, bf16_t* o_f2) {
  const float* src; bf16_t* dst; int64_t e;
  if (c < 2048) { e = (c * 256 + tid) * 4; src = W_out; dst = o_out; }
  else if (c < 6144) { e = ((c - 2048) * 256 + tid) * 4; src = W_f1; dst = o_f1; }
  else { e = ((c - 6144) * 256 + tid) * 4; src = W_f2; dst = o_f2; }
  float4 v = *(const float4*)(src + e);
  bf16_t* o = dst + e;
  o[0] = (bf16_t)v.x; o[1] = (bf16_t)v.y; o[2] = (bf16_t)v.z; o[3] = (bf16_t)v.w;
}

__global__ __launch_bounds__(256) void cvt3_k(const float* __restrict__ W_out,
                                              const float* __restrict__ W_f1,
                                              const float* __restrict__ W_f2,
                                              bf16_t* o_out, bf16_t* o_f1,
                                              bf16_t* o_f2) {
  conv3(blockIdx.x, threadIdx.x, W_out, W_f1, W_f2, o_out, o_f1, o_f2);
}

// ---------------- rmsnorm (fallback) ----------------
__global__ __launch_bounds__(256) void rmsnorm_k(const float* __restrict__ x,
                                                 const float* __restrict__ g,
                                                 bf16_t* __restrict__ out) {
  int row = blockIdx.x;
  int tid = threadIdx.x;
  const float4 v = *(const float4*)(x + (int64_t)row * DM + tid * 4);
  float ss = v.x * v.x + v.y * v.y + v.z * v.z + v.w * v.w;
#pragma unroll
  for (int o = 32; o; o >>= 1) ss += __shfl_xor(ss, o, 64);
  __shared__ float red[4];
  if ((tid & 63) == 0) red[tid >> 6] = ss;
  __syncthreads();
  float tot = red[0] + red[1] + red[2] + red[3];
  float sc = rsqrtf(tot * (1.0f / DM) + 1e-6f);
  const float4 gv = *(const float4*)(g + tid * 4);
  bf16_t* o = out + (int64_t)row * DM + tid * 4;
  o[0] = (bf16_t)(v.x * sc * gv.x);
  o[1] = (bf16_t)(v.y * sc * gv.y);
  o[2] = (bf16_t)(v.z * sc * gv.z);
  o[3] = (bf16_t)(v.w * sc * gv.w);
}

// ---------------- silu + fp32 -> bf16 (fallback) ----------------
__global__ __launch_bounds__(256) void silu_cvt(const float* __restrict__ in,
                                                bf16_t* __restrict__ out,
                                                int in_stride, int ncols) {
  int64_t e = ((int64_t)blockIdx.x * 256 + threadIdx.x) * 4;
  int row = (int)(e / ncols);
  int col = (int)(e % ncols);
  const float4 v = *(const float4*)(in + (int64_t)row * in_stride + col);
  bf16_t* o = out + e;
  o[0] = (bf16_t)(v.x / (1.f + expf(-v.x)));
  o[1] = (bf16_t)(v.y / (1.f + expf(-v.y)));
  o[2] = (bf16_t)(v.z / (1.f + expf(-v.z)));
  o[3] = (bf16_t)(v.w / (1.f + expf(-v.w)));
}

// ---------------- standalone ssm_prep (fallback only) ----------------------
__global__ __launch_bounds__(256) void ssm_prep(const float* __restrict__ params,
                                                const float* __restrict__ A_log,
                                                float* __restrict__ ssmp) {
  int gid = blockIdx.x * 256 + threadIdx.x;  // 32 * 1024
  int bg = gid >> 10, t = gid & 1023;
  int b = bg >> 4, g = bg & 15;
  const float* pr = params + (int64_t)(b * 1024 + t) * PPAD + g * 33;
  float raw = pr[0];
  float delta = raw > 0.f ? raw + log1pf(expf(-raw)) : log1pf(expf(raw));
  float* o = ssmp + (int64_t)gid * 48;
#pragma unroll
  for (int s = 0; s < 16; ++s) {
    float A = -expf(A_log[s]);
    float dA = delta * A;
    dA = fminf(10.f, fmaxf(-10.f, dA));
    float e = expf(dA);
    float frac = (fabsf(dA) < 1e-4f) ? delta : (e - 1.f) / (A + 1e-12f);
    o[s] = dA;
    o[16 + s] = frac * pr[1 + s];
    o[32 + s] = pr[17 + s];
  }
}

// ---------------- split-K reduce (bf16 partials) + residual + rmsnorm -------
__global__ __launch_bounds__(256) void reduce_rms(const bf16_t* __restrict__ P,
                                                  const float* __restrict__ x,
                                                  const float* __restrict__ g,
                                                  float* __restrict__ xmid,
                                                  bf16_t* __restrict__ zb) {
  int row = blockIdx.x;
  int tid = threadIdx.x;
  int64_t base = (int64_t)row * DM + tid * 4;
  float4 v = *(const float4*)(x + base);
#pragma unroll
  for (int p = 0; p < 4; ++p) {
    bf16x4 pv = *(const bf16x4*)(P + (int64_t)p * ROWS * DM + base);
    v.x += (float)pv[0]; v.y += (float)pv[1]; v.z += (float)pv[2]; v.w += (float)pv[3];
  }
  *(float4*)(xmid + base) = v;
  float ss = v.x * v.x + v.y * v.y + v.z * v.z + v.w * v.w;
#pragma unroll
  for (int o = 32; o; o >>= 1) ss += __shfl_xor(ss, o, 64);
  __shared__ float red[4];
  if ((tid & 63) == 0) red[tid >> 6] = ss;
  __syncthreads();
  float tot = red[0] + red[1] + red[2] + red[3];
  float sc = rsqrtf(tot * (1.0f / DM) + 1e-6f);
  const float4 gv = *(const float4*)(g + tid * 4);
  bf16_t* o = zb + base;
  o[0] = (bf16_t)(v.x * sc * gv.x);
  o[1] = (bf16_t)(v.y * sc * gv.y);
  o[2] = (bf16_t)(v.z * sc * gv.z);
  o[3] = (bf16_t)(v.w * sc * gv.w);
}

__global__ __launch_bounds__(256) void reduce_bias(const bf16_t* __restrict__ P,
                                                   const float* __restrict__ res,
                                                   const float* __restrict__ bias,
                                                   float* __restrict__ out) {
  int64_t e = ((int64_t)blockIdx.x * 256 + threadIdx.x) * 4;
  int col = (int)(e % DM);
  float4 v = *(const float4*)(res + e);
  const float4 bv = *(const float4*)(bias + col);
  v.x += bv.x; v.y += bv.y; v.z += bv.z; v.w += bv.w;
#pragma unroll
  for (int p = 0; p < 4; ++p) {
    bf16x4 pv = *(const bf16x4*)(P + (int64_t)p * ROWS * DM + e);
    v.x += (float)pv[0]; v.y += (float)pv[1]; v.z += (float)pv[2]; v.w += (float)pv[3];
  }
  *(float4*)(out + e) = v;
}

// inline prep: compute 64 rows of coefficients into cf[64*48] from bf16
// split-K partials (4 parts). cf row t: { dA[16], frac*b[16], c[16] }.
__device__ __forceinline__ void prep_rows(const bf16_t* __restrict__ pb,
                                          const float* __restrict__ A_log,
                                          float* cf, int b, int g, int t0,
                                          int tid) {
  if (tid >= 64) return;
  int t = tid;
  int64_t row = (int64_t)(b * 1024) + t0 + t;
  float acc[33];
#pragma unroll
  for (int i = 0; i < 33; ++i) acc[i] = 0.f;
#pragma unroll
  for (int p = 0; p < 4; ++p) {
    const bf16_t* pr = pb + (int64_t)p * ROWS * PPAD + row * PPAD + g * 33;
#pragma unroll
    for (int i = 0; i < 33; ++i) acc[i] += (float)pr[i];
  }
  float raw = acc[0];
  float delta = raw > 0.f ? raw + log1pf(expf(-raw)) : log1pf(expf(raw));
  float* o = cf + t * 48;
#pragma unroll
  for (int s = 0; s < 16; ++s) {
    float A = -expf(A_log[s]);
    float dA = delta * A;
    dA = fminf(10.f, fmaxf(-10.f, dA));
    float e = expf(dA);
    float frac = (fabsf(dA) < 1e-4f) ? delta : (e - 1.f) / (A + 1e-12f);
    o[s] = dA;
    o[16 + s] = frac * acc[1 + s];
    o[32 + s] = acc[17 + s];
  }
}

// Ut layout: element (ch, t) at byte ch*128 + ((t*2) ^ ((ch&7)<<4))

// ---------------- Phase A: per-chunk boundary operator (MFMA) ---------------
template <int PREP>
__global__ __launch_bounds__(256) void ssm_chunk(const float* __restrict__ ssmp,
                                                 const bf16_t* __restrict__ pb,
                                                 const float* __restrict__ A_log,
                                                 const bf16_t* __restrict__ u,
                                                 float* __restrict__ S,
                                                 float* __restrict__ Etot) {
  __shared__ __align__(16) float cf[64 * 48];
  __shared__ __align__(16) float Lb[64 * 16];
  __shared__ __align__(16) bf16_t wl[16 * 64];
  __shared__ __align__(16) bf16_t Ut[128 * 64];
  int bgc = blockIdx.x;
  int bg = bgc >> 4, c = bgc & 15;
  int b = bg >> 4, g = bg & 15;
  int t0 = c * 64;
  int tid = threadIdx.x;
  {
    int lt = tid >> 4;
    int c8 = (tid & 15) * 8;
#pragma unroll
    for (int p = 0; p < 4; ++p) {
      int t = p * 16 + lt;
      bf16x8 v = *(const bf16x8*)(u + ((int64_t)(b * 1024) + t0 + t) * 2048 + g * 128 + c8);
#pragma unroll
      for (int j = 0; j < 8; ++j)
        Ut[(c8 + j) * 64 + (((t >> 3) ^ j) << 3) + (t & 7)] = v[j];
    }
  }
  if (PREP) {
    prep_rows(pb, A_log, cf, b, g, t0, tid);
  } else {
    const float4* src = (const float4*)(ssmp + ((int64_t)bg * 1024 + t0) * 48);
    float4* dst = (float4*)cf;
#pragma unroll
    for (int i = 0; i < 3; ++i) dst[i * 256 + tid] = src[i * 256 + tid];
  }
  __syncthreads();
  if (tid < 16) {
    float l = 0.f;
    for (int t = 0; t < 64; ++t) { l += cf[t * 48 + tid]; Lb[t * 16 + tid] = l; }
  }
  __syncthreads();
  {
    int s = tid >> 4, tb4 = (tid & 15) * 4;
    float lend = Lb[63 * 16 + s];
    bf16x4 wv;
#pragma unroll
    for (int j = 0; j < 4; ++j) {
      int t = tb4 + j;
      wv[j] = (bf16_t)(__expf(lend - Lb[t * 16 + s]) * cf[t * 48 + 16 + s]);
    }
    unsigned byo = (unsigned)(s * 128 + tb4 * 2) ^ ((unsigned)(s & 7) << 4);
    *(bf16x4*)((char*)wl + byo) = wv;
    if (tid < 16) Etot[(int64_t)bgc * 16 + tid] = __expf(Lb[63 * 16 + tid]);
  }
  __syncthreads();
  {
    int lane = tid & 63, wave = tid >> 6;
    int fr = lane & 15, kq = lane >> 4;
    f32x4 acc2[2] = {};
#pragma unroll
    for (int kk = 0; kk < 2; ++kk) {
      int kb = kk * 4 + kq;
      bf16x8 af = *(const bf16x8*)((const char*)wl +
                    ((unsigned)(fr * 128 + kb * 16) ^ ((unsigned)(fr & 7) << 4)));
#pragma unroll
      for (int q = 0; q < 2; ++q) {
        int ch = (wave * 2 + q) * 16 + fr;
        bf16x8 bfr = *(const bf16x8*)((const char*)Ut +
                       ((unsigned)(ch * 128 + kb * 16) ^ ((unsigned)(ch & 7) << 4)));
        acc2[q] = __builtin_amdgcn_mfma_f32_16x16x32_bf16(af, bfr, acc2[q], 0, 0, 0);
      }
    }
    float* Sp = S + (int64_t)bgc * 2048;
#pragma unroll
    for (int q = 0; q < 2; ++q) {
      int ch = (wave * 2 + q) * 16 + fr;
#pragma unroll
      for (int j = 0; j < 4; ++j) Sp[(kq * 4 + j) * 128 + ch] = acc2[q][j];
    }
  }
}

// ---------------- Phase B: sequential combine over 16 chunks ----------------
__global__ __launch_bounds__(256) void ssm_combine(const float* __restrict__ S,
                                                   const float* __restrict__ Etot,
                                                   float* __restrict__ H) {
  int gid = blockIdx.x * 256 + threadIdx.x;
  int bg = gid >> 11;
  int s = (gid >> 7) & 15;
  int ch = gid & 127;
  float h = 0.f;
  for (int c = 0; c < 16; ++c) {
    int bgc = bg * 16 + c;
    int64_t idx = ((int64_t)bgc * 16 + s) * 128 + ch;
    H[idx] = h;
    h = Etot[(int64_t)bgc * 16 + s] * h + S[idx];
  }
}

// ---------------- Phase C: y = tril(K)@U + ce@H, fused gate (MFMA) ----------
template <int PREP, int GM>
__global__ __launch_bounds__(256) void ssm_out(const float* __restrict__ ssmp,
                                               const bf16_t* __restrict__ pb,
                                               const float* __restrict__ A_log,
                                               const bf16_t* __restrict__ u,
                                               const float* __restrict__ H,
                                               const float* __restrict__ gate_f,
                                               const bf16_t* __restrict__ gate_b,
                                               int gstride,
                                               bf16_t* __restrict__ yout) {
  __shared__ __align__(16) float cf[64 * 48];
  __shared__ __align__(16) float Lb[64 * 16];
  __shared__ __align__(16) bf16_t Km[64 * 64];
  __shared__ __align__(16) bf16_t Ut[128 * 64];
  __shared__ __align__(16) bf16_t Hb[128 * 32];
  int bgc = blockIdx.x;
  int bg = bgc >> 4, c = bgc & 15;
  int b = bg >> 4, g = bg & 15;
  int t0 = c * 64;
  int tid = threadIdx.x;
  int lane = tid & 63, wave = tid >> 6;
  {
    int lt = tid >> 4;
    int c8 = (tid & 15) * 8;
#pragma unroll
    for (int p = 0; p < 4; ++p) {
      int t = p * 16 + lt;
      bf16x8 v = *(const bf16x8*)(u + ((int64_t)(b * 1024) + t0 + t) * 2048 + g * 128 + c8);
#pragma unroll
      for (int j = 0; j < 8; ++j)
        Ut[(c8 + j) * 64 + (((t >> 3) ^ j) << 3) + (t & 7)] = v[j];
    }
  }
  {
    int ch = tid >> 1, h8 = (tid & 1) * 8;
    const float* Hp = H + (int64_t)bgc * 2048 + ch;
#pragma unroll
    for (int j = 0; j < 8; ++j) {
      Hb[ch * 32 + h8 + j] = (bf16_t)Hp[(h8 + j) * 128];
      Hb[ch * 32 + 16 + h8 + j] = (bf16_t)0.f;
    }
  }
  if (PREP) {
    prep_rows(pb, A_log, cf, b, g, t0, tid);
  } else {
    const float4* src = (const float4*)(ssmp + ((int64_t)bg * 1024 + t0) * 48);
    float4* dst = (float4*)cf;
#pragma unroll
    for (int i = 0; i < 3; ++i) dst[i * 256 + tid] = src[i * 256 + tid];
  }
  __syncthreads();
  if (tid < 16) {
    float l = 0.f;
    for (int t = 0; t < 64; ++t) { l += cf[t * 48 + tid]; Lb[t * 16 + tid] = l; }
  }
  __syncthreads();
  {
    int t = tid >> 2, tp0 = (tid & 3) * 16;
    float4 cv[4], lv[4];
#pragma unroll
    for (int i = 0; i < 4; ++i) {
      cv[i] = *(const float4*)&cf[t * 48 + 32 + i * 4];
      lv[i] = *(const float4*)&Lb[t * 16 + i * 4];
    }
    float kv[16];
#pragma unroll
    for (int i = 0; i < 16; ++i) {
      int tp = tp0 + i;
      float k = 0.f;
      if (tp <= t) {
#pragma unroll
        for (int q = 0; q < 4; ++q) {
          float4 lpv = *(const float4*)&Lb[tp * 16 + q * 4];
          float4 fbv = *(const float4*)&cf[tp * 48 + 16 + q * 4];
          k += cv[q].x * __expf(lv[q].x - lpv.x) * fbv.x
             + cv[q].y * __expf(lv[q].y - lpv.y) * fbv.y
             + cv[q].z * __expf(lv[q].z - lpv.z) * fbv.z
             + cv[q].w * __expf(lv[q].w - lpv.w) * fbv.w;
        }
      }
      kv[i] = k;
    }
    bf16x8 lo, hi;
#pragma unroll
    for (int i = 0; i < 8; ++i) { lo[i] = (bf16_t)kv[i]; hi[i] = (bf16_t)kv[8 + i]; }
    unsigned b0 = (unsigned)(t * 128 + tp0 * 2) ^ ((unsigned)(t & 7) << 4);
    unsigned b1 = (unsigned)(t * 128 + tp0 * 2 + 16) ^ ((unsigned)(t & 7) << 4);
    *(bf16x8*)((char*)Km + b0) = lo;
    *(bf16x8*)((char*)Km + b1) = hi;
  }
  __syncthreads();
  int fr = lane & 15, kq = lane >> 4;
  int trow = (wave >> 1) * 32, wc = (wave & 1) * 64;
  f32x4 acc[2][4] = {};
#pragma unroll
  for (int kk = 0; kk < 2; ++kk) {
    int kb = kk * 4 + kq;
    bf16x8 af[2];
#pragma unroll
    for (int mi = 0; mi < 2; ++mi) {
      int row = trow + mi * 16 + fr;
      af[mi] = *(const bf16x8*)((const char*)Km +
                 ((unsigned)(row * 128 + kb * 16) ^ ((unsigned)(row & 7) << 4)));
    }
#pragma unroll
    for (int ni = 0; ni < 4; ++ni) {
      int ch = wc + ni * 16 + fr;
      bf16x8 bfr = *(const bf16x8*)((const char*)Ut +
                     ((unsigned)(ch * 128 + kb * 16) ^ ((unsigned)(ch & 7) << 4)));
#pragma unroll
      for (int mi = 0; mi < 2; ++mi)
        acc[mi][ni] = __builtin_amdgcn_mfma_f32_16x16x32_bf16(af[mi], bfr, acc[mi][ni], 0, 0, 0);
    }
  }
  {
    int s0 = kq * 8;
    bf16x8 cef[2];
    if (s0 < 16) {
#pragma unroll
      for (int mi = 0; mi < 2; ++mi) {
        int t = trow + mi * 16 + fr;
#pragma unroll
        for (int j = 0; j < 8; ++j)
          cef[mi][j] = (bf16_t)(cf[t * 48 + 32 + s0 + j] * __expf(Lb[t * 16 + s0 + j]));
      }
    } else {
#pragma unroll
      for (int mi = 0; mi < 2; ++mi)
#pragma unroll
        for (int j = 0; j < 8; ++j) cef[mi][j] = (bf16_t)0.f;
    }
#pragma unroll
    for (int ni = 0; ni < 4; ++ni) {
      int ch = wc + ni * 16 + fr;
      bf16x8 bhf = *(const bf16x8*)((const char*)Hb + ch * 64 + s0 * 2);
#pragma unroll
      for (int mi = 0; mi < 2; ++mi)
        acc[mi][ni] = __builtin_amdgcn_mfma_f32_16x16x32_bf16(cef[mi], bhf, acc[mi][ni], 0, 0, 0);
    }
  }
  {
    int64_t rowbase = (int64_t)b * 1024 + t0;
    int colbase = g * 128;
#pragma unroll
    for (int mi = 0; mi < 2; ++mi) {
#pragma unroll
      for (int ni = 0; ni < 4; ++ni) {
        int col = colbase + wc + ni * 16 + fr;
#pragma unroll
        for (int j = 0; j < 4; ++j) {
          int t = trow + mi * 16 + kq * 4 + j;
          float sg;
          if (GM) {
            sg = (float)gate_b[(rowbase + t) * 2048 + col];
          } else {
            float gv = gate_f[(rowbase + t) * (int64_t)gstride + col];
            sg = gv / (1.f + __expf(-gv));
          }
          yout[(rowbase + t) * 2048 + col] = (bf16_t)(acc[mi][ni][j] * sg);
        }
      }
    }
  }
}

// ======== epilogue helper shared by GEMM kernels ========
template <int EPI>
__device__ __forceinline__ void epi_store(float v, int64_t r, int64_t cn, int N,
                                          float* Cz, const float* bias,
                                          const float* res, bf16_t* obf,
                                          bf16_t* ogate, int z) {
  if (EPI & 1) v += bias[cn];
  if (EPI & 2) v += res[r * N + cn];
  if (EPI & 4) {
    float sv = v / (1.f + __expf(-v));
    if (cn < 2048) obf[r * 2048 + cn] = (bf16_t)sv;
    else ogate[r * 2048 + cn - 2048] = (bf16_t)sv;
  } else if (EPI & 8) {
    obf[r * N + cn] = (bf16_t)(v / (1.f + __expf(-v)));
  } else if (EPI & 16) {
    obf[(int64_t)z * ROWS * N + r * N + cn] = (bf16_t)v;
  } else {
    Cz[r * N + cn] = v;
  }
}

// bijective XCD swizzle over flattened grid (identity if nwg%8 != 0)
__device__ __forceinline__ void xcd_swz(int& bx, int& by, int& bz) {
  int gx = gridDim.x, gy = gridDim.y, gz = gridDim.z;
  int flat = blockIdx.x + gx * (blockIdx.y + gy * blockIdx.z);
  int nwg = gx * gy * gz;
  int swz = flat;
  if ((nwg & 7) == 0) swz = (flat & 7) * (nwg >> 3) + (flat >> 3);
  bx = swz % gx;
  int rem = swz / gx;
  by = rem % gy;
  bz = rem / gy;
}

// ---------------- bf16 GEMM 128x128, double-buffered 2-phase (fallback) -----
template <int EPI>
__global__ __launch_bounds__(256) void gemm_bt(const bf16_t* __restrict__ A,
                                               const bf16_t* __restrict__ Bw,
                                               float* __restrict__ C,
                                               const float* __restrict__ bias,
                                               const float* __restrict__ res,
                                               bf16_t* __restrict__ obf,
                                               bf16_t* __restrict__ ogate,
                                               int N, int Kps) {
  __shared__ bf16_t As[2][128 * 64];
  __shared__ bf16_t Bs[2][128 * 64];
  const int tid = threadIdx.x;
  const int wave = tid >> 6;
  const int lane = tid & 63;
  int bxi, byi, bzi;
  xcd_swz(bxi, byi, bzi);
  const int64_t m0 = (int64_t)byi * 128;
  const int64_t n0 = (int64_t)bxi * 128;
  const int K = Kps * gridDim.z;
  const int kbeg = bzi * Kps;
  float* Cz = C + (int64_t)bzi * ROWS * N;
  const int wm = (wave >> 1) * 64;
  const int wn = (wave & 1) * 64;
  f32x4 acc[4][4] = {};

  const int er = tid >> 3;
  const int ec = (tid * 8) & 63;
  const int fr = lane & 15;
  const int kq = (lane >> 4) * 8;

  auto stage = [&](int buf, int k0) {
#pragma unroll
    for (int i = 0; i < 4; ++i) {
      const bf16_t* ga = A + (m0 + er + i * 32) * K + k0 + ec;
      __builtin_amdgcn_global_load_lds((gvoid_t*)ga,
                                       (lvoid_t*)&As[buf][(i * 256 + wave * 64) * 8],
                                       16, 0, 0);
    }
#pragma unroll
    for (int i = 0; i < 4; ++i) {
      const bf16_t* gb = Bw + (n0 + er + i * 32) * K + k0 + ec;
      __builtin_amdgcn_global_load_lds((gvoid_t*)gb,
                                       (lvoid_t*)&Bs[buf][(i * 256 + wave * 64) * 8],
                                       16, 0, 0);
    }
  };
  auto compute = [&](int buf) {
#pragma unroll
    for (int kk = 0; kk < 2; ++kk) {
      bf16x8 af[4], bv[4];
#pragma unroll
      for (int mi = 0; mi < 4; ++mi)
        af[mi] = *reinterpret_cast<const bf16x8*>(&As[buf][(wm + mi * 16 + fr) * 64 + kk * 32 + kq]);
#pragma unroll
      for (int ni = 0; ni < 4; ++ni)
        bv[ni] = *reinterpret_cast<const bf16x8*>(&Bs[buf][(wn + ni * 16 + fr) * 64 + kk * 32 + kq]);
#pragma unroll
      for (int mi = 0; mi < 4; ++mi)
#pragma unroll
        for (int ni = 0; ni < 4; ++ni)
          acc[mi][ni] = __builtin_amdgcn_mfma_f32_16x16x32_bf16(af[mi], bv[ni], acc[mi][ni], 0, 0, 0);
    }
  };

  const int nk = Kps >> 6;  // assumed even
  stage(0, kbeg);
  asm volatile("s_waitcnt vmcnt(0)" ::: "memory");
  __builtin_amdgcn_s_barrier();
  int kc = kbeg;
  for (int t = 0; t < nk; t += 2) {
    stage(1, kc + 64);
    compute(0);
    asm volatile("s_waitcnt vmcnt(0)" ::: "memory");
    __builtin_amdgcn_s_barrier();
    if (t + 2 < nk) stage(0, kc + 128);
    compute(1);
    asm volatile("s_waitcnt vmcnt(0)" ::: "memory");
    __builtin_amdgcn_s_barrier();
    kc += 128;
  }

  const int crow = (lane >> 4) * 4;
  const int ccol = lane & 15;
#pragma unroll
  for (int mi = 0; mi < 4; ++mi)
#pragma unroll
    for (int ni = 0; ni < 4; ++ni)
#pragma unroll
      for (int j = 0; j < 4; ++j)
        epi_store<EPI>(acc[mi][ni][j], m0 + wm + mi * 16 + crow + j,
                       n0 + wn + ni * 16 + ccol, N, Cz, bias, res, obf, ogate,
                       bzi);
}

// ---------------- param GEMM (128x128, SK=4) + W_out/W_f1/W_f2 conversion ---
// blocks [0,320): GEMM xz_act @ W_param^T -> bf16 partials pout[z][2048][PPAD]
// blocks [320,10560): fp32->bf16 conversion riding the GEMM's idle HBM BW.
__global__ __launch_bounds__(256) void gemm_param_conv(
    const bf16_t* __restrict__ A, const bf16_t* __restrict__ Bw,
    bf16_t* __restrict__ pout,
    const float* __restrict__ W_out, const float* __restrict__ W_f1,
    const float* __restrict__ W_f2,
    bf16_t* o_out, bf16_t* o_f1, bf16_t* o_f2) {
  __shared__ bf16_t As[2][128 * 64];
  __shared__ bf16_t Bs[2][128 * 64];
  const int tid = threadIdx.x;
  if (blockIdx.x >= 320) {
    conv3(blockIdx.x - 320, tid, W_out, W_f1, W_f2, o_out, o_f1, o_f2);
    return;
  }
  const int flat = blockIdx.x;
  const int swz = (flat & 7) * 40 + (flat >> 3);  // 320 % 8 == 0, bijective
  const int bxi = swz % 5;
  const int byi = (swz / 5) % 16;
  const int bzi = swz / 80;
  const int wave = tid >> 6;
  const int lane = tid & 63;
  const int64_t m0 = (int64_t)byi * 128;
  const int64_t n0 = (int64_t)bxi * 128;
  const int K = 2048, Kps = 512;
  const int kbeg = bzi * Kps;
  const int wm = (wave >> 1) * 64;
  const int wn = (wave & 1) * 64;
  f32x4 acc[4][4] = {};
  const int er = tid >> 3;
  const int ec = (tid * 8) & 63;
  const int fr = lane & 15;
  const int kq = (lane >> 4) * 8;

  auto stage = [&](int buf, int k0) {
#pragma unroll
    for (int i = 0; i < 4; ++i) {
      const bf16_t* ga = A + (m0 + er + i * 32) * K + k0 + ec;
      __builtin_amdgcn_global_load_lds((gvoid_t*)ga,
                                       (lvoid_t*)&As[buf][(i * 256 + wave * 64) * 8],
                                       16, 0, 0);
    }
#pragma unroll
    for (int i = 0; i < 4; ++i) {
      const bf16_t* gb = Bw + (n0 + er + i * 32) * K + k0 + ec;
      __builtin_amdgcn_global_load_lds((gvoid_t*)gb,
                                       (lvoid_t*)&Bs[buf][(i * 256 + wave * 64) * 8],
                                       16, 0, 0);
    }
  };
  auto compute = [&](int buf) {
#pragma unroll
    for (int kk = 0; kk < 2; ++kk) {
      bf16x8 af[4], bv[4];
#pragma unroll
      for (int mi = 0; mi < 4; ++mi)
        af[mi] = *reinterpret_cast<const bf16x8*>(&As[buf][(wm + mi * 16 + fr) * 64 + kk * 32 + kq]);
#pragma unroll
      for (int ni = 0; ni < 4; ++ni)
        bv[ni] = *reinterpret_cast<const bf16x8*>(&Bs[buf][(wn + ni * 16 + fr) * 64 + kk * 32 + kq]);
#pragma unroll
      for (int mi = 0; mi < 4; ++mi)
#pragma unroll
        for (int ni = 0; ni < 4; ++ni)
          acc[mi][ni] = __builtin_amdgcn_mfma_f32_16x16x32_bf16(af[mi], bv[ni], acc[mi][ni], 0, 0, 0);
    }
  };

  const int nk = Kps >> 6;  // 8
  stage(0, kbeg);
  asm volatile("s_waitcnt vmcnt(0)" ::: "memory");
  __builtin_amdgcn_s_barrier();
  int kc = kbeg;
  for (int t = 0; t < nk; t += 2) {
    stage(1, kc + 64);
    compute(0);
    asm volatile("s_waitcnt vmcnt(0)" ::: "memory");
    __builtin_amdgcn_s_barrier();
    if (t + 2 < nk) stage(0, kc + 128);
    compute(1);
    asm volatile("s_waitcnt vmcnt(0)" ::: "memory");
    __builtin_amdgcn_s_barrier();
    kc += 128;
  }

  const int crow = (lane >> 4) * 4;
  const int ccol = lane & 15;
  bf16_t* pz = pout + (int64_t)bzi * ROWS * PPAD;
#pragma unroll
  for (int mi = 0; mi < 4; ++mi)
#pragma unroll
    for (int ni = 0; ni < 4; ++ni)
#pragma unroll
      for (int j = 0; j < 4; ++j) {
        int64_t r = m0 + wm + mi * 16 + crow + j;
        int64_t cn = n0 + wn + ni * 16 + ccol;
        pz[r * PPAD + cn] = (bf16_t)acc[mi][ni][j];
      }
}

// ---------------- bf16 GEMM 128x256, 8-wave, depth-2 counted-vmcnt pipeline --
template <int EPI>
__global__ __launch_bounds__(512, 2) void gemm_big(const bf16_t* __restrict__ A,
                                                   const bf16_t* __restrict__ Bw,
                                                   float* __restrict__ C,
                                                   const float* __restrict__ bias,
                                                   const float* __restrict__ res,
                                                   bf16_t* __restrict__ obf,
                                                   bf16_t* __restrict__ ogate,
                                                   int N, int Kps) {
  __shared__ bf16_t As[2][128 * 64];
  __shared__ bf16_t Bs[2][256 * 64];
  const int tid = threadIdx.x;
  const int wave = tid >> 6;
  const int lane = tid & 63;
  int bxi, byi, bzi;
  xcd_swz(bxi, byi, bzi);
  const int64_t m0 = (int64_t)byi * 128;
  const int64_t n0 = (int64_t)bxi * 256;
  const int K = Kps * gridDim.z;
  const int kbeg = bzi * Kps;
  float* Cz = C + (int64_t)bzi * ROWS * N;
  const int wm = (wave >> 2) * 64;
  const int wc = (wave & 3) * 64;
  const int fr = lane & 15;
  const int kq16 = (lane >> 4) * 16;
  const int er = tid >> 3;
  const int ec_sw = ((tid & 7) * 8) ^ ((er & 7) << 3);
  f32x4 acc[4][4] = {};

  auto stage = [&](int buf, int k0) {
#pragma unroll
    for (int i = 0; i < 2; ++i) {
      const bf16_t* ga = A + (m0 + er + i * 64) * K + k0 + ec_sw;
      __builtin_amdgcn_global_load_lds((gvoid_t*)ga,
          (lvoid_t*)((char*)&As[buf][0] + i * 8192 + wave * 1024), 16, 0, 0);
    }
#pragma unroll
    for (int i = 0; i < 4; ++i) {
      const bf16_t* gb = Bw + (n0 + er + i * 64) * K + k0 + ec_sw;
      __builtin_amdgcn_global_load_lds((gvoid_t*)gb,
          (lvoid_t*)((char*)&Bs[buf][0] + i * 8192 + wave * 1024), 16, 0, 0);
    }
  };

  const int nk = Kps >> 6;
  stage(0, kbeg);
  if (nk > 1) {
    stage(1, kbeg + 64);
    asm volatile("s_waitcnt vmcnt(6)" ::: "memory");
  } else {
    asm volatile("s_waitcnt vmcnt(0)" ::: "memory");
  }
  __builtin_amdgcn_s_barrier();
  __builtin_amdgcn_sched_barrier(0);

  for (int t = 0; t < nk; ++t) {
    const int buf = t & 1;
    bf16x8 af[2][4], bf[2][4];
#pragma unroll
    for (int kk = 0; kk < 2; ++kk) {
#pragma unroll
      for (int mi = 0; mi < 4; ++mi) {
        int r = wm + mi * 16 + fr;
        af[kk][mi] = *(const bf16x8*)((const char*)&As[buf][0] + r * 128 +
                       ((kk * 64 + kq16) ^ ((r & 7) << 4)));
      }
#pragma unroll
      for (int ni = 0; ni < 4; ++ni) {
        int r = wc + ni * 16 + fr;
        bf[kk][ni] = *(const bf16x8*)((const char*)&Bs[buf][0] + r * 128 +
                       ((kk * 64 + kq16) ^ ((r & 7) << 4)));
      }
    }
    asm volatile("s_waitcnt lgkmcnt(8)" ::: "memory");
    __builtin_amdgcn_sched_barrier(0);
    __builtin_amdgcn_s_setprio(1);
#pragma unroll
    for (int mi = 0; mi < 4; ++mi)
#pragma unroll
      for (int ni = 0; ni < 4; ++ni)
        acc[mi][ni] = __builtin_amdgcn_mfma_f32_16x16x32_bf16(
            af[0][mi], bf[0][ni], acc[mi][ni], 0, 0, 0);
    __builtin_amdgcn_s_setprio(0);
    __builtin_amdgcn_sched_barrier(0);
    asm volatile("s_waitcnt lgkmcnt(0)" ::: "memory");
    __builtin_amdgcn_sched_barrier(0);
    __builtin_amdgcn_s_barrier();
    __builtin_amdgcn_sched_barrier(0);
    if (t + 2 < nk) stage(buf, kbeg + (t + 2) * 64);
    __builtin_amdgcn_s_setprio(1);
#pragma unroll
    for (int mi = 0; mi < 4; ++mi)
#pragma unroll
      for (int ni = 0; ni < 4; ++ni)
        acc[mi][ni] = __builtin_amdgcn_mfma_f32_16x16x32_bf16(
            af[1][mi], bf[1][ni], acc[mi][ni], 0, 0, 0);
    __builtin_amdgcn_s_setprio(0);
    if (t + 1 < nk) {
      if (t + 2 < nk) asm volatile("s_waitcnt vmcnt(6)" ::: "memory");
      else            asm volatile("s_waitcnt vmcnt(0)" ::: "memory");
      __builtin_amdgcn_s_barrier();
      __builtin_amdgcn_sched_barrier(0);
    }
  }

  const int crow = (lane >> 4) * 4;
  const int ccol = lane & 15;
#pragma unroll
  for (int mi = 0; mi < 4; ++mi)
#pragma unroll
    for (int ni = 0; ni < 4; ++ni)
#pragma unroll
      for (int j = 0; j < 4; ++j)
        epi_store<EPI>(acc[mi][ni][j], m0 + wm + mi * 16 + crow + j,
                       n0 + wc + ni * 16 + ccol, N, Cz, bias, res, obf, ogate,
                       bzi);
}

extern "C" void kernel_launch(void* const* d_in, const int* in_sizes, int n_in,
                              void* d_out, int out_size, void* d_ws, size_t ws_size,
                              hipStream_t stream) {
  const float* x       = (const float*)d_in[0];
  const float* A_log   = (const float*)d_in[1];
  const float* g1      = (const float*)d_in[2];
  const float* g2      = (const float*)d_in[3];
  const float* W_in    = (const float*)d_in[4];
  const float* W_param = (const float*)d_in[5];
  const float* W_out   = (const float*)d_in[6];
  const float* W_ffn1  = (const float*)d_in[7];
  const float* b_ffn1  = (const float*)d_in[8];
  const float* W_ffn2  = (const float*)d_in[9];
  const float* b_ffn2  = (const float*)d_in[10];
  float* out = (float*)d_out;

  char* ws = (char*)d_ws;
  size_t off = 0;
  auto alloc = [&](size_t bytes) {
    char* p = ws + off;
    off += (bytes + 255) & ~(size_t)255;
    return p;
  };
  bf16_t* wb_in  = (bf16_t*)alloc(4096ull * 1024 * 2);
  bf16_t* wb_par = (bf16_t*)alloc((size_t)PPAD * 2048 * 2);
  bf16_t* wb_out = (bf16_t*)alloc(1024ull * 2048 * 2);
  bf16_t* wb_f1  = (bf16_t*)alloc(4096ull * 1024 * 2);
  bf16_t* wb_f2  = (bf16_t*)alloc(1024ull * 4096 * 2);
  bf16_t* zbuf   = (bf16_t*)alloc(2048ull * 1024 * 2);   // z, later h2
  float*  xzg    = (float*)alloc(2048ull * 4096 * 4);    // sgate bf16 (sk) / fp32 (fallback)
  float*  params = (float*)alloc(2048ull * PPAD * 4);    // fallback only; S/Etot overlay
  float*  ssmp   = (float*)alloc(32ull * 1024 * 48 * 4); // fallback only
  float*  xmid   = (float*)alloc(2048ull * 1024 * 4);
  char*   regA   = alloc(2048ull * 4096 * 2);            // 16MB union
  bf16_t* xz_act = (bf16_t*)regA;
  bf16_t* y_b16  = (bf16_t*)(regA + 2048ull * 2048 * 2);
  bf16_t* f_act  = (bf16_t*)regA;
  bf16_t* sgate  = (bf16_t*)xzg;                         // [2048][2048] bf16 (sk)
  float* Sbuf = params;
  float* Etot = params + 32ull * 16 * 16 * 128;
  float* Hbuf = xmid;
  float*  psum = (float*)alloc(4ull * ROWS * 1024 * 4);  // fp32 partials (fallback)
  bf16_t* pb16 = (bf16_t*)psum;                          // bf16 partials overlay
  const bool sk = (off <= ws_size);

  dim3 b256(256), b512(512);
  // W_in/W_param -> bf16 + z = rmsnorm(x,g1)
  prep0<<<7424, b256, 0, stream>>>(W_in, W_param, wb_in, wb_par, x, g1, zbuf);

  if (sk) {
    // xz|gate = z @ W_in^T, fused: silu(xz)->xz_act, silu(gate)->sgate (bf16)
    gemm_big<4><<<dim3(16, 16), b512, 0, stream>>>(zbuf, wb_in, psum, nullptr, nullptr, xz_act, sgate, 4096, 1024);
    // param partials (bf16, SK=4) + W_out/W_f1/W_f2 conversion riding along
    gemm_param_conv<<<10560, b256, 0, stream>>>(xz_act, wb_par, pb16,
                                                W_out, W_ffn1, W_ffn2,
                                                wb_out, wb_f1, wb_f2);
    // chunked scan (coefficient prep inlined from bf16 partials)
    ssm_chunk<1><<<512, b256, 0, stream>>>(nullptr, pb16, A_log, xz_act, Sbuf, Etot);
    ssm_combine<<<256, b256, 0, stream>>>(Sbuf, Etot, Hbuf);
    ssm_out<1, 1><<<512, b256, 0, stream>>>(nullptr, pb16, A_log, xz_act, Hbuf, nullptr, sgate, 2048, y_b16);
    // xmid = x + y @ W_out^T (SK=4, bf16 partials) fused reduce+rmsnorm
    gemm_big<16><<<dim3(4, 16, 4), b512, 0, stream>>>(y_b16, wb_out, psum, nullptr, nullptr, pb16, nullptr, 1024, 512);
    reduce_rms<<<2048, b256, 0, stream>>>(pb16, x, g2, xmid, zbuf);
    // ffn1 + bias + silu -> f_act bf16 (fused)
    gemm_big<9><<<dim3(16, 16), b512, 0, stream>>>(zbuf, wb_f1, psum, b_ffn1, nullptr, f_act, nullptr, 4096, 1024);
    // out = xmid + b_ffn2 + f_act @ W_ffn2^T (SK=4, bf16 partials)
    gemm_big<16><<<dim3(4, 16, 4), b512, 0, stream>>>(f_act, wb_f2, psum, nullptr, nullptr, pb16, nullptr, 1024, 1024);
    reduce_bias<<<2048, b256, 0, stream>>>(pb16, xmid, b_ffn2, out);
  } else {
    cvt3_k<<<10240, b256, 0, stream>>>(W_out, W_ffn1, W_ffn2, wb_out, wb_f1, wb_f2);
    gemm_bt<0><<<dim3(32, 16), b256, 0, stream>>>(zbuf, wb_in, xzg, nullptr, nullptr, nullptr, nullptr, 4096, 1024);
    silu_cvt<<<4096, b256, 0, stream>>>(xzg, xz_act, 4096, 2048);
    gemm_bt<0><<<dim3(PPAD / 128, 16), b256, 0, stream>>>(xz_act, wb_par, params, nullptr, nullptr, nullptr, nullptr, PPAD, 2048);
    ssm_prep<<<128, b256, 0, stream>>>(params, A_log, ssmp);
    ssm_chunk<0><<<512, b256, 0, stream>>>(ssmp, nullptr, A_log, xz_act, Sbuf, Etot);
    ssm_combine<<<256, b256, 0, stream>>>(Sbuf, Etot, Hbuf);
    ssm_out<0, 0><<<512, b256, 0, stream>>>(ssmp, nullptr, A_log, xz_act, Hbuf, xzg + 2048, nullptr, 4096, y_b16);
    gemm_bt<2><<<dim3(8, 16), b256, 0, stream>>>(y_b16, wb_out, xmid, nullptr, x, nullptr, nullptr, 1024, 2048);
    rmsnorm_k<<<2048, b256, 0, stream>>>(xmid, g2, zbuf);
    gemm_bt<1><<<dim3(32, 16), b256, 0, stream>>>(zbuf, wb_f1, xzg, b_ffn1, nullptr, nullptr, nullptr, 4096, 1024);
    silu_cvt<<<8192, b256, 0, stream>>>(xzg, f_act, 4096, 4096);
    gemm_bt<3><<<dim3(8, 16), b256, 0, stream>>>(f_act, wb_f2, out, b_ffn2, xmid, nullptr, nullptr, 1024, 4096);
  }
}

// Round 9
// 170.693 us; speedup vs baseline: 5.9237x; 1.0357x over previous
//
#include <hip/hip_runtime.h>
#include <hip/hip_bf16.h>
#include <stdint.h>

// MambaBlock: B=2, T=1024, D_MODEL=1024, D_INNER=2048, GROUPS=16, D_STATE=16
#define ROWS 2048      // B*T
#define DM   1024
#define DI   2048
#define PPAD 640       // 528 param rows padded to 5*128

typedef __bf16 bf16_t;
typedef __attribute__((ext_vector_type(8))) __bf16 bf16x8;
typedef __attribute__((ext_vector_type(4))) __bf16 bf16x4;
typedef __attribute__((ext_vector_type(4))) float f32x4;
typedef __attribute__((address_space(1))) void gvoid_t;
typedef __attribute__((address_space(3))) void lvoid_t;

// ---------------- prep0: W_in + W_param -> bf16, z = rmsnorm(x,g1) ----------
__global__ __launch_bounds__(256) void prep0(const float* __restrict__ W_in,
                                             const float* __restrict__ W_param,
                                             bf16_t* o_in, bf16_t* o_par,
                                             const float* __restrict__ x,
                                             const float* __restrict__ g1,
                                             bf16_t* __restrict__ zb) {
  int tid = threadIdx.x;
  if (blockIdx.x >= 5376) {  // rmsnorm
    int row = blockIdx.x - 5376;
    const float4 v = *(const float4*)(x + (int64_t)row * DM + tid * 4);
    float ss = v.x * v.x + v.y * v.y + v.z * v.z + v.w * v.w;
#pragma unroll
    for (int o = 32; o; o >>= 1) ss += __shfl_xor(ss, o, 64);
    __shared__ float red[4];
    if ((tid & 63) == 0) red[tid >> 6] = ss;
    __syncthreads();
    float tot = red[0] + red[1] + red[2] + red[3];
    float sc = rsqrtf(tot * (1.0f / DM) + 1e-6f);
    const float4 gv = *(const float4*)(g1 + tid * 4);
    bf16_t* o = zb + (int64_t)row * DM + tid * 4;
    o[0] = (bf16_t)(v.x * sc * gv.x);
    o[1] = (bf16_t)(v.y * sc * gv.y);
    o[2] = (bf16_t)(v.z * sc * gv.z);
    o[3] = (bf16_t)(v.w * sc * gv.w);
    return;
  }
  if (blockIdx.x >= 4096) {  // W_param, zero-padded 528 -> 640 rows
    int64_t e = (((int64_t)(blockIdx.x - 4096)) * 256 + tid) * 4;
    int row = (int)(e >> 11), col = (int)(e & 2047);
    float4 v = make_float4(0.f, 0.f, 0.f, 0.f);
    if (row < 528) v = *(const float4*)(W_param + (int64_t)row * 2048 + col);
    bf16_t* o = o_par + e;
    o[0] = (bf16_t)v.x; o[1] = (bf16_t)v.y; o[2] = (bf16_t)v.z; o[3] = (bf16_t)v.w;
    return;
  }
  int64_t e = ((int64_t)blockIdx.x * 256 + tid) * 4;
  float4 v = *(const float4*)(W_in + e);
  bf16_t* o = o_in + e;
  o[0] = (bf16_t)v.x; o[1] = (bf16_t)v.y; o[2] = (bf16_t)v.z; o[3] = (bf16_t)v.w;
}

// ---------------- conversion of W_out/W_f1/W_f2 (10240 blocks) --------------
__device__ __forceinline__ void conv3(int64_t c, int tid,
                                      const float* __restrict__ W_out,
                                      const float* __restrict__ W_f1,
                                      const float* __restrict__ W_f2,
                                      bf16_t* o_out, bf16_t* o_f1, bf16_t* o_f2) {
  const float* src; bf16_t* dst; int64_t e;
  if (c < 2048) { e = (c * 256 + tid) * 4; src = W_out; dst = o_out; }
  else if (c < 6144) { e = ((c - 2048) * 256 + tid) * 4; src = W_f1; dst = o_f1; }
  else { e = ((c - 6144) * 256 + tid) * 4; src = W_f2; dst = o_f2; }
  float4 v = *(const float4*)(src + e);
  bf16_t* o = dst + e;
  o[0] = (bf16_t)v.x; o[1] = (bf16_t)v.y; o[2] = (bf16_t)v.z; o[3] = (bf16_t)v.w;
}

__global__ __launch_bounds__(256) void cvt3_k(const float* __restrict__ W_out,
                                              const float* __restrict__ W_f1,
                                              const float* __restrict__ W_f2,
                                              bf16_t* o_out, bf16_t* o_f1,
                                              bf16_t* o_f2) {
  conv3(blockIdx.x, threadIdx.x, W_out, W_f1, W_f2, o_out, o_f1, o_f2);
}

// ---------------- rmsnorm (fallback) ----------------
__global__ __launch_bounds__(256) void rmsnorm_k(const float* __restrict__ x,
                                                 const float* __restrict__ g,
                                                 bf16_t* __restrict__ out) {
  int row = blockIdx.x;
  int tid = threadIdx.x;
  const float4 v = *(const float4*)(x + (int64_t)row * DM + tid * 4);
  float ss = v.x * v.x + v.y * v.y + v.z * v.z + v.w * v.w;
#pragma unroll
  for (int o = 32; o; o >>= 1) ss += __shfl_xor(ss, o, 64);
  __shared__ float red[4];
  if ((tid & 63) == 0) red[tid >> 6] = ss;
  __syncthreads();
  float tot = red[0] + red[1] + red[2] + red[3];
  float sc = rsqrtf(tot * (1.0f / DM) + 1e-6f);
  const float4 gv = *(const float4*)(g + tid * 4);
  bf16_t* o = out + (int64_t)row * DM + tid * 4;
  o[0] = (bf16_t)(v.x * sc * gv.x);
  o[1] = (bf16_t)(v.y * sc * gv.y);
  o[2] = (bf16_t)(v.z * sc * gv.z);
  o[3] = (bf16_t)(v.w * sc * gv.w);
}

// ---------------- silu + fp32 -> bf16 (fallback) ----------------
__global__ __launch_bounds__(256) void silu_cvt(const float* __restrict__ in,
                                                bf16_t* __restrict__ out,
                                                int in_stride, int ncols) {
  int64_t e = ((int64_t)blockIdx.x * 256 + threadIdx.x) * 4;
  int row = (int)(e / ncols);
  int col = (int)(e % ncols);
  const float4 v = *(const float4*)(in + (int64_t)row * in_stride + col);
  bf16_t* o = out + e;
  o[0] = (bf16_t)(v.x / (1.f + expf(-v.x)));
  o[1] = (bf16_t)(v.y / (1.f + expf(-v.y)));
  o[2] = (bf16_t)(v.z / (1.f + expf(-v.z)));
  o[3] = (bf16_t)(v.w / (1.f + expf(-v.w)));
}

// ---------------- standalone ssm_prep (fallback only) ----------------------
__global__ __launch_bounds__(256) void ssm_prep(const float* __restrict__ params,
                                                const float* __restrict__ A_log,
                                                float* __restrict__ ssmp) {
  int gid = blockIdx.x * 256 + threadIdx.x;  // 32 * 1024
  int bg = gid >> 10, t = gid & 1023;
  int b = bg >> 4, g = bg & 15;
  const float* pr = params + (int64_t)(b * 1024 + t) * PPAD + g * 33;
  float raw = pr[0];
  float delta = raw > 0.f ? raw + log1pf(expf(-raw)) : log1pf(expf(raw));
  float* o = ssmp + (int64_t)gid * 48;
#pragma unroll
  for (int s = 0; s < 16; ++s) {
    float A = -expf(A_log[s]);
    float dA = delta * A;
    dA = fminf(10.f, fmaxf(-10.f, dA));
    float e = expf(dA);
    float frac = (fabsf(dA) < 1e-4f) ? delta : (e - 1.f) / (A + 1e-12f);
    o[s] = dA;
    o[16 + s] = frac * pr[1 + s];
    o[32 + s] = pr[17 + s];
  }
}

// ---------------- split-K reduce (bf16 partials) + residual + rmsnorm -------
__global__ __launch_bounds__(256) void reduce_rms(const bf16_t* __restrict__ P,
                                                  const float* __restrict__ x,
                                                  const float* __restrict__ g,
                                                  float* __restrict__ xmid,
                                                  bf16_t* __restrict__ zb) {
  int row = blockIdx.x;
  int tid = threadIdx.x;
  int64_t base = (int64_t)row * DM + tid * 4;
  float4 v = *(const float4*)(x + base);
#pragma unroll
  for (int p = 0; p < 4; ++p) {
    bf16x4 pv = *(const bf16x4*)(P + (int64_t)p * ROWS * DM + base);
    v.x += (float)pv[0]; v.y += (float)pv[1]; v.z += (float)pv[2]; v.w += (float)pv[3];
  }
  *(float4*)(xmid + base) = v;
  float ss = v.x * v.x + v.y * v.y + v.z * v.z + v.w * v.w;
#pragma unroll
  for (int o = 32; o; o >>= 1) ss += __shfl_xor(ss, o, 64);
  __shared__ float red[4];
  if ((tid & 63) == 0) red[tid >> 6] = ss;
  __syncthreads();
  float tot = red[0] + red[1] + red[2] + red[3];
  float sc = rsqrtf(tot * (1.0f / DM) + 1e-6f);
  const float4 gv = *(const float4*)(g + tid * 4);
  bf16_t* o = zb + base;
  o[0] = (bf16_t)(v.x * sc * gv.x);
  o[1] = (bf16_t)(v.y * sc * gv.y);
  o[2] = (bf16_t)(v.z * sc * gv.z);
  o[3] = (bf16_t)(v.w * sc * gv.w);
}

__global__ __launch_bounds__(256) void reduce_bias(const bf16_t* __restrict__ P,
                                                   const float* __restrict__ res,
                                                   const float* __restrict__ bias,
                                                   float* __restrict__ out) {
  int64_t e = ((int64_t)blockIdx.x * 256 + threadIdx.x) * 4;
  int col = (int)(e % DM);
  float4 v = *(const float4*)(res + e);
  const float4 bv = *(const float4*)(bias + col);
  v.x += bv.x; v.y += bv.y; v.z += bv.z; v.w += bv.w;
#pragma unroll
  for (int p = 0; p < 4; ++p) {
    bf16x4 pv = *(const bf16x4*)(P + (int64_t)p * ROWS * DM + e);
    v.x += (float)pv[0]; v.y += (float)pv[1]; v.z += (float)pv[2]; v.w += (float)pv[3];
  }
  *(float4*)(out + e) = v;
}

// inline prep: compute 64 rows of coefficients into cf[64*48] from bf16
// split-K partials (4 parts). cf row t: { dA[16], frac*b[16], c[16] }.
__device__ __forceinline__ void prep_rows(const bf16_t* __restrict__ pb,
                                          const float* __restrict__ A_log,
                                          float* cf, int b, int g, int t0,
                                          int tid) {
  if (tid >= 64) return;
  int t = tid;
  int64_t row = (int64_t)(b * 1024) + t0 + t;
  float acc[33];
#pragma unroll
  for (int i = 0; i < 33; ++i) acc[i] = 0.f;
#pragma unroll
  for (int p = 0; p < 4; ++p) {
    const bf16_t* pr = pb + (int64_t)p * ROWS * PPAD + row * PPAD + g * 33;
#pragma unroll
    for (int i = 0; i < 33; ++i) acc[i] += (float)pr[i];
  }
  float raw = acc[0];
  float delta = raw > 0.f ? raw + log1pf(expf(-raw)) : log1pf(expf(raw));
  float* o = cf + t * 48;
#pragma unroll
  for (int s = 0; s < 16; ++s) {
    float A = -expf(A_log[s]);
    float dA = delta * A;
    dA = fminf(10.f, fmaxf(-10.f, dA));
    float e = expf(dA);
    float frac = (fabsf(dA) < 1e-4f) ? delta : (e - 1.f) / (A + 1e-12f);
    o[s] = dA;
    o[16 + s] = frac * acc[1 + s];
    o[32 + s] = acc[17 + s];
  }
}

// Ut layout: element (ch, t) at byte ch*128 + ((t*2) ^ ((ch&7)<<4))

// ---------------- Phase A: per-chunk boundary operator (MFMA) ---------------
template <int PREP>
__global__ __launch_bounds__(256) void ssm_chunk(const float* __restrict__ ssmp,
                                                 const bf16_t* __restrict__ pb,
                                                 const float* __restrict__ A_log,
                                                 const bf16_t* __restrict__ u,
                                                 float* __restrict__ S,
                                                 float* __restrict__ Etot) {
  __shared__ __align__(16) float cf[64 * 48];
  __shared__ __align__(16) float Lb[64 * 16];
  __shared__ __align__(16) bf16_t wl[16 * 64];
  __shared__ __align__(16) bf16_t Ut[128 * 64];
  int bgc = blockIdx.x;
  int bg = bgc >> 4, c = bgc & 15;
  int b = bg >> 4, g = bg & 15;
  int t0 = c * 64;
  int tid = threadIdx.x;
  {
    int lt = tid >> 4;
    int c8 = (tid & 15) * 8;
#pragma unroll
    for (int p = 0; p < 4; ++p) {
      int t = p * 16 + lt;
      bf16x8 v = *(const bf16x8*)(u + ((int64_t)(b * 1024) + t0 + t) * 2048 + g * 128 + c8);
#pragma unroll
      for (int j = 0; j < 8; ++j)
        Ut[(c8 + j) * 64 + (((t >> 3) ^ j) << 3) + (t & 7)] = v[j];
    }
  }
  if (PREP) {
    prep_rows(pb, A_log, cf, b, g, t0, tid);
  } else {
    const float4* src = (const float4*)(ssmp + ((int64_t)bg * 1024 + t0) * 48);
    float4* dst = (float4*)cf;
#pragma unroll
    for (int i = 0; i < 3; ++i) dst[i * 256 + tid] = src[i * 256 + tid];
  }
  __syncthreads();
  if (tid < 16) {
    float l = 0.f;
    for (int t = 0; t < 64; ++t) { l += cf[t * 48 + tid]; Lb[t * 16 + tid] = l; }
  }
  __syncthreads();
  {
    int s = tid >> 4, tb4 = (tid & 15) * 4;
    float lend = Lb[63 * 16 + s];
    bf16x4 wv;
#pragma unroll
    for (int j = 0; j < 4; ++j) {
      int t = tb4 + j;
      wv[j] = (bf16_t)(__expf(lend - Lb[t * 16 + s]) * cf[t * 48 + 16 + s]);
    }
    unsigned byo = (unsigned)(s * 128 + tb4 * 2) ^ ((unsigned)(s & 7) << 4);
    *(bf16x4*)((char*)wl + byo) = wv;
    if (tid < 16) Etot[(int64_t)bgc * 16 + tid] = __expf(Lb[63 * 16 + tid]);
  }
  __syncthreads();
  {
    int lane = tid & 63, wave = tid >> 6;
    int fr = lane & 15, kq = lane >> 4;
    f32x4 acc2[2] = {};
#pragma unroll
    for (int kk = 0; kk < 2; ++kk) {
      int kb = kk * 4 + kq;
      bf16x8 af = *(const bf16x8*)((const char*)wl +
                    ((unsigned)(fr * 128 + kb * 16) ^ ((unsigned)(fr & 7) << 4)));
#pragma unroll
      for (int q = 0; q < 2; ++q) {
        int ch = (wave * 2 + q) * 16 + fr;
        bf16x8 bfr = *(const bf16x8*)((const char*)Ut +
                       ((unsigned)(ch * 128 + kb * 16) ^ ((unsigned)(ch & 7) << 4)));
        acc2[q] = __builtin_amdgcn_mfma_f32_16x16x32_bf16(af, bfr, acc2[q], 0, 0, 0);
      }
    }
    float* Sp = S + (int64_t)bgc * 2048;
#pragma unroll
    for (int q = 0; q < 2; ++q) {
      int ch = (wave * 2 + q) * 16 + fr;
#pragma unroll
      for (int j = 0; j < 4; ++j) Sp[(kq * 4 + j) * 128 + ch] = acc2[q][j];
    }
  }
}

// ---------------- Phase C: combine (inline) + y = tril(K)@U + ce@H + gate ---
template <int PREP, int GM>
__global__ __launch_bounds__(256) void ssm_out(const float* __restrict__ ssmp,
                                               const bf16_t* __restrict__ pb,
                                               const float* __restrict__ A_log,
                                               const bf16_t* __restrict__ u,
                                               const float* __restrict__ S,
                                               const float* __restrict__ Etot,
                                               const float* __restrict__ gate_f,
                                               const bf16_t* __restrict__ gate_b,
                                               int gstride,
                                               bf16_t* __restrict__ yout) {
  __shared__ __align__(16) float cf[64 * 48];
  __shared__ __align__(16) float Lb[64 * 16];
  __shared__ __align__(16) bf16_t Km[64 * 64];
  __shared__ __align__(16) bf16_t Ut[128 * 64];
  __shared__ __align__(16) bf16_t Hb[128 * 32];
  int bgc = blockIdx.x;
  int bg = bgc >> 4, c = bgc & 15;
  int b = bg >> 4, g = bg & 15;
  int t0 = c * 64;
  int tid = threadIdx.x;
  int lane = tid & 63, wave = tid >> 6;
  {
    int lt = tid >> 4;
    int c8 = (tid & 15) * 8;
#pragma unroll
    for (int p = 0; p < 4; ++p) {
      int t = p * 16 + lt;
      bf16x8 v = *(const bf16x8*)(u + ((int64_t)(b * 1024) + t0 + t) * 2048 + g * 128 + c8);
#pragma unroll
      for (int j = 0; j < 8; ++j)
        Ut[(c8 + j) * 64 + (((t >> 3) ^ j) << 3) + (t & 7)] = v[j];
    }
  }
  // inline sequential combine over preceding chunks -> Hb[ch][s] (bf16)
  {
    int ch = tid & 127, s0 = (tid >> 7) * 8;
    const float* Sp = S + (int64_t)(bg * 16) * 2048;
    const float* Ep = Etot + (int64_t)(bg * 16) * 16;
    float h[8];
#pragma unroll
    for (int j = 0; j < 8; ++j) h[j] = 0.f;
    for (int cc = 0; cc < c; ++cc) {
#pragma unroll
      for (int j = 0; j < 8; ++j)
        h[j] = Ep[cc * 16 + s0 + j] * h[j] +
               Sp[(int64_t)cc * 2048 + (s0 + j) * 128 + ch];
    }
#pragma unroll
    for (int j = 0; j < 8; ++j) {
      Hb[ch * 32 + s0 + j] = (bf16_t)h[j];
      Hb[ch * 32 + 16 + s0 + j] = (bf16_t)0.f;
    }
  }
  if (PREP) {
    prep_rows(pb, A_log, cf, b, g, t0, tid);
  } else {
    const float4* src = (const float4*)(ssmp + ((int64_t)bg * 1024 + t0) * 48);
    float4* dst = (float4*)cf;
#pragma unroll
    for (int i = 0; i < 3; ++i) dst[i * 256 + tid] = src[i * 256 + tid];
  }
  __syncthreads();
  if (tid < 16) {
    float l = 0.f;
    for (int t = 0; t < 64; ++t) { l += cf[t * 48 + tid]; Lb[t * 16 + tid] = l; }
  }
  __syncthreads();
  {
    int t = tid >> 2, tp0 = (tid & 3) * 16;
    float4 cv[4], lv[4];
#pragma unroll
    for (int i = 0; i < 4; ++i) {
      cv[i] = *(const float4*)&cf[t * 48 + 32 + i * 4];
      lv[i] = *(const float4*)&Lb[t * 16 + i * 4];
    }
    float kv[16];
#pragma unroll
    for (int i = 0; i < 16; ++i) {
      int tp = tp0 + i;
      float k = 0.f;
      if (tp <= t) {
#pragma unroll
        for (int q = 0; q < 4; ++q) {
          float4 lpv = *(const float4*)&Lb[tp * 16 + q * 4];
          float4 fbv = *(const float4*)&cf[tp * 48 + 16 + q * 4];
          k += cv[q].x * __expf(lv[q].x - lpv.x) * fbv.x
             + cv[q].y * __expf(lv[q].y - lpv.y) * fbv.y
             + cv[q].z * __expf(lv[q].z - lpv.z) * fbv.z
             + cv[q].w * __expf(lv[q].w - lpv.w) * fbv.w;
        }
      }
      kv[i] = k;
    }
    bf16x8 lo, hi;
#pragma unroll
    for (int i = 0; i < 8; ++i) { lo[i] = (bf16_t)kv[i]; hi[i] = (bf16_t)kv[8 + i]; }
    unsigned b0 = (unsigned)(t * 128 + tp0 * 2) ^ ((unsigned)(t & 7) << 4);
    unsigned b1 = (unsigned)(t * 128 + tp0 * 2 + 16) ^ ((unsigned)(t & 7) << 4);
    *(bf16x8*)((char*)Km + b0) = lo;
    *(bf16x8*)((char*)Km + b1) = hi;
  }
  __syncthreads();
  int fr = lane & 15, kq = lane >> 4;
  int trow = (wave >> 1) * 32, wc = (wave & 1) * 64;
  f32x4 acc[2][4] = {};
#pragma unroll
  for (int kk = 0; kk < 2; ++kk) {
    int kb = kk * 4 + kq;
    bf16x8 af[2];
#pragma unroll
    for (int mi = 0; mi < 2; ++mi) {
      int row = trow + mi * 16 + fr;
      af[mi] = *(const bf16x8*)((const char*)Km +
                 ((unsigned)(row * 128 + kb * 16) ^ ((unsigned)(row & 7) << 4)));
    }
#pragma unroll
    for (int ni = 0; ni < 4; ++ni) {
      int ch = wc + ni * 16 + fr;
      bf16x8 bfr = *(const bf16x8*)((const char*)Ut +
                     ((unsigned)(ch * 128 + kb * 16) ^ ((unsigned)(ch & 7) << 4)));
#pragma unroll
      for (int mi = 0; mi < 2; ++mi)
        acc[mi][ni] = __builtin_amdgcn_mfma_f32_16x16x32_bf16(af[mi], bfr, acc[mi][ni], 0, 0, 0);
    }
  }
  {
    int s0 = kq * 8;
    bf16x8 cef[2];
    if (s0 < 16) {
#pragma unroll
      for (int mi = 0; mi < 2; ++mi) {
        int t = trow + mi * 16 + fr;
#pragma unroll
        for (int j = 0; j < 8; ++j)
          cef[mi][j] = (bf16_t)(cf[t * 48 + 32 + s0 + j] * __expf(Lb[t * 16 + s0 + j]));
      }
    } else {
#pragma unroll
      for (int mi = 0; mi < 2; ++mi)
#pragma unroll
        for (int j = 0; j < 8; ++j) cef[mi][j] = (bf16_t)0.f;
    }
#pragma unroll
    for (int ni = 0; ni < 4; ++ni) {
      int ch = wc + ni * 16 + fr;
      bf16x8 bhf = *(const bf16x8*)((const char*)Hb + ch * 64 + s0 * 2);
#pragma unroll
      for (int mi = 0; mi < 2; ++mi)
        acc[mi][ni] = __builtin_amdgcn_mfma_f32_16x16x32_bf16(cef[mi], bhf, acc[mi][ni], 0, 0, 0);
    }
  }
  {
    int64_t rowbase = (int64_t)b * 1024 + t0;
    int colbase = g * 128;
#pragma unroll
    for (int mi = 0; mi < 2; ++mi) {
#pragma unroll
      for (int ni = 0; ni < 4; ++ni) {
        int col = colbase + wc + ni * 16 + fr;
#pragma unroll
        for (int j = 0; j < 4; ++j) {
          int t = trow + mi * 16 + kq * 4 + j;
          float sg;
          if (GM) {
            sg = (float)gate_b[(rowbase + t) * 2048 + col];
          } else {
            float gv = gate_f[(rowbase + t) * (int64_t)gstride + col];
            sg = gv / (1.f + __expf(-gv));
          }
          yout[(rowbase + t) * 2048 + col] = (bf16_t)(acc[mi][ni][j] * sg);
        }
      }
    }
  }
}

// ======== epilogue helper shared by GEMM kernels ========
template <int EPI>
__device__ __forceinline__ void epi_store(float v, int64_t r, int64_t cn, int N,
                                          float* Cz, const float* bias,
                                          const float* res, bf16_t* obf,
                                          bf16_t* ogate, int z) {
  if (EPI & 1) v += bias[cn];
  if (EPI & 2) v += res[r * N + cn];
  if (EPI & 4) {
    float sv = v / (1.f + __expf(-v));
    if (cn < 2048) obf[r * 2048 + cn] = (bf16_t)sv;
    else ogate[r * 2048 + cn - 2048] = (bf16_t)sv;
  } else if (EPI & 8) {
    obf[r * N + cn] = (bf16_t)(v / (1.f + __expf(-v)));
  } else if (EPI & 16) {
    obf[(int64_t)z * ROWS * N + r * N + cn] = (bf16_t)v;
  } else {
    Cz[r * N + cn] = v;
  }
}

// bijective XCD swizzle over flattened grid (identity if nwg%8 != 0)
__device__ __forceinline__ void xcd_swz(int& bx, int& by, int& bz) {
  int gx = gridDim.x, gy = gridDim.y, gz = gridDim.z;
  int flat = blockIdx.x + gx * (blockIdx.y + gy * blockIdx.z);
  int nwg = gx * gy * gz;
  int swz = flat;
  if ((nwg & 7) == 0) swz = (flat & 7) * (nwg >> 3) + (flat >> 3);
  bx = swz % gx;
  int rem = swz / gx;
  by = rem % gy;
  bz = rem / gy;
}

// ---------------- bf16 GEMM 128x128, double-buffered 2-phase (fallback) -----
template <int EPI>
__global__ __launch_bounds__(256) void gemm_bt(const bf16_t* __restrict__ A,
                                               const bf16_t* __restrict__ Bw,
                                               float* __restrict__ C,
                                               const float* __restrict__ bias,
                                               const float* __restrict__ res,
                                               bf16_t* __restrict__ obf,
                                               bf16_t* __restrict__ ogate,
                                               int N, int Kps) {
  __shared__ bf16_t As[2][128 * 64];
  __shared__ bf16_t Bs[2][128 * 64];
  const int tid = threadIdx.x;
  const int wave = tid >> 6;
  const int lane = tid & 63;
  int bxi, byi, bzi;
  xcd_swz(bxi, byi, bzi);
  const int64_t m0 = (int64_t)byi * 128;
  const int64_t n0 = (int64_t)bxi * 128;
  const int K = Kps * gridDim.z;
  const int kbeg = bzi * Kps;
  float* Cz = C + (int64_t)bzi * ROWS * N;
  const int wm = (wave >> 1) * 64;
  const int wn = (wave & 1) * 64;
  f32x4 acc[4][4] = {};

  const int er = tid >> 3;
  const int ec = (tid * 8) & 63;
  const int fr = lane & 15;
  const int kq = (lane >> 4) * 8;

  auto stage = [&](int buf, int k0) {
#pragma unroll
    for (int i = 0; i < 4; ++i) {
      const bf16_t* ga = A + (m0 + er + i * 32) * K + k0 + ec;
      __builtin_amdgcn_global_load_lds((gvoid_t*)ga,
                                       (lvoid_t*)&As[buf][(i * 256 + wave * 64) * 8],
                                       16, 0, 0);
    }
#pragma unroll
    for (int i = 0; i < 4; ++i) {
      const bf16_t* gb = Bw + (n0 + er + i * 32) * K + k0 + ec;
      __builtin_amdgcn_global_load_lds((gvoid_t*)gb,
                                       (lvoid_t*)&Bs[buf][(i * 256 + wave * 64) * 8],
                                       16, 0, 0);
    }
  };
  auto compute = [&](int buf) {
#pragma unroll
    for (int kk = 0; kk < 2; ++kk) {
      bf16x8 af[4], bv[4];
#pragma unroll
      for (int mi = 0; mi < 4; ++mi)
        af[mi] = *reinterpret_cast<const bf16x8*>(&As[buf][(wm + mi * 16 + fr) * 64 + kk * 32 + kq]);
#pragma unroll
      for (int ni = 0; ni < 4; ++ni)
        bv[ni] = *reinterpret_cast<const bf16x8*>(&Bs[buf][(wn + ni * 16 + fr) * 64 + kk * 32 + kq]);
#pragma unroll
      for (int mi = 0; mi < 4; ++mi)
#pragma unroll
        for (int ni = 0; ni < 4; ++ni)
          acc[mi][ni] = __builtin_amdgcn_mfma_f32_16x16x32_bf16(af[mi], bv[ni], acc[mi][ni], 0, 0, 0);
    }
  };

  const int nk = Kps >> 6;  // assumed even
  stage(0, kbeg);
  asm volatile("s_waitcnt vmcnt(0)" ::: "memory");
  __builtin_amdgcn_s_barrier();
  int kc = kbeg;
  for (int t = 0; t < nk; t += 2) {
    stage(1, kc + 64);
    compute(0);
    asm volatile("s_waitcnt vmcnt(0)" ::: "memory");
    __builtin_amdgcn_s_barrier();
    if (t + 2 < nk) stage(0, kc + 128);
    compute(1);
    asm volatile("s_waitcnt vmcnt(0)" ::: "memory");
    __builtin_amdgcn_s_barrier();
    kc += 128;
  }

  const int crow = (lane >> 4) * 4;
  const int ccol = lane & 15;
#pragma unroll
  for (int mi = 0; mi < 4; ++mi)
#pragma unroll
    for (int ni = 0; ni < 4; ++ni)
#pragma unroll
      for (int j = 0; j < 4; ++j)
        epi_store<EPI>(acc[mi][ni][j], m0 + wm + mi * 16 + crow + j,
                       n0 + wn + ni * 16 + ccol, N, Cz, bias, res, obf, ogate,
                       bzi);
}

// ---------------- param GEMM (128x128, SK=4) + W_out/W_f1/W_f2 conversion ---
__global__ __launch_bounds__(256) void gemm_param_conv(
    const bf16_t* __restrict__ A, const bf16_t* __restrict__ Bw,
    bf16_t* __restrict__ pout,
    const float* __restrict__ W_out, const float* __restrict__ W_f1,
    const float* __restrict__ W_f2,
    bf16_t* o_out, bf16_t* o_f1, bf16_t* o_f2) {
  __shared__ bf16_t As[2][128 * 64];
  __shared__ bf16_t Bs[2][128 * 64];
  const int tid = threadIdx.x;
  if (blockIdx.x >= 320) {
    conv3(blockIdx.x - 320, tid, W_out, W_f1, W_f2, o_out, o_f1, o_f2);
    return;
  }
  const int flat = blockIdx.x;
  const int swz = (flat & 7) * 40 + (flat >> 3);  // 320 % 8 == 0, bijective
  const int bxi = swz % 5;
  const int byi = (swz / 5) % 16;
  const int bzi = swz / 80;
  const int wave = tid >> 6;
  const int lane = tid & 63;
  const int64_t m0 = (int64_t)byi * 128;
  const int64_t n0 = (int64_t)bxi * 128;
  const int K = 2048, Kps = 512;
  const int kbeg = bzi * Kps;
  const int wm = (wave >> 1) * 64;
  const int wn = (wave & 1) * 64;
  f32x4 acc[4][4] = {};
  const int er = tid >> 3;
  const int ec = (tid * 8) & 63;
  const int fr = lane & 15;
  const int kq = (lane >> 4) * 8;

  auto stage = [&](int buf, int k0) {
#pragma unroll
    for (int i = 0; i < 4; ++i) {
      const bf16_t* ga = A + (m0 + er + i * 32) * K + k0 + ec;
      __builtin_amdgcn_global_load_lds((gvoid_t*)ga,
                                       (lvoid_t*)&As[buf][(i * 256 + wave * 64) * 8],
                                       16, 0, 0);
    }
#pragma unroll
    for (int i = 0; i < 4; ++i) {
      const bf16_t* gb = Bw + (n0 + er + i * 32) * K + k0 + ec;
      __builtin_amdgcn_global_load_lds((gvoid_t*)gb,
                                       (lvoid_t*)&Bs[buf][(i * 256 + wave * 64) * 8],
                                       16, 0, 0);
    }
  };
  auto compute = [&](int buf) {
#pragma unroll
    for (int kk = 0; kk < 2; ++kk) {
      bf16x8 af[4], bv[4];
#pragma unroll
      for (int mi = 0; mi < 4; ++mi)
        af[mi] = *reinterpret_cast<const bf16x8*>(&As[buf][(wm + mi * 16 + fr) * 64 + kk * 32 + kq]);
#pragma unroll
      for (int ni = 0; ni < 4; ++ni)
        bv[ni] = *reinterpret_cast<const bf16x8*>(&Bs[buf][(wn + ni * 16 + fr) * 64 + kk * 32 + kq]);
#pragma unroll
      for (int mi = 0; mi < 4; ++mi)
#pragma unroll
        for (int ni = 0; ni < 4; ++ni)
          acc[mi][ni] = __builtin_amdgcn_mfma_f32_16x16x32_bf16(af[mi], bv[ni], acc[mi][ni], 0, 0, 0);
    }
  };

  const int nk = Kps >> 6;  // 8
  stage(0, kbeg);
  asm volatile("s_waitcnt vmcnt(0)" ::: "memory");
  __builtin_amdgcn_s_barrier();
  int kc = kbeg;
  for (int t = 0; t < nk; t += 2) {
    stage(1, kc + 64);
    compute(0);
    asm volatile("s_waitcnt vmcnt(0)" ::: "memory");
    __builtin_amdgcn_s_barrier();
    if (t + 2 < nk) stage(0, kc + 128);
    compute(1);
    asm volatile("s_waitcnt vmcnt(0)" ::: "memory");
    __builtin_amdgcn_s_barrier();
    kc += 128;
  }

  const int crow = (lane >> 4) * 4;
  const int ccol = lane & 15;
  bf16_t* pz = pout + (int64_t)bzi * ROWS * PPAD;
#pragma unroll
  for (int mi = 0; mi < 4; ++mi)
#pragma unroll
    for (int ni = 0; ni < 4; ++ni)
#pragma unroll
      for (int j = 0; j < 4; ++j) {
        int64_t r = m0 + wm + mi * 16 + crow + j;
        int64_t cn = n0 + wn + ni * 16 + ccol;
        pz[r * PPAD + cn] = (bf16_t)acc[mi][ni][j];
      }
}

// ---------------- bf16 GEMM 128x256, 8-wave, depth-3 counted-vmcnt pipeline --
// Per K-tile: reads -> lgkm(8) -> MFMA Q0 -> stage((t+2)%3) -> MFMA Q1 ->
// vmcnt(6)+barrier. ONE barrier per tile: stage targets the buffer read at
// tile t-1, whose reads were consumed before tile t-1's closing barrier.
template <int EPI>
__global__ __launch_bounds__(512) void gemm_big(const bf16_t* __restrict__ A,
                                                const bf16_t* __restrict__ Bw,
                                                float* __restrict__ C,
                                                const float* __restrict__ bias,
                                                const float* __restrict__ res,
                                                bf16_t* __restrict__ obf,
                                                bf16_t* __restrict__ ogate,
                                                int N, int Kps) {
  __shared__ bf16_t As[3][128 * 64];
  __shared__ bf16_t Bs[3][256 * 64];
  const int tid = threadIdx.x;
  const int wave = tid >> 6;
  const int lane = tid & 63;
  int bxi, byi, bzi;
  xcd_swz(bxi, byi, bzi);
  const int64_t m0 = (int64_t)byi * 128;
  const int64_t n0 = (int64_t)bxi * 256;
  const int K = Kps * gridDim.z;
  const int kbeg = bzi * Kps;
  float* Cz = C + (int64_t)bzi * ROWS * N;
  const int wm = (wave >> 2) * 64;
  const int wc = (wave & 3) * 64;
  const int fr = lane & 15;
  const int kq16 = (lane >> 4) * 16;
  const int er = tid >> 3;
  const int ec_sw = ((tid & 7) * 8) ^ ((er & 7) << 3);
  f32x4 acc[4][4] = {};

  auto stage = [&](int buf, int k0) {
#pragma unroll
    for (int i = 0; i < 2; ++i) {
      const bf16_t* ga = A + (m0 + er + i * 64) * K + k0 + ec_sw;
      __builtin_amdgcn_global_load_lds((gvoid_t*)ga,
          (lvoid_t*)((char*)&As[buf][0] + i * 8192 + wave * 1024), 16, 0, 0);
    }
#pragma unroll
    for (int i = 0; i < 4; ++i) {
      const bf16_t* gb = Bw + (n0 + er + i * 64) * K + k0 + ec_sw;
      __builtin_amdgcn_global_load_lds((gvoid_t*)gb,
          (lvoid_t*)((char*)&Bs[buf][0] + i * 8192 + wave * 1024), 16, 0, 0);
    }
  };

  const int nk = Kps >> 6;
  stage(0, kbeg);
  if (nk > 1) {
    stage(1, kbeg + 64);
    asm volatile("s_waitcnt vmcnt(6)" ::: "memory");
  } else {
    asm volatile("s_waitcnt vmcnt(0)" ::: "memory");
  }
  __builtin_amdgcn_s_barrier();
  __builtin_amdgcn_sched_barrier(0);

  for (int t = 0; t < nk; ++t) {
    const int buf = t % 3;
    bf16x8 af[2][4], bf[2][4];
#pragma unroll
    for (int kk = 0; kk < 2; ++kk) {
#pragma unroll
      for (int mi = 0; mi < 4; ++mi) {
        int r = wm + mi * 16 + fr;
        af[kk][mi] = *(const bf16x8*)((const char*)&As[buf][0] + r * 128 +
                       ((kk * 64 + kq16) ^ ((r & 7) << 4)));
      }
#pragma unroll
      for (int ni = 0; ni < 4; ++ni) {
        int r = wc + ni * 16 + fr;
        bf[kk][ni] = *(const bf16x8*)((const char*)&Bs[buf][0] + r * 128 +
                       ((kk * 64 + kq16) ^ ((r & 7) << 4)));
      }
    }
    asm volatile("s_waitcnt lgkmcnt(8)" ::: "memory");
    __builtin_amdgcn_sched_barrier(0);
    __builtin_amdgcn_s_setprio(1);
#pragma unroll
    for (int mi = 0; mi < 4; ++mi)
#pragma unroll
      for (int ni = 0; ni < 4; ++ni)
        acc[mi][ni] = __builtin_amdgcn_mfma_f32_16x16x32_bf16(
            af[0][mi], bf[0][ni], acc[mi][ni], 0, 0, 0);
    __builtin_amdgcn_s_setprio(0);
    __builtin_amdgcn_sched_barrier(0);
    if (t + 2 < nk) stage((t + 2) % 3, kbeg + (t + 2) * 64);
    // compiler inserts lgkmcnt for Q1's ds_read results
    __builtin_amdgcn_s_setprio(1);
#pragma unroll
    for (int mi = 0; mi < 4; ++mi)
#pragma unroll
      for (int ni = 0; ni < 4; ++ni)
        acc[mi][ni] = __builtin_amdgcn_mfma_f32_16x16x32_bf16(
            af[1][mi], bf[1][ni], acc[mi][ni], 0, 0, 0);
    __builtin_amdgcn_s_setprio(0);
    if (t + 1 < nk) {
      if (t + 2 < nk) asm volatile("s_waitcnt vmcnt(6)" ::: "memory");
      else            asm volatile("s_waitcnt vmcnt(0)" ::: "memory");
      __builtin_amdgcn_s_barrier();   // stage(t+1) landed; reads of buf done pre-MFMA
      __builtin_amdgcn_sched_barrier(0);
    }
  }

  const int crow = (lane >> 4) * 4;
  const int ccol = lane & 15;
#pragma unroll
  for (int mi = 0; mi < 4; ++mi)
#pragma unroll
    for (int ni = 0; ni < 4; ++ni)
#pragma unroll
      for (int j = 0; j < 4; ++j)
        epi_store<EPI>(acc[mi][ni][j], m0 + wm + mi * 16 + crow + j,
                       n0 + wc + ni * 16 + ccol, N, Cz, bias, res, obf, ogate,
                       bzi);
}

extern "C" void kernel_launch(void* const* d_in, const int* in_sizes, int n_in,
                              void* d_out, int out_size, void* d_ws, size_t ws_size,
                              hipStream_t stream) {
  const float* x       = (const float*)d_in[0];
  const float* A_log   = (const float*)d_in[1];
  const float* g1      = (const float*)d_in[2];
  const float* g2      = (const float*)d_in[3];
  const float* W_in    = (const float*)d_in[4];
  const float* W_param = (const float*)d_in[5];
  const float* W_out   = (const float*)d_in[6];
  const float* W_ffn1  = (const float*)d_in[7];
  const float* b_ffn1  = (const float*)d_in[8];
  const float* W_ffn2  = (const float*)d_in[9];
  const float* b_ffn2  = (const float*)d_in[10];
  float* out = (float*)d_out;

  char* ws = (char*)d_ws;
  size_t off = 0;
  auto alloc = [&](size_t bytes) {
    char* p = ws + off;
    off += (bytes + 255) & ~(size_t)255;
    return p;
  };
  bf16_t* wb_in  = (bf16_t*)alloc(4096ull * 1024 * 2);
  bf16_t* wb_par = (bf16_t*)alloc((size_t)PPAD * 2048 * 2);
  bf16_t* wb_out = (bf16_t*)alloc(1024ull * 2048 * 2);
  bf16_t* wb_f1  = (bf16_t*)alloc(4096ull * 1024 * 2);
  bf16_t* wb_f2  = (bf16_t*)alloc(1024ull * 4096 * 2);
  bf16_t* zbuf   = (bf16_t*)alloc(2048ull * 1024 * 2);   // z, later h2
  float*  xzg    = (float*)alloc(2048ull * 4096 * 4);    // sgate bf16 (sk) / fp32 (fallback)
  float*  params = (float*)alloc(2048ull * PPAD * 4);    // fallback GEMM out; S/Etot overlay
  float*  ssmp   = (float*)alloc(32ull * 1024 * 48 * 4); // fallback only
  float*  xmid   = (float*)alloc(2048ull * 1024 * 4);
  char*   regA   = alloc(2048ull * 4096 * 2);            // 16MB union
  bf16_t* xz_act = (bf16_t*)regA;
  bf16_t* y_b16  = (bf16_t*)(regA + 2048ull * 2048 * 2);
  bf16_t* f_act  = (bf16_t*)regA;
  bf16_t* sgate  = (bf16_t*)xzg;                         // [2048][2048] bf16 (sk)
  float* Sbuf = params;
  float* Etot = params + 32ull * 16 * 16 * 128;
  float*  psum = (float*)alloc(4ull * ROWS * 1024 * 4);  // fp32 partials (fallback)
  bf16_t* pb16 = (bf16_t*)psum;                          // bf16 partials overlay
  const bool sk = (off <= ws_size);

  dim3 b256(256), b512(512);
  // W_in/W_param -> bf16 + z = rmsnorm(x,g1)
  prep0<<<7424, b256, 0, stream>>>(W_in, W_param, wb_in, wb_par, x, g1, zbuf);

  if (sk) {
    // xz|gate = z @ W_in^T, fused: silu(xz)->xz_act, silu(gate)->sgate (bf16)
    gemm_big<4><<<dim3(16, 16), b512, 0, stream>>>(zbuf, wb_in, psum, nullptr, nullptr, xz_act, sgate, 4096, 1024);
    // param partials (bf16, SK=4) + W_out/W_f1/W_f2 conversion riding along
    gemm_param_conv<<<10560, b256, 0, stream>>>(xz_act, wb_par, pb16,
                                                W_out, W_ffn1, W_ffn2,
                                                wb_out, wb_f1, wb_f2);
    // chunked scan (coefficient prep inlined; combine inlined in ssm_out)
    ssm_chunk<1><<<512, b256, 0, stream>>>(nullptr, pb16, A_log, xz_act, Sbuf, Etot);
    ssm_out<1, 1><<<512, b256, 0, stream>>>(nullptr, pb16, A_log, xz_act, Sbuf, Etot, nullptr, sgate, 2048, y_b16);
    // xmid = x + y @ W_out^T (SK=4, bf16 partials) fused reduce+rmsnorm
    gemm_big<16><<<dim3(4, 16, 4), b512, 0, stream>>>(y_b16, wb_out, psum, nullptr, nullptr, pb16, nullptr, 1024, 512);
    reduce_rms<<<2048, b256, 0, stream>>>(pb16, x, g2, xmid, zbuf);
    // ffn1 + bias + silu -> f_act bf16 (fused)
    gemm_big<9><<<dim3(16, 16), b512, 0, stream>>>(zbuf, wb_f1, psum, b_ffn1, nullptr, f_act, nullptr, 4096, 1024);
    // out = xmid + b_ffn2 + f_act @ W_ffn2^T (SK=4, bf16 partials)
    gemm_big<16><<<dim3(4, 16, 4), b512, 0, stream>>>(f_act, wb_f2, psum, nullptr, nullptr, pb16, nullptr, 1024, 1024);
    reduce_bias<<<2048, b256, 0, stream>>>(pb16, xmid, b_ffn2, out);
  } else {
    cvt3_k<<<10240, b256, 0, stream>>>(W_out, W_ffn1, W_ffn2, wb_out, wb_f1, wb_f2);
    gemm_bt<0><<<dim3(32, 16), b256, 0, stream>>>(zbuf, wb_in, xzg, nullptr, nullptr, nullptr, nullptr, 4096, 1024);
    silu_cvt<<<4096, b256, 0, stream>>>(xzg, xz_act, 4096, 2048);
    gemm_bt<0><<<dim3(PPAD / 128, 16), b256, 0, stream>>>(xz_act, wb_par, params, nullptr, nullptr, nullptr, nullptr, PPAD, 2048);
    ssm_prep<<<128, b256, 0, stream>>>(params, A_log, ssmp);
    ssm_chunk<0><<<512, b256, 0, stream>>>(ssmp, nullptr, A_log, xz_act, Sbuf, Etot);
    ssm_out<0, 0><<<512, b256, 0, stream>>>(ssmp, nullptr, A_log, xz_act, Sbuf, Etot, xzg + 2048, nullptr, 4096, y_b16);
    gemm_bt<2><<<dim3(8, 16), b256, 0, stream>>>(y_b16, wb_out, xmid, nullptr, x, nullptr, nullptr, 1024, 2048);
    rmsnorm_k<<<2048, b256, 0, stream>>>(xmid, g2, zbuf);
    gemm_bt<1><<<dim3(32, 16), b256, 0, stream>>>(zbuf, wb_f1, xzg, b_ffn1, nullptr, nullptr, nullptr, 4096, 1024);
    silu_cvt<<<8192, b256, 0, stream>>>(xzg, f_act, 4096, 4096);
    gemm_bt<3><<<dim3(8, 16), b256, 0, stream>>>(f_act, wb_f2, out, b_ffn2, xmid, nullptr, nullptr, 1024, 4096);
  }
}

// Round 10
// 170.681 us; speedup vs baseline: 5.9242x; 1.0001x over previous
//
#include <hip/hip_runtime.h>
#include <hip/hip_bf16.h>
#include <stdint.h>

// MambaBlock: B=2, T=1024, D_MODEL=1024, D_INNER=2048, GROUPS=16, D_STATE=16
#define ROWS 2048      // B*T
#define DM   1024
#define DI   2048
#define PPAD 640       // 528 param rows padded to 5*128

typedef __bf16 bf16_t;
typedef __attribute__((ext_vector_type(8))) __bf16 bf16x8;
typedef __attribute__((ext_vector_type(4))) __bf16 bf16x4;
typedef __attribute__((ext_vector_type(4))) float f32x4;
typedef __attribute__((address_space(1))) void gvoid_t;
typedef __attribute__((address_space(3))) void lvoid_t;

// ---------------- prep0: W_in + W_param -> bf16, z = rmsnorm(x,g1) ----------
__global__ __launch_bounds__(256) void prep0(const float* __restrict__ W_in,
                                             const float* __restrict__ W_param,
                                             bf16_t* o_in, bf16_t* o_par,
                                             const float* __restrict__ x,
                                             const float* __restrict__ g1,
                                             bf16_t* __restrict__ zb) {
  int tid = threadIdx.x;
  if (blockIdx.x >= 5376) {  // rmsnorm
    int row = blockIdx.x - 5376;
    const float4 v = *(const float4*)(x + (int64_t)row * DM + tid * 4);
    float ss = v.x * v.x + v.y * v.y + v.z * v.z + v.w * v.w;
#pragma unroll
    for (int o = 32; o; o >>= 1) ss += __shfl_xor(ss, o, 64);
    __shared__ float red[4];
    if ((tid & 63) == 0) red[tid >> 6] = ss;
    __syncthreads();
    float tot = red[0] + red[1] + red[2] + red[3];
    float sc = rsqrtf(tot * (1.0f / DM) + 1e-6f);
    const float4 gv = *(const float4*)(g1 + tid * 4);
    bf16_t* o = zb + (int64_t)row * DM + tid * 4;
    o[0] = (bf16_t)(v.x * sc * gv.x);
    o[1] = (bf16_t)(v.y * sc * gv.y);
    o[2] = (bf16_t)(v.z * sc * gv.z);
    o[3] = (bf16_t)(v.w * sc * gv.w);
    return;
  }
  if (blockIdx.x >= 4096) {  // W_param, zero-padded 528 -> 640 rows
    int64_t e = (((int64_t)(blockIdx.x - 4096)) * 256 + tid) * 4;
    int row = (int)(e >> 11), col = (int)(e & 2047);
    float4 v = make_float4(0.f, 0.f, 0.f, 0.f);
    if (row < 528) v = *(const float4*)(W_param + (int64_t)row * 2048 + col);
    bf16_t* o = o_par + e;
    o[0] = (bf16_t)v.x; o[1] = (bf16_t)v.y; o[2] = (bf16_t)v.z; o[3] = (bf16_t)v.w;
    return;
  }
  int64_t e = ((int64_t)blockIdx.x * 256 + tid) * 4;
  float4 v = *(const float4*)(W_in + e);
  bf16_t* o = o_in + e;
  o[0] = (bf16_t)v.x; o[1] = (bf16_t)v.y; o[2] = (bf16_t)v.z; o[3] = (bf16_t)v.w;
}

// ---------------- conversion of W_out/W_f1/W_f2 (10240 blocks) --------------
__device__ __forceinline__ void conv3(int64_t c, int tid,
                                      const float* __restrict__ W_out,
                                      const float* __restrict__ W_f1,
                                      const float* __restrict__ W_f2,
                                      bf16_t* o_out, bf16_t* o_f1, bf16_t* o_f2) {
  const float* src; bf16_t* dst; int64_t e;
  if (c < 2048) { e = (c * 256 + tid) * 4; src = W_out; dst = o_out; }
  else if (c < 6144) { e = ((c - 2048) * 256 + tid) * 4; src = W_f1; dst = o_f1; }
  else { e = ((c - 6144) * 256 + tid) * 4; src = W_f2; dst = o_f2; }
  float4 v = *(const float4*)(src + e);
  bf16_t* o = dst + e;
  o[0] = (bf16_t)v.x; o[1] = (bf16_t)v.y; o[2] = (bf16_t)v.z; o[3] = (bf16_t)v.w;
}

__global__ __launch_bounds__(256) void cvt3_k(const float* __restrict__ W_out,
                                              const float* __restrict__ W_f1,
                                              const float* __restrict__ W_f2,
                                              bf16_t* o_out, bf16_t* o_f1,
                                              bf16_t* o_f2) {
  conv3(blockIdx.x, threadIdx.x, W_out, W_f1, W_f2, o_out, o_f1, o_f2);
}

// ---------------- rmsnorm (fallback) ----------------
__global__ __launch_bounds__(256) void rmsnorm_k(const float* __restrict__ x,
                                                 const float* __restrict__ g,
                                                 bf16_t* __restrict__ out) {
  int row = blockIdx.x;
  int tid = threadIdx.x;
  const float4 v = *(const float4*)(x + (int64_t)row * DM + tid * 4);
  float ss = v.x * v.x + v.y * v.y + v.z * v.z + v.w * v.w;
#pragma unroll
  for (int o = 32; o; o >>= 1) ss += __shfl_xor(ss, o, 64);
  __shared__ float red[4];
  if ((tid & 63) == 0) red[tid >> 6] = ss;
  __syncthreads();
  float tot = red[0] + red[1] + red[2] + red[3];
  float sc = rsqrtf(tot * (1.0f / DM) + 1e-6f);
  const float4 gv = *(const float4*)(g + tid * 4);
  bf16_t* o = out + (int64_t)row * DM + tid * 4;
  o[0] = (bf16_t)(v.x * sc * gv.x);
  o[1] = (bf16_t)(v.y * sc * gv.y);
  o[2] = (bf16_t)(v.z * sc * gv.z);
  o[3] = (bf16_t)(v.w * sc * gv.w);
}

// ---------------- silu + fp32 -> bf16 (fallback) ----------------
__global__ __launch_bounds__(256) void silu_cvt(const float* __restrict__ in,
                                                bf16_t* __restrict__ out,
                                                int in_stride, int ncols) {
  int64_t e = ((int64_t)blockIdx.x * 256 + threadIdx.x) * 4;
  int row = (int)(e / ncols);
  int col = (int)(e % ncols);
  const float4 v = *(const float4*)(in + (int64_t)row * in_stride + col);
  bf16_t* o = out + e;
  o[0] = (bf16_t)(v.x / (1.f + expf(-v.x)));
  o[1] = (bf16_t)(v.y / (1.f + expf(-v.y)));
  o[2] = (bf16_t)(v.z / (1.f + expf(-v.z)));
  o[3] = (bf16_t)(v.w / (1.f + expf(-v.w)));
}

// ---------------- standalone ssm_prep (fallback only) ----------------------
__global__ __launch_bounds__(256) void ssm_prep(const float* __restrict__ params,
                                                const float* __restrict__ A_log,
                                                float* __restrict__ ssmp) {
  int gid = blockIdx.x * 256 + threadIdx.x;  // 32 * 1024
  int bg = gid >> 10, t = gid & 1023;
  int b = bg >> 4, g = bg & 15;
  const float* pr = params + (int64_t)(b * 1024 + t) * PPAD + g * 33;
  float raw = pr[0];
  float delta = raw > 0.f ? raw + log1pf(expf(-raw)) : log1pf(expf(raw));
  float* o = ssmp + (int64_t)gid * 48;
#pragma unroll
  for (int s = 0; s < 16; ++s) {
    float A = -expf(A_log[s]);
    float dA = delta * A;
    dA = fminf(10.f, fmaxf(-10.f, dA));
    float e = expf(dA);
    float frac = (fabsf(dA) < 1e-4f) ? delta : (e - 1.f) / (A + 1e-12f);
    o[s] = dA;
    o[16 + s] = frac * pr[1 + s];
    o[32 + s] = pr[17 + s];
  }
}

// ---------------- split-K reduce (bf16 partials) + residual + rmsnorm -------
// xmid stored bf16 (residual only; |xmid|~O(5), err<=0.02 within margin)
__global__ __launch_bounds__(256) void reduce_rms(const bf16_t* __restrict__ P,
                                                  const float* __restrict__ x,
                                                  const float* __restrict__ g,
                                                  bf16_t* __restrict__ xmid,
                                                  bf16_t* __restrict__ zb) {
  int row = blockIdx.x;
  int tid = threadIdx.x;
  int64_t base = (int64_t)row * DM + tid * 4;
  float4 v = *(const float4*)(x + base);
#pragma unroll
  for (int p = 0; p < 4; ++p) {
    bf16x4 pv = *(const bf16x4*)(P + (int64_t)p * ROWS * DM + base);
    v.x += (float)pv[0]; v.y += (float)pv[1]; v.z += (float)pv[2]; v.w += (float)pv[3];
  }
  bf16x4 xm;
  xm[0] = (bf16_t)v.x; xm[1] = (bf16_t)v.y; xm[2] = (bf16_t)v.z; xm[3] = (bf16_t)v.w;
  *(bf16x4*)(xmid + base) = xm;
  float ss = v.x * v.x + v.y * v.y + v.z * v.z + v.w * v.w;
#pragma unroll
  for (int o = 32; o; o >>= 1) ss += __shfl_xor(ss, o, 64);
  __shared__ float red[4];
  if ((tid & 63) == 0) red[tid >> 6] = ss;
  __syncthreads();
  float tot = red[0] + red[1] + red[2] + red[3];
  float sc = rsqrtf(tot * (1.0f / DM) + 1e-6f);
  const float4 gv = *(const float4*)(g + tid * 4);
  bf16_t* o = zb + base;
  o[0] = (bf16_t)(v.x * sc * gv.x);
  o[1] = (bf16_t)(v.y * sc * gv.y);
  o[2] = (bf16_t)(v.z * sc * gv.z);
  o[3] = (bf16_t)(v.w * sc * gv.w);
}

__global__ __launch_bounds__(256) void reduce_bias(const bf16_t* __restrict__ P,
                                                   const bf16_t* __restrict__ res,
                                                   const float* __restrict__ bias,
                                                   float* __restrict__ out) {
  int64_t e = ((int64_t)blockIdx.x * 256 + threadIdx.x) * 4;
  int col = (int)(e % DM);
  bf16x4 rv = *(const bf16x4*)(res + e);
  const float4 bv = *(const float4*)(bias + col);
  float4 v = make_float4((float)rv[0] + bv.x, (float)rv[1] + bv.y,
                         (float)rv[2] + bv.z, (float)rv[3] + bv.w);
#pragma unroll
  for (int p = 0; p < 4; ++p) {
    bf16x4 pv = *(const bf16x4*)(P + (int64_t)p * ROWS * DM + e);
    v.x += (float)pv[0]; v.y += (float)pv[1]; v.z += (float)pv[2]; v.w += (float)pv[3];
  }
  *(float4*)(out + e) = v;
}

// inline prep: compute 64 rows of coefficients into cf[64*48] from bf16
// split-K partials (4 parts). cf row t: { dA[16], frac*b[16], c[16] }.
__device__ __forceinline__ void prep_rows(const bf16_t* __restrict__ pb,
                                          const float* __restrict__ A_log,
                                          float* cf, int b, int g, int t0,
                                          int tid) {
  if (tid >= 64) return;
  int t = tid;
  int64_t row = (int64_t)(b * 1024) + t0 + t;
  float acc[33];
#pragma unroll
  for (int i = 0; i < 33; ++i) acc[i] = 0.f;
#pragma unroll
  for (int p = 0; p < 4; ++p) {
    const bf16_t* pr = pb + (int64_t)p * ROWS * PPAD + row * PPAD + g * 33;
#pragma unroll
    for (int i = 0; i < 33; ++i) acc[i] += (float)pr[i];
  }
  float raw = acc[0];
  float delta = raw > 0.f ? raw + log1pf(expf(-raw)) : log1pf(expf(raw));
  float* o = cf + t * 48;
#pragma unroll
  for (int s = 0; s < 16; ++s) {
    float A = -expf(A_log[s]);
    float dA = delta * A;
    dA = fminf(10.f, fmaxf(-10.f, dA));
    float e = expf(dA);
    float frac = (fabsf(dA) < 1e-4f) ? delta : (e - 1.f) / (A + 1e-12f);
    o[s] = dA;
    o[16 + s] = frac * acc[1 + s];
    o[32 + s] = acc[17 + s];
  }
}

// Ut layout: element (ch, t) at byte ch*128 + ((t*2) ^ ((ch&7)<<4))

// ---------------- Phase A: per-chunk boundary operator (MFMA) ---------------
// grid 480: chunks 0..14 only (chunk 15's S/Etot are never consumed)
template <int PREP>
__global__ __launch_bounds__(256) void ssm_chunk(const float* __restrict__ ssmp,
                                                 const bf16_t* __restrict__ pb,
                                                 const float* __restrict__ A_log,
                                                 const bf16_t* __restrict__ u,
                                                 float* __restrict__ S,
                                                 float* __restrict__ Etot) {
  __shared__ __align__(16) float cf[64 * 48];
  __shared__ __align__(16) float Lb[64 * 16];
  __shared__ __align__(16) bf16_t wl[16 * 64];
  __shared__ __align__(16) bf16_t Ut[128 * 64];
  int bg = blockIdx.x / 15, c = blockIdx.x % 15;
  int bgc = bg * 16 + c;
  int b = bg >> 4, g = bg & 15;
  int t0 = c * 64;
  int tid = threadIdx.x;
  {
    int lt = tid >> 4;
    int c8 = (tid & 15) * 8;
#pragma unroll
    for (int p = 0; p < 4; ++p) {
      int t = p * 16 + lt;
      bf16x8 v = *(const bf16x8*)(u + ((int64_t)(b * 1024) + t0 + t) * 2048 + g * 128 + c8);
#pragma unroll
      for (int j = 0; j < 8; ++j)
        Ut[(c8 + j) * 64 + (((t >> 3) ^ j) << 3) + (t & 7)] = v[j];
    }
  }
  if (PREP) {
    prep_rows(pb, A_log, cf, b, g, t0, tid);
  } else {
    const float4* src = (const float4*)(ssmp + ((int64_t)bg * 1024 + t0) * 48);
    float4* dst = (float4*)cf;
#pragma unroll
    for (int i = 0; i < 3; ++i) dst[i * 256 + tid] = src[i * 256 + tid];
  }
  __syncthreads();
  if (tid < 16) {
    float l = 0.f;
    for (int t = 0; t < 64; ++t) { l += cf[t * 48 + tid]; Lb[t * 16 + tid] = l; }
  }
  __syncthreads();
  {
    int s = tid >> 4, tb4 = (tid & 15) * 4;
    float lend = Lb[63 * 16 + s];
    bf16x4 wv;
#pragma unroll
    for (int j = 0; j < 4; ++j) {
      int t = tb4 + j;
      wv[j] = (bf16_t)(__expf(lend - Lb[t * 16 + s]) * cf[t * 48 + 16 + s]);
    }
    unsigned byo = (unsigned)(s * 128 + tb4 * 2) ^ ((unsigned)(s & 7) << 4);
    *(bf16x4*)((char*)wl + byo) = wv;
    if (tid < 16) Etot[(int64_t)bgc * 16 + tid] = __expf(Lb[63 * 16 + tid]);
  }
  __syncthreads();
  {
    int lane = tid & 63, wave = tid >> 6;
    int fr = lane & 15, kq = lane >> 4;
    f32x4 acc2[2] = {};
#pragma unroll
    for (int kk = 0; kk < 2; ++kk) {
      int kb = kk * 4 + kq;
      bf16x8 af = *(const bf16x8*)((const char*)wl +
                    ((unsigned)(fr * 128 + kb * 16) ^ ((unsigned)(fr & 7) << 4)));
#pragma unroll
      for (int q = 0; q < 2; ++q) {
        int ch = (wave * 2 + q) * 16 + fr;
        bf16x8 bfr = *(const bf16x8*)((const char*)Ut +
                       ((unsigned)(ch * 128 + kb * 16) ^ ((unsigned)(ch & 7) << 4)));
        acc2[q] = __builtin_amdgcn_mfma_f32_16x16x32_bf16(af, bfr, acc2[q], 0, 0, 0);
      }
    }
    float* Sp = S + (int64_t)bgc * 2048;
#pragma unroll
    for (int q = 0; q < 2; ++q) {
      int ch = (wave * 2 + q) * 16 + fr;
#pragma unroll
      for (int j = 0; j < 4; ++j) Sp[(kq * 4 + j) * 128 + ch] = acc2[q][j];
    }
  }
}

// ---------------- Phase C: combine (inline) + y = tril(K)@U + ce@H + gate ---
template <int PREP, int GM>
__global__ __launch_bounds__(256) void ssm_out(const float* __restrict__ ssmp,
                                               const bf16_t* __restrict__ pb,
                                               const float* __restrict__ A_log,
                                               const bf16_t* __restrict__ u,
                                               const float* __restrict__ S,
                                               const float* __restrict__ Etot,
                                               const float* __restrict__ gate_f,
                                               const bf16_t* __restrict__ gate_b,
                                               int gstride,
                                               bf16_t* __restrict__ yout) {
  __shared__ __align__(16) float cf[64 * 48];
  __shared__ __align__(16) float Lb[64 * 16];
  __shared__ __align__(16) bf16_t Km[64 * 64];
  __shared__ __align__(16) bf16_t Ut[128 * 64];
  __shared__ __align__(16) bf16_t Hb[128 * 32];
  int bgc = blockIdx.x;
  int bg = bgc >> 4, c = bgc & 15;
  int b = bg >> 4, g = bg & 15;
  int t0 = c * 64;
  int tid = threadIdx.x;
  int lane = tid & 63, wave = tid >> 6;
  {
    int lt = tid >> 4;
    int c8 = (tid & 15) * 8;
#pragma unroll
    for (int p = 0; p < 4; ++p) {
      int t = p * 16 + lt;
      bf16x8 v = *(const bf16x8*)(u + ((int64_t)(b * 1024) + t0 + t) * 2048 + g * 128 + c8);
#pragma unroll
      for (int j = 0; j < 8; ++j)
        Ut[(c8 + j) * 64 + (((t >> 3) ^ j) << 3) + (t & 7)] = v[j];
    }
  }
  // inline sequential combine over preceding chunks -> Hb[ch][s] (bf16)
  {
    int ch = tid & 127, s0 = (tid >> 7) * 8;
    const float* Sp = S + (int64_t)(bg * 16) * 2048;
    const float* Ep = Etot + (int64_t)(bg * 16) * 16;
    float h[8];
#pragma unroll
    for (int j = 0; j < 8; ++j) h[j] = 0.f;
    for (int cc = 0; cc < c; ++cc) {
#pragma unroll
      for (int j = 0; j < 8; ++j)
        h[j] = Ep[cc * 16 + s0 + j] * h[j] +
               Sp[(int64_t)cc * 2048 + (s0 + j) * 128 + ch];
    }
#pragma unroll
    for (int j = 0; j < 8; ++j) {
      Hb[ch * 32 + s0 + j] = (bf16_t)h[j];
      Hb[ch * 32 + 16 + s0 + j] = (bf16_t)0.f;
    }
  }
  if (PREP) {
    prep_rows(pb, A_log, cf, b, g, t0, tid);
  } else {
    const float4* src = (const float4*)(ssmp + ((int64_t)bg * 1024 + t0) * 48);
    float4* dst = (float4*)cf;
#pragma unroll
    for (int i = 0; i < 3; ++i) dst[i * 256 + tid] = src[i * 256 + tid];
  }
  __syncthreads();
  if (tid < 16) {
    float l = 0.f;
    for (int t = 0; t < 64; ++t) { l += cf[t * 48 + tid]; Lb[t * 16 + tid] = l; }
  }
  __syncthreads();
  {
    int t = tid >> 2, tp0 = (tid & 3) * 16;
    float4 cv[4], lv[4];
#pragma unroll
    for (int i = 0; i < 4; ++i) {
      cv[i] = *(const float4*)&cf[t * 48 + 32 + i * 4];
      lv[i] = *(const float4*)&Lb[t * 16 + i * 4];
    }
    float kv[16];
#pragma unroll
    for (int i = 0; i < 16; ++i) {
      int tp = tp0 + i;
      float k = 0.f;
      if (tp <= t) {
#pragma unroll
        for (int q = 0; q < 4; ++q) {
          float4 lpv = *(const float4*)&Lb[tp * 16 + q * 4];
          float4 fbv = *(const float4*)&cf[tp * 48 + 16 + q * 4];
          k += cv[q].x * __expf(lv[q].x - lpv.x) * fbv.x
             + cv[q].y * __expf(lv[q].y - lpv.y) * fbv.y
             + cv[q].z * __expf(lv[q].z - lpv.z) * fbv.z
             + cv[q].w * __expf(lv[q].w - lpv.w) * fbv.w;
        }
      }
      kv[i] = k;
    }
    bf16x8 lo, hi;
#pragma unroll
    for (int i = 0; i < 8; ++i) { lo[i] = (bf16_t)kv[i]; hi[i] = (bf16_t)kv[8 + i]; }
    unsigned b0 = (unsigned)(t * 128 + tp0 * 2) ^ ((unsigned)(t & 7) << 4);
    unsigned b1 = (unsigned)(t * 128 + tp0 * 2 + 16) ^ ((unsigned)(t & 7) << 4);
    *(bf16x8*)((char*)Km + b0) = lo;
    *(bf16x8*)((char*)Km + b1) = hi;
  }
  __syncthreads();
  int fr = lane & 15, kq = lane >> 4;
  int trow = (wave >> 1) * 32, wc = (wave & 1) * 64;
  f32x4 acc[2][4] = {};
#pragma unroll
  for (int kk = 0; kk < 2; ++kk) {
    int kb = kk * 4 + kq;
    bf16x8 af[2];
#pragma unroll
    for (int mi = 0; mi < 2; ++mi) {
      int row = trow + mi * 16 + fr;
      af[mi] = *(const bf16x8*)((const char*)Km +
                 ((unsigned)(row * 128 + kb * 16) ^ ((unsigned)(row & 7) << 4)));
    }
#pragma unroll
    for (int ni = 0; ni < 4; ++ni) {
      int ch = wc + ni * 16 + fr;
      bf16x8 bfr = *(const bf16x8*)((const char*)Ut +
                     ((unsigned)(ch * 128 + kb * 16) ^ ((unsigned)(ch & 7) << 4)));
#pragma unroll
      for (int mi = 0; mi < 2; ++mi)
        acc[mi][ni] = __builtin_amdgcn_mfma_f32_16x16x32_bf16(af[mi], bfr, acc[mi][ni], 0, 0, 0);
    }
  }
  {
    int s0 = kq * 8;
    bf16x8 cef[2];
    if (s0 < 16) {
#pragma unroll
      for (int mi = 0; mi < 2; ++mi) {
        int t = trow + mi * 16 + fr;
#pragma unroll
        for (int j = 0; j < 8; ++j)
          cef[mi][j] = (bf16_t)(cf[t * 48 + 32 + s0 + j] * __expf(Lb[t * 16 + s0 + j]));
      }
    } else {
#pragma unroll
      for (int mi = 0; mi < 2; ++mi)
#pragma unroll
        for (int j = 0; j < 8; ++j) cef[mi][j] = (bf16_t)0.f;
    }
#pragma unroll
    for (int ni = 0; ni < 4; ++ni) {
      int ch = wc + ni * 16 + fr;
      bf16x8 bhf = *(const bf16x8*)((const char*)Hb + ch * 64 + s0 * 2);
#pragma unroll
      for (int mi = 0; mi < 2; ++mi)
        acc[mi][ni] = __builtin_amdgcn_mfma_f32_16x16x32_bf16(cef[mi], bhf, acc[mi][ni], 0, 0, 0);
    }
  }
  {
    int64_t rowbase = (int64_t)b * 1024 + t0;
    int colbase = g * 128;
#pragma unroll
    for (int mi = 0; mi < 2; ++mi) {
#pragma unroll
      for (int ni = 0; ni < 4; ++ni) {
        int col = colbase + wc + ni * 16 + fr;
#pragma unroll
        for (int j = 0; j < 4; ++j) {
          int t = trow + mi * 16 + kq * 4 + j;
          float sg;
          if (GM) {
            sg = (float)gate_b[(rowbase + t) * 2048 + col];
          } else {
            float gv = gate_f[(rowbase + t) * (int64_t)gstride + col];
            sg = gv / (1.f + __expf(-gv));
          }
          yout[(rowbase + t) * 2048 + col] = (bf16_t)(acc[mi][ni][j] * sg);
        }
      }
    }
  }
}

// ======== epilogue helper (fallback gemm_bt only) ========
template <int EPI>
__device__ __forceinline__ void epi_store(float v, int64_t r, int64_t cn, int N,
                                          float* Cz, const float* bias,
                                          const float* res, bf16_t* obf,
                                          bf16_t* ogate, int z) {
  if (EPI & 1) v += bias[cn];
  if (EPI & 2) v += res[r * N + cn];
  if (EPI & 4) {
    float sv = v / (1.f + __expf(-v));
    if (cn < 2048) obf[r * 2048 + cn] = (bf16_t)sv;
    else ogate[r * 2048 + cn - 2048] = (bf16_t)sv;
  } else if (EPI & 8) {
    obf[r * N + cn] = (bf16_t)(v / (1.f + __expf(-v)));
  } else if (EPI & 16) {
    obf[(int64_t)z * ROWS * N + r * N + cn] = (bf16_t)v;
  } else {
    Cz[r * N + cn] = v;
  }
}

// bijective XCD swizzle over flattened grid (identity if nwg%8 != 0)
__device__ __forceinline__ void xcd_swz(int& bx, int& by, int& bz) {
  int gx = gridDim.x, gy = gridDim.y, gz = gridDim.z;
  int flat = blockIdx.x + gx * (blockIdx.y + gy * blockIdx.z);
  int nwg = gx * gy * gz;
  int swz = flat;
  if ((nwg & 7) == 0) swz = (flat & 7) * (nwg >> 3) + (flat >> 3);
  bx = swz % gx;
  int rem = swz / gx;
  by = rem % gy;
  bz = rem / gy;
}

// ---------------- bf16 GEMM 128x128, double-buffered 2-phase (fallback) -----
template <int EPI>
__global__ __launch_bounds__(256) void gemm_bt(const bf16_t* __restrict__ A,
                                               const bf16_t* __restrict__ Bw,
                                               float* __restrict__ C,
                                               const float* __restrict__ bias,
                                               const float* __restrict__ res,
                                               bf16_t* __restrict__ obf,
                                               bf16_t* __restrict__ ogate,
                                               int N, int Kps) {
  __shared__ bf16_t As[2][128 * 64];
  __shared__ bf16_t Bs[2][128 * 64];
  const int tid = threadIdx.x;
  const int wave = tid >> 6;
  const int lane = tid & 63;
  int bxi, byi, bzi;
  xcd_swz(bxi, byi, bzi);
  const int64_t m0 = (int64_t)byi * 128;
  const int64_t n0 = (int64_t)bxi * 128;
  const int K = Kps * gridDim.z;
  const int kbeg = bzi * Kps;
  float* Cz = C + (int64_t)bzi * ROWS * N;
  const int wm = (wave >> 1) * 64;
  const int wn = (wave & 1) * 64;
  f32x4 acc[4][4] = {};

  const int er = tid >> 3;
  const int ec = (tid * 8) & 63;
  const int fr = lane & 15;
  const int kq = (lane >> 4) * 8;

  auto stage = [&](int buf, int k0) {
#pragma unroll
    for (int i = 0; i < 4; ++i) {
      const bf16_t* ga = A + (m0 + er + i * 32) * K + k0 + ec;
      __builtin_amdgcn_global_load_lds((gvoid_t*)ga,
                                       (lvoid_t*)&As[buf][(i * 256 + wave * 64) * 8],
                                       16, 0, 0);
    }
#pragma unroll
    for (int i = 0; i < 4; ++i) {
      const bf16_t* gb = Bw + (n0 + er + i * 32) * K + k0 + ec;
      __builtin_amdgcn_global_load_lds((gvoid_t*)gb,
                                       (lvoid_t*)&Bs[buf][(i * 256 + wave * 64) * 8],
                                       16, 0, 0);
    }
  };
  auto compute = [&](int buf) {
#pragma unroll
    for (int kk = 0; kk < 2; ++kk) {
      bf16x8 af[4], bv[4];
#pragma unroll
      for (int mi = 0; mi < 4; ++mi)
        af[mi] = *reinterpret_cast<const bf16x8*>(&As[buf][(wm + mi * 16 + fr) * 64 + kk * 32 + kq]);
#pragma unroll
      for (int ni = 0; ni < 4; ++ni)
        bv[ni] = *reinterpret_cast<const bf16x8*>(&Bs[buf][(wn + ni * 16 + fr) * 64 + kk * 32 + kq]);
#pragma unroll
      for (int mi = 0; mi < 4; ++mi)
#pragma unroll
        for (int ni = 0; ni < 4; ++ni)
          acc[mi][ni] = __builtin_amdgcn_mfma_f32_16x16x32_bf16(af[mi], bv[ni], acc[mi][ni], 0, 0, 0);
    }
  };

  const int nk = Kps >> 6;  // assumed even
  stage(0, kbeg);
  asm volatile("s_waitcnt vmcnt(0)" ::: "memory");
  __builtin_amdgcn_s_barrier();
  int kc = kbeg;
  for (int t = 0; t < nk; t += 2) {
    stage(1, kc + 64);
    compute(0);
    asm volatile("s_waitcnt vmcnt(0)" ::: "memory");
    __builtin_amdgcn_s_barrier();
    if (t + 2 < nk) stage(0, kc + 128);
    compute(1);
    asm volatile("s_waitcnt vmcnt(0)" ::: "memory");
    __builtin_amdgcn_s_barrier();
    kc += 128;
  }

  const int crow = (lane >> 4) * 4;
  const int ccol = lane & 15;
#pragma unroll
  for (int mi = 0; mi < 4; ++mi)
#pragma unroll
    for (int ni = 0; ni < 4; ++ni)
#pragma unroll
      for (int j = 0; j < 4; ++j)
        epi_store<EPI>(acc[mi][ni][j], m0 + wm + mi * 16 + crow + j,
                       n0 + wn + ni * 16 + ccol, N, Cz, bias, res, obf, ogate,
                       bzi);
}

// ---------------- param GEMM (128x128, SK=4) + W_out/W_f1/W_f2 conversion ---
__global__ __launch_bounds__(256) void gemm_param_conv(
    const bf16_t* __restrict__ A, const bf16_t* __restrict__ Bw,
    bf16_t* __restrict__ pout,
    const float* __restrict__ W_out, const float* __restrict__ W_f1,
    const float* __restrict__ W_f2,
    bf16_t* o_out, bf16_t* o_f1, bf16_t* o_f2) {
  __shared__ bf16_t As[2][128 * 64];
  __shared__ bf16_t Bs[2][128 * 64];
  const int tid = threadIdx.x;
  if (blockIdx.x >= 320) {
    conv3(blockIdx.x - 320, tid, W_out, W_f1, W_f2, o_out, o_f1, o_f2);
    return;
  }
  const int flat = blockIdx.x;
  const int swz = (flat & 7) * 40 + (flat >> 3);  // 320 % 8 == 0, bijective
  const int bxi = swz % 5;
  const int byi = (swz / 5) % 16;
  const int bzi = swz / 80;
  const int wave = tid >> 6;
  const int lane = tid & 63;
  const int64_t m0 = (int64_t)byi * 128;
  const int64_t n0 = (int64_t)bxi * 128;
  const int K = 2048, Kps = 512;
  const int kbeg = bzi * Kps;
  const int wm = (wave >> 1) * 64;
  const int wn = (wave & 1) * 64;
  f32x4 acc[4][4] = {};
  const int er = tid >> 3;
  const int ec = (tid * 8) & 63;
  const int fr = lane & 15;
  const int kq = (lane >> 4) * 8;

  auto stage = [&](int buf, int k0) {
#pragma unroll
    for (int i = 0; i < 4; ++i) {
      const bf16_t* ga = A + (m0 + er + i * 32) * K + k0 + ec;
      __builtin_amdgcn_global_load_lds((gvoid_t*)ga,
                                       (lvoid_t*)&As[buf][(i * 256 + wave * 64) * 8],
                                       16, 0, 0);
    }
#pragma unroll
    for (int i = 0; i < 4; ++i) {
      const bf16_t* gb = Bw + (n0 + er + i * 32) * K + k0 + ec;
      __builtin_amdgcn_global_load_lds((gvoid_t*)gb,
                                       (lvoid_t*)&Bs[buf][(i * 256 + wave * 64) * 8],
                                       16, 0, 0);
    }
  };
  auto compute = [&](int buf) {
#pragma unroll
    for (int kk = 0; kk < 2; ++kk) {
      bf16x8 af[4], bv[4];
#pragma unroll
      for (int mi = 0; mi < 4; ++mi)
        af[mi] = *reinterpret_cast<const bf16x8*>(&As[buf][(wm + mi * 16 + fr) * 64 + kk * 32 + kq]);
#pragma unroll
      for (int ni = 0; ni < 4; ++ni)
        bv[ni] = *reinterpret_cast<const bf16x8*>(&Bs[buf][(wn + ni * 16 + fr) * 64 + kk * 32 + kq]);
#pragma unroll
      for (int mi = 0; mi < 4; ++mi)
#pragma unroll
        for (int ni = 0; ni < 4; ++ni)
          acc[mi][ni] = __builtin_amdgcn_mfma_f32_16x16x32_bf16(af[mi], bv[ni], acc[mi][ni], 0, 0, 0);
    }
  };

  const int nk = Kps >> 6;  // 8
  stage(0, kbeg);
  asm volatile("s_waitcnt vmcnt(0)" ::: "memory");
  __builtin_amdgcn_s_barrier();
  int kc = kbeg;
  for (int t = 0; t < nk; t += 2) {
    stage(1, kc + 64);
    compute(0);
    asm volatile("s_waitcnt vmcnt(0)" ::: "memory");
    __builtin_amdgcn_s_barrier();
    if (t + 2 < nk) stage(0, kc + 128);
    compute(1);
    asm volatile("s_waitcnt vmcnt(0)" ::: "memory");
    __builtin_amdgcn_s_barrier();
    kc += 128;
  }

  const int crow = (lane >> 4) * 4;
  const int ccol = lane & 15;
  bf16_t* pz = pout + (int64_t)bzi * ROWS * PPAD;
#pragma unroll
  for (int mi = 0; mi < 4; ++mi)
#pragma unroll
    for (int ni = 0; ni < 4; ++ni)
#pragma unroll
      for (int j = 0; j < 4; ++j) {
        int64_t r = m0 + wm + mi * 16 + crow + j;
        int64_t cn = n0 + wn + ni * 16 + ccol;
        pz[r * PPAD + cn] = (bf16_t)acc[mi][ni][j];
      }
}

// ---------------- bf16 GEMM 128x256, 8-wave, depth-3 counted-vmcnt pipeline --
// Coalesced epilogue: acc -> XOR-swizzled LDS tile (reusing Bs) -> 16B stores.
template <int EPI>
__global__ __launch_bounds__(512) void gemm_big(const bf16_t* __restrict__ A,
                                                const bf16_t* __restrict__ Bw,
                                                float* __restrict__ C,
                                                const float* __restrict__ bias,
                                                const float* __restrict__ res,
                                                bf16_t* __restrict__ obf,
                                                bf16_t* __restrict__ ogate,
                                                int N, int Kps) {
  __shared__ bf16_t As[3][128 * 64];
  __shared__ bf16_t Bs[3][256 * 64];
  const int tid = threadIdx.x;
  const int wave = tid >> 6;
  const int lane = tid & 63;
  int bxi, byi, bzi;
  xcd_swz(bxi, byi, bzi);
  const int64_t m0 = (int64_t)byi * 128;
  const int64_t n0 = (int64_t)bxi * 256;
  const int K = Kps * gridDim.z;
  const int kbeg = bzi * Kps;
  float* Cz = C + (int64_t)bzi * ROWS * N;
  (void)Cz; (void)res;
  const int wm = (wave >> 2) * 64;
  const int wc = (wave & 3) * 64;
  const int fr = lane & 15;
  const int kq16 = (lane >> 4) * 16;
  const int er = tid >> 3;
  const int ec_sw = ((tid & 7) * 8) ^ ((er & 7) << 3);
  f32x4 acc[4][4] = {};

  auto stage = [&](int buf, int k0) {
#pragma unroll
    for (int i = 0; i < 2; ++i) {
      const bf16_t* ga = A + (m0 + er + i * 64) * K + k0 + ec_sw;
      __builtin_amdgcn_global_load_lds((gvoid_t*)ga,
          (lvoid_t*)((char*)&As[buf][0] + i * 8192 + wave * 1024), 16, 0, 0);
    }
#pragma unroll
    for (int i = 0; i < 4; ++i) {
      const bf16_t* gb = Bw + (n0 + er + i * 64) * K + k0 + ec_sw;
      __builtin_amdgcn_global_load_lds((gvoid_t*)gb,
          (lvoid_t*)((char*)&Bs[buf][0] + i * 8192 + wave * 1024), 16, 0, 0);
    }
  };

  const int nk = Kps >> 6;
  stage(0, kbeg);
  if (nk > 1) {
    stage(1, kbeg + 64);
    asm volatile("s_waitcnt vmcnt(6)" ::: "memory");
  } else {
    asm volatile("s_waitcnt vmcnt(0)" ::: "memory");
  }
  __builtin_amdgcn_s_barrier();
  __builtin_amdgcn_sched_barrier(0);

  for (int t = 0; t < nk; ++t) {
    const int buf = t % 3;
    bf16x8 af[2][4], bf[2][4];
#pragma unroll
    for (int kk = 0; kk < 2; ++kk) {
#pragma unroll
      for (int mi = 0; mi < 4; ++mi) {
        int r = wm + mi * 16 + fr;
        af[kk][mi] = *(const bf16x8*)((const char*)&As[buf][0] + r * 128 +
                       ((kk * 64 + kq16) ^ ((r & 7) << 4)));
      }
#pragma unroll
      for (int ni = 0; ni < 4; ++ni) {
        int r = wc + ni * 16 + fr;
        bf[kk][ni] = *(const bf16x8*)((const char*)&Bs[buf][0] + r * 128 +
                       ((kk * 64 + kq16) ^ ((r & 7) << 4)));
      }
    }
    asm volatile("s_waitcnt lgkmcnt(8)" ::: "memory");
    __builtin_amdgcn_sched_barrier(0);
    __builtin_amdgcn_s_setprio(1);
#pragma unroll
    for (int mi = 0; mi < 4; ++mi)
#pragma unroll
      for (int ni = 0; ni < 4; ++ni)
        acc[mi][ni] = __builtin_amdgcn_mfma_f32_16x16x32_bf16(
            af[0][mi], bf[0][ni], acc[mi][ni], 0, 0, 0);
    __builtin_amdgcn_s_setprio(0);
    __builtin_amdgcn_sched_barrier(0);
    if (t + 2 < nk) stage((t + 2) % 3, kbeg + (t + 2) * 64);
    __builtin_amdgcn_s_setprio(1);
#pragma unroll
    for (int mi = 0; mi < 4; ++mi)
#pragma unroll
      for (int ni = 0; ni < 4; ++ni)
        acc[mi][ni] = __builtin_amdgcn_mfma_f32_16x16x32_bf16(
            af[1][mi], bf[1][ni], acc[mi][ni], 0, 0, 0);
    __builtin_amdgcn_s_setprio(0);
    if (t + 1 < nk) {
      if (t + 2 < nk) asm volatile("s_waitcnt vmcnt(6)" ::: "memory");
      else            asm volatile("s_waitcnt vmcnt(0)" ::: "memory");
      __builtin_amdgcn_s_barrier();
      __builtin_amdgcn_sched_barrier(0);
    }
  }

  // ---- coalesced epilogue: per-wave 64x64 bf16 tile in dead Bs, XOR-swizzled
  __syncthreads();  // all waves done reading LDS buffers
  {
    char* ep = (char*)&Bs[0][0] + wave * 8192;  // 64 rows x 128B
    const int crow = (lane >> 4) * 4;
    const int ccol = lane & 15;
#pragma unroll
    for (int mi = 0; mi < 4; ++mi) {
#pragma unroll
      for (int ni = 0; ni < 4; ++ni) {
        int lc = ni * 16 + ccol;
        float bv = (EPI & 1) ? bias[n0 + wc + lc] : 0.f;
#pragma unroll
        for (int j = 0; j < 4; ++j) {
          int lr = mi * 16 + crow + j;
          float v = acc[mi][ni][j] + bv;
          if (EPI & 12) v = v / (1.f + __expf(-v));
          *(bf16_t*)(ep + lr * 128 + ((lc * 2) ^ ((lr & 7) << 4))) = (bf16_t)v;
        }
      }
    }
    // read back row-major, 16B per lane; 8 consecutive lanes = one 128B row
#pragma unroll
    for (int i = 0; i < 8; ++i) {
      int idx = i * 64 + lane;
      int row = idx >> 3;
      int grp = idx & 7;
      bf16x8 v = *(const bf16x8*)(ep + row * 128 + ((grp * 16) ^ ((row & 7) << 4)));
      int64_t r = m0 + wm + row;
      int64_t cn = n0 + wc + grp * 8;
      bf16_t* dst;
      if (EPI & 4) {
        dst = (cn < 2048) ? (obf + r * 2048 + cn) : (ogate + r * 2048 + cn - 2048);
      } else if (EPI & 16) {
        dst = obf + (int64_t)bzi * ROWS * N + r * N + cn;
      } else {
        dst = obf + r * N + cn;
      }
      *(bf16x8*)dst = v;
    }
  }
}

extern "C" void kernel_launch(void* const* d_in, const int* in_sizes, int n_in,
                              void* d_out, int out_size, void* d_ws, size_t ws_size,
                              hipStream_t stream) {
  const float* x       = (const float*)d_in[0];
  const float* A_log   = (const float*)d_in[1];
  const float* g1      = (const float*)d_in[2];
  const float* g2      = (const float*)d_in[3];
  const float* W_in    = (const float*)d_in[4];
  const float* W_param = (const float*)d_in[5];
  const float* W_out   = (const float*)d_in[6];
  const float* W_ffn1  = (const float*)d_in[7];
  const float* b_ffn1  = (const float*)d_in[8];
  const float* W_ffn2  = (const float*)d_in[9];
  const float* b_ffn2  = (const float*)d_in[10];
  float* out = (float*)d_out;

  char* ws = (char*)d_ws;
  size_t off = 0;
  auto alloc = [&](size_t bytes) {
    char* p = ws + off;
    off += (bytes + 255) & ~(size_t)255;
    return p;
  };
  bf16_t* wb_in  = (bf16_t*)alloc(4096ull * 1024 * 2);
  bf16_t* wb_par = (bf16_t*)alloc((size_t)PPAD * 2048 * 2);
  bf16_t* wb_out = (bf16_t*)alloc(1024ull * 2048 * 2);
  bf16_t* wb_f1  = (bf16_t*)alloc(4096ull * 1024 * 2);
  bf16_t* wb_f2  = (bf16_t*)alloc(1024ull * 4096 * 2);
  bf16_t* zbuf   = (bf16_t*)alloc(2048ull * 1024 * 2);   // z, later h2
  float*  xzg    = (float*)alloc(2048ull * 4096 * 4);    // sgate bf16 (sk) / fp32 (fallback)
  float*  params = (float*)alloc(2048ull * PPAD * 4);    // fallback GEMM out; S/Etot overlay
  float*  ssmp   = (float*)alloc(32ull * 1024 * 48 * 4); // fallback only
  float*  xmid   = (float*)alloc(2048ull * 1024 * 4);    // bf16 (sk) / fp32 (fallback)
  char*   regA   = alloc(2048ull * 4096 * 2);            // 16MB union
  bf16_t* xz_act = (bf16_t*)regA;
  bf16_t* y_b16  = (bf16_t*)(regA + 2048ull * 2048 * 2);
  bf16_t* f_act  = (bf16_t*)regA;
  bf16_t* sgate  = (bf16_t*)xzg;                         // [2048][2048] bf16 (sk)
  bf16_t* xmid_b = (bf16_t*)xmid;                        // bf16 residual (sk)
  float* Sbuf = params;
  float* Etot = params + 32ull * 16 * 16 * 128;
  float*  psum = (float*)alloc(4ull * ROWS * 1024 * 4);  // fp32 partials (fallback)
  bf16_t* pb16 = (bf16_t*)psum;                          // bf16 partials overlay
  const bool sk = (off <= ws_size);

  dim3 b256(256), b512(512);
  // W_in/W_param -> bf16 + z = rmsnorm(x,g1)
  prep0<<<7424, b256, 0, stream>>>(W_in, W_param, wb_in, wb_par, x, g1, zbuf);

  if (sk) {
    // xz|gate = z @ W_in^T, fused: silu(xz)->xz_act, silu(gate)->sgate (bf16)
    gemm_big<4><<<dim3(16, 16), b512, 0, stream>>>(zbuf, wb_in, psum, nullptr, nullptr, xz_act, sgate, 4096, 1024);
    // param partials (bf16, SK=4) + W_out/W_f1/W_f2 conversion riding along
    gemm_param_conv<<<10560, b256, 0, stream>>>(xz_act, wb_par, pb16,
                                                W_out, W_ffn1, W_ffn2,
                                                wb_out, wb_f1, wb_f2);
    // chunked scan (coefficient prep inlined; combine inlined in ssm_out)
    ssm_chunk<1><<<480, b256, 0, stream>>>(nullptr, pb16, A_log, xz_act, Sbuf, Etot);
    ssm_out<1, 1><<<512, b256, 0, stream>>>(nullptr, pb16, A_log, xz_act, Sbuf, Etot, nullptr, sgate, 2048, y_b16);
    // xmid = x + y @ W_out^T (SK=4, bf16 partials) fused reduce+rmsnorm
    gemm_big<16><<<dim3(4, 16, 4), b512, 0, stream>>>(y_b16, wb_out, psum, nullptr, nullptr, pb16, nullptr, 1024, 512);
    reduce_rms<<<2048, b256, 0, stream>>>(pb16, x, g2, xmid_b, zbuf);
    // ffn1 + bias + silu -> f_act bf16 (fused)
    gemm_big<9><<<dim3(16, 16), b512, 0, stream>>>(zbuf, wb_f1, psum, b_ffn1, nullptr, f_act, nullptr, 4096, 1024);
    // out = xmid + b_ffn2 + f_act @ W_ffn2^T (SK=4, bf16 partials)
    gemm_big<16><<<dim3(4, 16, 4), b512, 0, stream>>>(f_act, wb_f2, psum, nullptr, nullptr, pb16, nullptr, 1024, 1024);
    reduce_bias<<<2048, b256, 0, stream>>>(pb16, xmid_b, b_ffn2, out);
  } else {
    cvt3_k<<<10240, b256, 0, stream>>>(W_out, W_ffn1, W_ffn2, wb_out, wb_f1, wb_f2);
    gemm_bt<0><<<dim3(32, 16), b256, 0, stream>>>(zbuf, wb_in, xzg, nullptr, nullptr, nullptr, nullptr, 4096, 1024);
    silu_cvt<<<4096, b256, 0, stream>>>(xzg, xz_act, 4096, 2048);
    gemm_bt<0><<<dim3(PPAD / 128, 16), b256, 0, stream>>>(xz_act, wb_par, params, nullptr, nullptr, nullptr, nullptr, PPAD, 2048);
    ssm_prep<<<128, b256, 0, stream>>>(params, A_log, ssmp);
    ssm_chunk<0><<<480, b256, 0, stream>>>(ssmp, nullptr, A_log, xz_act, Sbuf, Etot);
    ssm_out<0, 0><<<512, b256, 0, stream>>>(ssmp, nullptr, A_log, xz_act, Sbuf, Etot, xzg + 2048, nullptr, 4096, y_b16);
    gemm_bt<2><<<dim3(8, 16), b256, 0, stream>>>(y_b16, wb_out, xmid, nullptr, x, nullptr, nullptr, 1024, 2048);
    rmsnorm_k<<<2048, b256, 0, stream>>>(xmid, g2, zbuf);
    gemm_bt<1><<<dim3(32, 16), b256, 0, stream>>>(zbuf, wb_f1, xzg, b_ffn1, nullptr, nullptr, nullptr, 4096, 1024);
    silu_cvt<<<8192, b256, 0, stream>>>(xzg, f_act, 4096, 4096);
    gemm_bt<3><<<dim3(8, 16), b256, 0, stream>>>(f_act, wb_f2, out, b_ffn2, xmid, nullptr, nullptr, 1024, 4096);
  }
}

// Round 11
// 169.144 us; speedup vs baseline: 5.9780x; 1.0091x over previous
//
#include <hip/hip_runtime.h>
#include <hip/hip_bf16.h>
#include <stdint.h>

// MambaBlock: B=2, T=1024, D_MODEL=1024, D_INNER=2048, GROUPS=16, D_STATE=16
#define ROWS 2048      // B*T
#define DM   1024
#define DI   2048
#define PPAD 640       // 528 param rows padded to 5*128

typedef __bf16 bf16_t;
typedef __attribute__((ext_vector_type(8))) __bf16 bf16x8;
typedef __attribute__((ext_vector_type(4))) __bf16 bf16x4;
typedef __attribute__((ext_vector_type(4))) float f32x4;
typedef __attribute__((address_space(1))) void gvoid_t;
typedef __attribute__((address_space(3))) void lvoid_t;

// ---------------- prep0: W_in + W_param -> bf16, z = rmsnorm(x,g1) ----------
__global__ __launch_bounds__(256) void prep0(const float* __restrict__ W_in,
                                             const float* __restrict__ W_param,
                                             bf16_t* o_in, bf16_t* o_par,
                                             const float* __restrict__ x,
                                             const float* __restrict__ g1,
                                             bf16_t* __restrict__ zb) {
  int tid = threadIdx.x;
  if (blockIdx.x >= 5376) {  // rmsnorm
    int row = blockIdx.x - 5376;
    const float4 v = *(const float4*)(x + (int64_t)row * DM + tid * 4);
    float ss = v.x * v.x + v.y * v.y + v.z * v.z + v.w * v.w;
#pragma unroll
    for (int o = 32; o; o >>= 1) ss += __shfl_xor(ss, o, 64);
    __shared__ float red[4];
    if ((tid & 63) == 0) red[tid >> 6] = ss;
    __syncthreads();
    float tot = red[0] + red[1] + red[2] + red[3];
    float sc = rsqrtf(tot * (1.0f / DM) + 1e-6f);
    const float4 gv = *(const float4*)(g1 + tid * 4);
    bf16_t* o = zb + (int64_t)row * DM + tid * 4;
    o[0] = (bf16_t)(v.x * sc * gv.x);
    o[1] = (bf16_t)(v.y * sc * gv.y);
    o[2] = (bf16_t)(v.z * sc * gv.z);
    o[3] = (bf16_t)(v.w * sc * gv.w);
    return;
  }
  if (blockIdx.x >= 4096) {  // W_param, zero-padded 528 -> 640 rows
    int64_t e = (((int64_t)(blockIdx.x - 4096)) * 256 + tid) * 4;
    int row = (int)(e >> 11), col = (int)(e & 2047);
    float4 v = make_float4(0.f, 0.f, 0.f, 0.f);
    if (row < 528) v = *(const float4*)(W_param + (int64_t)row * 2048 + col);
    bf16_t* o = o_par + e;
    o[0] = (bf16_t)v.x; o[1] = (bf16_t)v.y; o[2] = (bf16_t)v.z; o[3] = (bf16_t)v.w;
    return;
  }
  int64_t e = ((int64_t)blockIdx.x * 256 + tid) * 4;
  float4 v = *(const float4*)(W_in + e);
  bf16_t* o = o_in + e;
  o[0] = (bf16_t)v.x; o[1] = (bf16_t)v.y; o[2] = (bf16_t)v.z; o[3] = (bf16_t)v.w;
}

// ---------------- conversion of W_out/W_f1/W_f2 (10240 blocks) --------------
__device__ __forceinline__ void conv3(int64_t c, int tid,
                                      const float* __restrict__ W_out,
                                      const float* __restrict__ W_f1,
                                      const float* __restrict__ W_f2,
                                      bf16_t* o_out, bf16_t* o_f1, bf16_t* o_f2) {
  const float* src; bf16_t* dst; int64_t e;
  if (c < 2048) { e = (c * 256 + tid) * 4; src = W_out; dst = o_out; }
  else if (c < 6144) { e = ((c - 2048) * 256 + tid) * 4; src = W_f1; dst = o_f1; }
  else { e = ((c - 6144) * 256 + tid) * 4; src = W_f2; dst = o_f2; }
  float4 v = *(const float4*)(src + e);
  bf16_t* o = dst + e;
  o[0] = (bf16_t)v.x; o[1] = (bf16_t)v.y; o[2] = (bf16_t)v.z; o[3] = (bf16_t)v.w;
}

__global__ __launch_bounds__(256) void cvt3_k(const float* __restrict__ W_out,
                                              const float* __restrict__ W_f1,
                                              const float* __restrict__ W_f2,
                                              bf16_t* o_out, bf16_t* o_f1,
                                              bf16_t* o_f2) {
  conv3(blockIdx.x, threadIdx.x, W_out, W_f1, W_f2, o_out, o_f1, o_f2);
}

// ---------------- rmsnorm (fallback) ----------------
__global__ __launch_bounds__(256) void rmsnorm_k(const float* __restrict__ x,
                                                 const float* __restrict__ g,
                                                 bf16_t* __restrict__ out) {
  int row = blockIdx.x;
  int tid = threadIdx.x;
  const float4 v = *(const float4*)(x + (int64_t)row * DM + tid * 4);
  float ss = v.x * v.x + v.y * v.y + v.z * v.z + v.w * v.w;
#pragma unroll
  for (int o = 32; o; o >>= 1) ss += __shfl_xor(ss, o, 64);
  __shared__ float red[4];
  if ((tid & 63) == 0) red[tid >> 6] = ss;
  __syncthreads();
  float tot = red[0] + red[1] + red[2] + red[3];
  float sc = rsqrtf(tot * (1.0f / DM) + 1e-6f);
  const float4 gv = *(const float4*)(g + tid * 4);
  bf16_t* o = out + (int64_t)row * DM + tid * 4;
  o[0] = (bf16_t)(v.x * sc * gv.x);
  o[1] = (bf16_t)(v.y * sc * gv.y);
  o[2] = (bf16_t)(v.z * sc * gv.z);
  o[3] = (bf16_t)(v.w * sc * gv.w);
}

// ---------------- silu + fp32 -> bf16 (fallback) ----------------
__global__ __launch_bounds__(256) void silu_cvt(const float* __restrict__ in,
                                                bf16_t* __restrict__ out,
                                                int in_stride, int ncols) {
  int64_t e = ((int64_t)blockIdx.x * 256 + threadIdx.x) * 4;
  int row = (int)(e / ncols);
  int col = (int)(e % ncols);
  const float4 v = *(const float4*)(in + (int64_t)row * in_stride + col);
  bf16_t* o = out + e;
  o[0] = (bf16_t)(v.x / (1.f + expf(-v.x)));
  o[1] = (bf16_t)(v.y / (1.f + expf(-v.y)));
  o[2] = (bf16_t)(v.z / (1.f + expf(-v.z)));
  o[3] = (bf16_t)(v.w / (1.f + expf(-v.w)));
}

// ---------------- standalone ssm_prep (fallback only) ----------------------
__global__ __launch_bounds__(256) void ssm_prep(const float* __restrict__ params,
                                                const float* __restrict__ A_log,
                                                float* __restrict__ ssmp) {
  int gid = blockIdx.x * 256 + threadIdx.x;  // 32 * 1024
  int bg = gid >> 10, t = gid & 1023;
  int b = bg >> 4, g = bg & 15;
  const float* pr = params + (int64_t)(b * 1024 + t) * PPAD + g * 33;
  float raw = pr[0];
  float delta = raw > 0.f ? raw + log1pf(expf(-raw)) : log1pf(expf(raw));
  float* o = ssmp + (int64_t)gid * 48;
#pragma unroll
  for (int s = 0; s < 16; ++s) {
    float A = -expf(A_log[s]);
    float dA = delta * A;
    dA = fminf(10.f, fmaxf(-10.f, dA));
    float e = expf(dA);
    float frac = (fabsf(dA) < 1e-4f) ? delta : (e - 1.f) / (A + 1e-12f);
    o[s] = dA;
    o[16 + s] = frac * pr[1 + s];
    o[32 + s] = pr[17 + s];
  }
}

// ---------------- split-K reduce (bf16 partials) + residual + rmsnorm -------
__global__ __launch_bounds__(256) void reduce_rms(const bf16_t* __restrict__ P,
                                                  const float* __restrict__ x,
                                                  const float* __restrict__ g,
                                                  bf16_t* __restrict__ xmid,
                                                  bf16_t* __restrict__ zb) {
  int row = blockIdx.x;
  int tid = threadIdx.x;
  int64_t base = (int64_t)row * DM + tid * 4;
  float4 v = *(const float4*)(x + base);
#pragma unroll
  for (int p = 0; p < 4; ++p) {
    bf16x4 pv = *(const bf16x4*)(P + (int64_t)p * ROWS * DM + base);
    v.x += (float)pv[0]; v.y += (float)pv[1]; v.z += (float)pv[2]; v.w += (float)pv[3];
  }
  bf16x4 xm;
  xm[0] = (bf16_t)v.x; xm[1] = (bf16_t)v.y; xm[2] = (bf16_t)v.z; xm[3] = (bf16_t)v.w;
  *(bf16x4*)(xmid + base) = xm;
  float ss = v.x * v.x + v.y * v.y + v.z * v.z + v.w * v.w;
#pragma unroll
  for (int o = 32; o; o >>= 1) ss += __shfl_xor(ss, o, 64);
  __shared__ float red[4];
  if ((tid & 63) == 0) red[tid >> 6] = ss;
  __syncthreads();
  float tot = red[0] + red[1] + red[2] + red[3];
  float sc = rsqrtf(tot * (1.0f / DM) + 1e-6f);
  const float4 gv = *(const float4*)(g + tid * 4);
  bf16_t* o = zb + base;
  o[0] = (bf16_t)(v.x * sc * gv.x);
  o[1] = (bf16_t)(v.y * sc * gv.y);
  o[2] = (bf16_t)(v.z * sc * gv.z);
  o[3] = (bf16_t)(v.w * sc * gv.w);
}

__global__ __launch_bounds__(256) void reduce_bias(const bf16_t* __restrict__ P,
                                                   const bf16_t* __restrict__ res,
                                                   const float* __restrict__ bias,
                                                   float* __restrict__ out) {
  int64_t e = ((int64_t)blockIdx.x * 256 + threadIdx.x) * 4;
  int col = (int)(e % DM);
  bf16x4 rv = *(const bf16x4*)(res + e);
  const float4 bv = *(const float4*)(bias + col);
  float4 v = make_float4((float)rv[0] + bv.x, (float)rv[1] + bv.y,
                         (float)rv[2] + bv.z, (float)rv[3] + bv.w);
#pragma unroll
  for (int p = 0; p < 4; ++p) {
    bf16x4 pv = *(const bf16x4*)(P + (int64_t)p * ROWS * DM + e);
    v.x += (float)pv[0]; v.y += (float)pv[1]; v.z += (float)pv[2]; v.w += (float)pv[3];
  }
  *(float4*)(out + e) = v;
}

// inline prep: compute 64 rows of coefficients into cf[64*48] from bf16
// split-K partials (4 parts). cf row t: { dA[16], frac*b[16], c[16] }.
__device__ __forceinline__ void prep_rows(const bf16_t* __restrict__ pb,
                                          const float* __restrict__ A_log,
                                          float* cf, int b, int g, int t0,
                                          int tid) {
  if (tid >= 64) return;
  int t = tid;
  int64_t row = (int64_t)(b * 1024) + t0 + t;
  float acc[33];
#pragma unroll
  for (int i = 0; i < 33; ++i) acc[i] = 0.f;
#pragma unroll
  for (int p = 0; p < 4; ++p) {
    const bf16_t* pr = pb + (int64_t)p * ROWS * PPAD + row * PPAD + g * 33;
#pragma unroll
    for (int i = 0; i < 33; ++i) acc[i] += (float)pr[i];
  }
  float raw = acc[0];
  float delta = raw > 0.f ? raw + log1pf(expf(-raw)) : log1pf(expf(raw));
  float* o = cf + t * 48;
#pragma unroll
  for (int s = 0; s < 16; ++s) {
    float A = -expf(A_log[s]);
    float dA = delta * A;
    dA = fminf(10.f, fmaxf(-10.f, dA));
    float e = expf(dA);
    float frac = (fabsf(dA) < 1e-4f) ? delta : (e - 1.f) / (A + 1e-12f);
    o[s] = dA;
    o[16 + s] = frac * acc[1 + s];
    o[32 + s] = acc[17 + s];
  }
}

// Ut layout: element (ch, t) at byte ch*128 + ((t*2) ^ ((ch&7)<<4))

// ---------------- Phase A: per-chunk boundary operator (MFMA) ---------------
// grid 480: chunks 0..14 only (chunk 15's S/Etot are never consumed)
template <int PREP>
__global__ __launch_bounds__(256) void ssm_chunk(const float* __restrict__ ssmp,
                                                 const bf16_t* __restrict__ pb,
                                                 const float* __restrict__ A_log,
                                                 const bf16_t* __restrict__ u,
                                                 float* __restrict__ S,
                                                 float* __restrict__ Etot) {
  __shared__ __align__(16) float cf[64 * 48];
  __shared__ __align__(16) float Lb[64 * 16];
  __shared__ __align__(16) bf16_t wl[16 * 64];
  __shared__ __align__(16) bf16_t Ut[128 * 64];
  int bg = blockIdx.x / 15, c = blockIdx.x % 15;
  int bgc = bg * 16 + c;
  int b = bg >> 4, g = bg & 15;
  int t0 = c * 64;
  int tid = threadIdx.x;
  {
    int lt = tid >> 4;
    int c8 = (tid & 15) * 8;
#pragma unroll
    for (int p = 0; p < 4; ++p) {
      int t = p * 16 + lt;
      bf16x8 v = *(const bf16x8*)(u + ((int64_t)(b * 1024) + t0 + t) * 2048 + g * 128 + c8);
#pragma unroll
      for (int j = 0; j < 8; ++j)
        Ut[(c8 + j) * 64 + (((t >> 3) ^ j) << 3) + (t & 7)] = v[j];
    }
  }
  if (PREP) {
    prep_rows(pb, A_log, cf, b, g, t0, tid);
  } else {
    const float4* src = (const float4*)(ssmp + ((int64_t)bg * 1024 + t0) * 48);
    float4* dst = (float4*)cf;
#pragma unroll
    for (int i = 0; i < 3; ++i) dst[i * 256 + tid] = src[i * 256 + tid];
  }
  __syncthreads();
  if (tid < 16) {
    float l = 0.f;
    for (int t = 0; t < 64; ++t) { l += cf[t * 48 + tid]; Lb[t * 16 + tid] = l; }
  }
  __syncthreads();
  {
    int s = tid >> 4, tb4 = (tid & 15) * 4;
    float lend = Lb[63 * 16 + s];
    bf16x4 wv;
#pragma unroll
    for (int j = 0; j < 4; ++j) {
      int t = tb4 + j;
      wv[j] = (bf16_t)(__expf(lend - Lb[t * 16 + s]) * cf[t * 48 + 16 + s]);
    }
    unsigned byo = (unsigned)(s * 128 + tb4 * 2) ^ ((unsigned)(s & 7) << 4);
    *(bf16x4*)((char*)wl + byo) = wv;
    if (tid < 16) Etot[(int64_t)bgc * 16 + tid] = __expf(Lb[63 * 16 + tid]);
  }
  __syncthreads();
  {
    int lane = tid & 63, wave = tid >> 6;
    int fr = lane & 15, kq = lane >> 4;
    f32x4 acc2[2] = {};
#pragma unroll
    for (int kk = 0; kk < 2; ++kk) {
      int kb = kk * 4 + kq;
      bf16x8 af = *(const bf16x8*)((const char*)wl +
                    ((unsigned)(fr * 128 + kb * 16) ^ ((unsigned)(fr & 7) << 4)));
#pragma unroll
      for (int q = 0; q < 2; ++q) {
        int ch = (wave * 2 + q) * 16 + fr;
        bf16x8 bfr = *(const bf16x8*)((const char*)Ut +
                       ((unsigned)(ch * 128 + kb * 16) ^ ((unsigned)(ch & 7) << 4)));
        acc2[q] = __builtin_amdgcn_mfma_f32_16x16x32_bf16(af, bfr, acc2[q], 0, 0, 0);
      }
    }
    float* Sp = S + (int64_t)bgc * 2048;
#pragma unroll
    for (int q = 0; q < 2; ++q) {
      int ch = (wave * 2 + q) * 16 + fr;
#pragma unroll
      for (int j = 0; j < 4; ++j) Sp[(kq * 4 + j) * 128 + ch] = acc2[q][j];
    }
  }
}

// ---------------- Phase C: combine (inline) + y = tril(K)@U + ce@H + gate ---
template <int PREP, int GM>
__global__ __launch_bounds__(256) void ssm_out(const float* __restrict__ ssmp,
                                               const bf16_t* __restrict__ pb,
                                               const float* __restrict__ A_log,
                                               const bf16_t* __restrict__ u,
                                               const float* __restrict__ S,
                                               const float* __restrict__ Etot,
                                               const float* __restrict__ gate_f,
                                               const bf16_t* __restrict__ gate_b,
                                               int gstride,
                                               bf16_t* __restrict__ yout) {
  __shared__ __align__(16) float cf[64 * 48];
  __shared__ __align__(16) float Lb[64 * 16];
  __shared__ __align__(16) bf16_t Km[64 * 64];
  __shared__ __align__(16) bf16_t Ut[128 * 64];
  __shared__ __align__(16) bf16_t Hb[128 * 32];
  int bgc = blockIdx.x;
  int bg = bgc >> 4, c = bgc & 15;
  int b = bg >> 4, g = bg & 15;
  int t0 = c * 64;
  int tid = threadIdx.x;
  int lane = tid & 63, wave = tid >> 6;
  {
    int lt = tid >> 4;
    int c8 = (tid & 15) * 8;
#pragma unroll
    for (int p = 0; p < 4; ++p) {
      int t = p * 16 + lt;
      bf16x8 v = *(const bf16x8*)(u + ((int64_t)(b * 1024) + t0 + t) * 2048 + g * 128 + c8);
#pragma unroll
      for (int j = 0; j < 8; ++j)
        Ut[(c8 + j) * 64 + (((t >> 3) ^ j) << 3) + (t & 7)] = v[j];
    }
  }
  // inline sequential combine over preceding chunks -> Hb[ch][s] (bf16)
  {
    int ch = tid & 127, s0 = (tid >> 7) * 8;
    const float* Sp = S + (int64_t)(bg * 16) * 2048;
    const float* Ep = Etot + (int64_t)(bg * 16) * 16;
    float h[8];
#pragma unroll
    for (int j = 0; j < 8; ++j) h[j] = 0.f;
    for (int cc = 0; cc < c; ++cc) {
#pragma unroll
      for (int j = 0; j < 8; ++j)
        h[j] = Ep[cc * 16 + s0 + j] * h[j] +
               Sp[(int64_t)cc * 2048 + (s0 + j) * 128 + ch];
    }
#pragma unroll
    for (int j = 0; j < 8; ++j) {
      Hb[ch * 32 + s0 + j] = (bf16_t)h[j];
      Hb[ch * 32 + 16 + s0 + j] = (bf16_t)0.f;
    }
  }
  if (PREP) {
    prep_rows(pb, A_log, cf, b, g, t0, tid);
  } else {
    const float4* src = (const float4*)(ssmp + ((int64_t)bg * 1024 + t0) * 48);
    float4* dst = (float4*)cf;
#pragma unroll
    for (int i = 0; i < 3; ++i) dst[i * 256 + tid] = src[i * 256 + tid];
  }
  __syncthreads();
  if (tid < 16) {
    float l = 0.f;
    for (int t = 0; t < 64; ++t) { l += cf[t * 48 + tid]; Lb[t * 16 + tid] = l; }
  }
  __syncthreads();
  {
    int t = tid >> 2, tp0 = (tid & 3) * 16;
    float4 cv[4], lv[4];
#pragma unroll
    for (int i = 0; i < 4; ++i) {
      cv[i] = *(const float4*)&cf[t * 48 + 32 + i * 4];
      lv[i] = *(const float4*)&Lb[t * 16 + i * 4];
    }
    float kv[16];
#pragma unroll
    for (int i = 0; i < 16; ++i) {
      int tp = tp0 + i;
      float k = 0.f;
      if (tp <= t) {
#pragma unroll
        for (int q = 0; q < 4; ++q) {
          float4 lpv = *(const float4*)&Lb[tp * 16 + q * 4];
          float4 fbv = *(const float4*)&cf[tp * 48 + 16 + q * 4];
          k += cv[q].x * __expf(lv[q].x - lpv.x) * fbv.x
             + cv[q].y * __expf(lv[q].y - lpv.y) * fbv.y
             + cv[q].z * __expf(lv[q].z - lpv.z) * fbv.z
             + cv[q].w * __expf(lv[q].w - lpv.w) * fbv.w;
        }
      }
      kv[i] = k;
    }
    bf16x8 lo, hi;
#pragma unroll
    for (int i = 0; i < 8; ++i) { lo[i] = (bf16_t)kv[i]; hi[i] = (bf16_t)kv[8 + i]; }
    unsigned b0 = (unsigned)(t * 128 + tp0 * 2) ^ ((unsigned)(t & 7) << 4);
    unsigned b1 = (unsigned)(t * 128 + tp0 * 2 + 16) ^ ((unsigned)(t & 7) << 4);
    *(bf16x8*)((char*)Km + b0) = lo;
    *(bf16x8*)((char*)Km + b1) = hi;
  }
  __syncthreads();
  int fr = lane & 15, kq = lane >> 4;
  int trow = (wave >> 1) * 32, wc = (wave & 1) * 64;
  f32x4 acc[2][4] = {};
#pragma unroll
  for (int kk = 0; kk < 2; ++kk) {
    int kb = kk * 4 + kq;
    bf16x8 af[2];
#pragma unroll
    for (int mi = 0; mi < 2; ++mi) {
      int row = trow + mi * 16 + fr;
      af[mi] = *(const bf16x8*)((const char*)Km +
                 ((unsigned)(row * 128 + kb * 16) ^ ((unsigned)(row & 7) << 4)));
    }
#pragma unroll
    for (int ni = 0; ni < 4; ++ni) {
      int ch = wc + ni * 16 + fr;
      bf16x8 bfr = *(const bf16x8*)((const char*)Ut +
                     ((unsigned)(ch * 128 + kb * 16) ^ ((unsigned)(ch & 7) << 4)));
#pragma unroll
      for (int mi = 0; mi < 2; ++mi)
        acc[mi][ni] = __builtin_amdgcn_mfma_f32_16x16x32_bf16(af[mi], bfr, acc[mi][ni], 0, 0, 0);
    }
  }
  {
    int s0 = kq * 8;
    bf16x8 cef[2];
    if (s0 < 16) {
#pragma unroll
      for (int mi = 0; mi < 2; ++mi) {
        int t = trow + mi * 16 + fr;
#pragma unroll
        for (int j = 0; j < 8; ++j)
          cef[mi][j] = (bf16_t)(cf[t * 48 + 32 + s0 + j] * __expf(Lb[t * 16 + s0 + j]));
      }
    } else {
#pragma unroll
      for (int mi = 0; mi < 2; ++mi)
#pragma unroll
        for (int j = 0; j < 8; ++j) cef[mi][j] = (bf16_t)0.f;
    }
#pragma unroll
    for (int ni = 0; ni < 4; ++ni) {
      int ch = wc + ni * 16 + fr;
      bf16x8 bhf = *(const bf16x8*)((const char*)Hb + ch * 64 + s0 * 2);
#pragma unroll
      for (int mi = 0; mi < 2; ++mi)
        acc[mi][ni] = __builtin_amdgcn_mfma_f32_16x16x32_bf16(cef[mi], bhf, acc[mi][ni], 0, 0, 0);
    }
  }
  {
    int64_t rowbase = (int64_t)b * 1024 + t0;
    int colbase = g * 128;
#pragma unroll
    for (int mi = 0; mi < 2; ++mi) {
#pragma unroll
      for (int ni = 0; ni < 4; ++ni) {
        int col = colbase + wc + ni * 16 + fr;
#pragma unroll
        for (int j = 0; j < 4; ++j) {
          int t = trow + mi * 16 + kq * 4 + j;
          float sg;
          if (GM) {
            sg = (float)gate_b[(rowbase + t) * 2048 + col];
          } else {
            float gv = gate_f[(rowbase + t) * (int64_t)gstride + col];
            sg = gv / (1.f + __expf(-gv));
          }
          yout[(rowbase + t) * 2048 + col] = (bf16_t)(acc[mi][ni][j] * sg);
        }
      }
    }
  }
}

// ======== epilogue helper (fallback gemm_bt only) ========
template <int EPI>
__device__ __forceinline__ void epi_store(float v, int64_t r, int64_t cn, int N,
                                          float* Cz, const float* bias,
                                          const float* res, bf16_t* obf,
                                          bf16_t* ogate, int z) {
  if (EPI & 1) v += bias[cn];
  if (EPI & 2) v += res[r * N + cn];
  if (EPI & 4) {
    float sv = v / (1.f + __expf(-v));
    if (cn < 2048) obf[r * 2048 + cn] = (bf16_t)sv;
    else ogate[r * 2048 + cn - 2048] = (bf16_t)sv;
  } else if (EPI & 8) {
    obf[r * N + cn] = (bf16_t)(v / (1.f + __expf(-v)));
  } else if (EPI & 16) {
    obf[(int64_t)z * ROWS * N + r * N + cn] = (bf16_t)v;
  } else {
    Cz[r * N + cn] = v;
  }
}

// bijective XCD swizzle over flattened grid (identity if nwg%8 != 0)
__device__ __forceinline__ void xcd_swz(int& bx, int& by, int& bz) {
  int gx = gridDim.x, gy = gridDim.y, gz = gridDim.z;
  int flat = blockIdx.x + gx * (blockIdx.y + gy * blockIdx.z);
  int nwg = gx * gy * gz;
  int swz = flat;
  if ((nwg & 7) == 0) swz = (flat & 7) * (nwg >> 3) + (flat >> 3);
  bx = swz % gx;
  int rem = swz / gx;
  by = rem % gy;
  bz = rem / gy;
}

// ---------------- bf16 GEMM 128x128, double-buffered 2-phase (fallback) -----
template <int EPI>
__global__ __launch_bounds__(256) void gemm_bt(const bf16_t* __restrict__ A,
                                               const bf16_t* __restrict__ Bw,
                                               float* __restrict__ C,
                                               const float* __restrict__ bias,
                                               const float* __restrict__ res,
                                               bf16_t* __restrict__ obf,
                                               bf16_t* __restrict__ ogate,
                                               int N, int Kps) {
  __shared__ bf16_t As[2][128 * 64];
  __shared__ bf16_t Bs[2][128 * 64];
  const int tid = threadIdx.x;
  const int wave = tid >> 6;
  const int lane = tid & 63;
  int bxi, byi, bzi;
  xcd_swz(bxi, byi, bzi);
  const int64_t m0 = (int64_t)byi * 128;
  const int64_t n0 = (int64_t)bxi * 128;
  const int K = Kps * gridDim.z;
  const int kbeg = bzi * Kps;
  float* Cz = C + (int64_t)bzi * ROWS * N;
  const int wm = (wave >> 1) * 64;
  const int wn = (wave & 1) * 64;
  f32x4 acc[4][4] = {};

  const int er = tid >> 3;
  const int ec = (tid * 8) & 63;
  const int fr = lane & 15;
  const int kq = (lane >> 4) * 8;

  auto stage = [&](int buf, int k0) {
#pragma unroll
    for (int i = 0; i < 4; ++i) {
      const bf16_t* ga = A + (m0 + er + i * 32) * K + k0 + ec;
      __builtin_amdgcn_global_load_lds((gvoid_t*)ga,
                                       (lvoid_t*)&As[buf][(i * 256 + wave * 64) * 8],
                                       16, 0, 0);
    }
#pragma unroll
    for (int i = 0; i < 4; ++i) {
      const bf16_t* gb = Bw + (n0 + er + i * 32) * K + k0 + ec;
      __builtin_amdgcn_global_load_lds((gvoid_t*)gb,
                                       (lvoid_t*)&Bs[buf][(i * 256 + wave * 64) * 8],
                                       16, 0, 0);
    }
  };
  auto compute = [&](int buf) {
#pragma unroll
    for (int kk = 0; kk < 2; ++kk) {
      bf16x8 af[4], bv[4];
#pragma unroll
      for (int mi = 0; mi < 4; ++mi)
        af[mi] = *reinterpret_cast<const bf16x8*>(&As[buf][(wm + mi * 16 + fr) * 64 + kk * 32 + kq]);
#pragma unroll
      for (int ni = 0; ni < 4; ++ni)
        bv[ni] = *reinterpret_cast<const bf16x8*>(&Bs[buf][(wn + ni * 16 + fr) * 64 + kk * 32 + kq]);
#pragma unroll
      for (int mi = 0; mi < 4; ++mi)
#pragma unroll
        for (int ni = 0; ni < 4; ++ni)
          acc[mi][ni] = __builtin_amdgcn_mfma_f32_16x16x32_bf16(af[mi], bv[ni], acc[mi][ni], 0, 0, 0);
    }
  };

  const int nk = Kps >> 6;  // assumed even
  stage(0, kbeg);
  asm volatile("s_waitcnt vmcnt(0)" ::: "memory");
  __builtin_amdgcn_s_barrier();
  int kc = kbeg;
  for (int t = 0; t < nk; t += 2) {
    stage(1, kc + 64);
    compute(0);
    asm volatile("s_waitcnt vmcnt(0)" ::: "memory");
    __builtin_amdgcn_s_barrier();
    if (t + 2 < nk) stage(0, kc + 128);
    compute(1);
    asm volatile("s_waitcnt vmcnt(0)" ::: "memory");
    __builtin_amdgcn_s_barrier();
    kc += 128;
  }

  const int crow = (lane >> 4) * 4;
  const int ccol = lane & 15;
#pragma unroll
  for (int mi = 0; mi < 4; ++mi)
#pragma unroll
    for (int ni = 0; ni < 4; ++ni)
#pragma unroll
      for (int j = 0; j < 4; ++j)
        epi_store<EPI>(acc[mi][ni][j], m0 + wm + mi * 16 + crow + j,
                       n0 + wn + ni * 16 + ccol, N, Cz, bias, res, obf, ogate,
                       bzi);
}

// ---------------- param GEMM (128x128, SK=4) + W_out/W_f1/W_f2 conversion ---
__global__ __launch_bounds__(256) void gemm_param_conv(
    const bf16_t* __restrict__ A, const bf16_t* __restrict__ Bw,
    bf16_t* __restrict__ pout,
    const float* __restrict__ W_out, const float* __restrict__ W_f1,
    const float* __restrict__ W_f2,
    bf16_t* o_out, bf16_t* o_f1, bf16_t* o_f2) {
  __shared__ bf16_t As[2][128 * 64];
  __shared__ bf16_t Bs[2][128 * 64];
  const int tid = threadIdx.x;
  if (blockIdx.x >= 320) {
    conv3(blockIdx.x - 320, tid, W_out, W_f1, W_f2, o_out, o_f1, o_f2);
    return;
  }
  const int flat = blockIdx.x;
  const int swz = (flat & 7) * 40 + (flat >> 3);  // 320 % 8 == 0, bijective
  const int bxi = swz % 5;
  const int byi = (swz / 5) % 16;
  const int bzi = swz / 80;
  const int wave = tid >> 6;
  const int lane = tid & 63;
  const int64_t m0 = (int64_t)byi * 128;
  const int64_t n0 = (int64_t)bxi * 128;
  const int K = 2048, Kps = 512;
  const int kbeg = bzi * Kps;
  const int wm = (wave >> 1) * 64;
  const int wn = (wave & 1) * 64;
  f32x4 acc[4][4] = {};
  const int er = tid >> 3;
  const int ec = (tid * 8) & 63;
  const int fr = lane & 15;
  const int kq = (lane >> 4) * 8;

  auto stage = [&](int buf, int k0) {
#pragma unroll
    for (int i = 0; i < 4; ++i) {
      const bf16_t* ga = A + (m0 + er + i * 32) * K + k0 + ec;
      __builtin_amdgcn_global_load_lds((gvoid_t*)ga,
                                       (lvoid_t*)&As[buf][(i * 256 + wave * 64) * 8],
                                       16, 0, 0);
    }
#pragma unroll
    for (int i = 0; i < 4; ++i) {
      const bf16_t* gb = Bw + (n0 + er + i * 32) * K + k0 + ec;
      __builtin_amdgcn_global_load_lds((gvoid_t*)gb,
                                       (lvoid_t*)&Bs[buf][(i * 256 + wave * 64) * 8],
                                       16, 0, 0);
    }
  };
  auto compute = [&](int buf) {
#pragma unroll
    for (int kk = 0; kk < 2; ++kk) {
      bf16x8 af[4], bv[4];
#pragma unroll
      for (int mi = 0; mi < 4; ++mi)
        af[mi] = *reinterpret_cast<const bf16x8*>(&As[buf][(wm + mi * 16 + fr) * 64 + kk * 32 + kq]);
#pragma unroll
      for (int ni = 0; ni < 4; ++ni)
        bv[ni] = *reinterpret_cast<const bf16x8*>(&Bs[buf][(wn + ni * 16 + fr) * 64 + kk * 32 + kq]);
#pragma unroll
      for (int mi = 0; mi < 4; ++mi)
#pragma unroll
        for (int ni = 0; ni < 4; ++ni)
          acc[mi][ni] = __builtin_amdgcn_mfma_f32_16x16x32_bf16(af[mi], bv[ni], acc[mi][ni], 0, 0, 0);
    }
  };

  const int nk = Kps >> 6;  // 8
  stage(0, kbeg);
  asm volatile("s_waitcnt vmcnt(0)" ::: "memory");
  __builtin_amdgcn_s_barrier();
  int kc = kbeg;
  for (int t = 0; t < nk; t += 2) {
    stage(1, kc + 64);
    compute(0);
    asm volatile("s_waitcnt vmcnt(0)" ::: "memory");
    __builtin_amdgcn_s_barrier();
    if (t + 2 < nk) stage(0, kc + 128);
    compute(1);
    asm volatile("s_waitcnt vmcnt(0)" ::: "memory");
    __builtin_amdgcn_s_barrier();
    kc += 128;
  }

  const int crow = (lane >> 4) * 4;
  const int ccol = lane & 15;
  bf16_t* pz = pout + (int64_t)bzi * ROWS * PPAD;
#pragma unroll
  for (int mi = 0; mi < 4; ++mi)
#pragma unroll
    for (int ni = 0; ni < 4; ++ni)
#pragma unroll
      for (int j = 0; j < 4; ++j) {
        int64_t r = m0 + wm + mi * 16 + crow + j;
        int64_t cn = n0 + wn + ni * 16 + ccol;
        pz[r * PPAD + cn] = (bf16_t)acc[mi][ni][j];
      }
}

// ---------------- bf16 GEMM 128x128, 8-wave, depth-2 counted pipeline -------
// 64KB LDS -> 2 blocks/CU (16 waves/CU): cross-block overlap hides drains.
// Per K-tile: reads Q0+Q1 -> lgkm(6) -> MFMA Q0 -> lgkm(0)+barrier ->
// restage buf (t+2) -> MFMA Q1 -> vmcnt(4)+barrier.
template <int EPI>
__global__ __launch_bounds__(512, 4) void gemm_big(const bf16_t* __restrict__ A,
                                                   const bf16_t* __restrict__ Bw,
                                                   float* __restrict__ C,
                                                   const float* __restrict__ bias,
                                                   const float* __restrict__ res,
                                                   bf16_t* __restrict__ obf,
                                                   bf16_t* __restrict__ ogate,
                                                   int N, int Kps) {
  __shared__ bf16_t As[2][128 * 64];
  __shared__ bf16_t Bs[2][128 * 64];
  const int tid = threadIdx.x;
  const int wave = tid >> 6;
  const int lane = tid & 63;
  int bxi, byi, bzi;
  xcd_swz(bxi, byi, bzi);
  const int64_t m0 = (int64_t)byi * 128;
  const int64_t n0 = (int64_t)bxi * 128;
  const int K = Kps * gridDim.z;
  const int kbeg = bzi * Kps;
  float* Cz = C + (int64_t)bzi * ROWS * N;
  (void)Cz; (void)res;
  const int wm = (wave >> 1) * 32;   // 4 M-wave rows of 32
  const int wc = (wave & 1) * 64;    // 2 N-wave cols of 64
  const int fr = lane & 15;
  const int kq16 = (lane >> 4) * 16;
  const int er = tid >> 3;                              // staging row 0..63
  const int ec_sw = ((tid & 7) * 8) ^ ((er & 7) << 3);  // swizzled src col
  f32x4 acc[2][4] = {};

  auto stage = [&](int buf, int k0) {
#pragma unroll
    for (int i = 0; i < 2; ++i) {
      const bf16_t* ga = A + (m0 + er + i * 64) * K + k0 + ec_sw;
      __builtin_amdgcn_global_load_lds((gvoid_t*)ga,
          (lvoid_t*)((char*)&As[buf][0] + i * 8192 + wave * 1024), 16, 0, 0);
    }
#pragma unroll
    for (int i = 0; i < 2; ++i) {
      const bf16_t* gb = Bw + (n0 + er + i * 64) * K + k0 + ec_sw;
      __builtin_amdgcn_global_load_lds((gvoid_t*)gb,
          (lvoid_t*)((char*)&Bs[buf][0] + i * 8192 + wave * 1024), 16, 0, 0);
    }
  };

  const int nk = Kps >> 6;
  stage(0, kbeg);
  if (nk > 1) {
    stage(1, kbeg + 64);
    asm volatile("s_waitcnt vmcnt(4)" ::: "memory");
  } else {
    asm volatile("s_waitcnt vmcnt(0)" ::: "memory");
  }
  __builtin_amdgcn_s_barrier();
  __builtin_amdgcn_sched_barrier(0);

  for (int t = 0; t < nk; ++t) {
    const int buf = t & 1;
    bf16x8 af[2][2], bf[2][4];
#pragma unroll
    for (int kk = 0; kk < 2; ++kk) {
#pragma unroll
      for (int mi = 0; mi < 2; ++mi) {
        int r = wm + mi * 16 + fr;
        af[kk][mi] = *(const bf16x8*)((const char*)&As[buf][0] + r * 128 +
                       ((kk * 64 + kq16) ^ ((r & 7) << 4)));
      }
#pragma unroll
      for (int ni = 0; ni < 4; ++ni) {
        int r = wc + ni * 16 + fr;
        bf[kk][ni] = *(const bf16x8*)((const char*)&Bs[buf][0] + r * 128 +
                       ((kk * 64 + kq16) ^ ((r & 7) << 4)));
      }
    }
    asm volatile("s_waitcnt lgkmcnt(6)" ::: "memory");
    __builtin_amdgcn_sched_barrier(0);
    __builtin_amdgcn_s_setprio(1);
#pragma unroll
    for (int mi = 0; mi < 2; ++mi)
#pragma unroll
      for (int ni = 0; ni < 4; ++ni)
        acc[mi][ni] = __builtin_amdgcn_mfma_f32_16x16x32_bf16(
            af[0][mi], bf[0][ni], acc[mi][ni], 0, 0, 0);
    __builtin_amdgcn_s_setprio(0);
    __builtin_amdgcn_sched_barrier(0);
    asm volatile("s_waitcnt lgkmcnt(0)" ::: "memory");
    __builtin_amdgcn_sched_barrier(0);
    __builtin_amdgcn_s_barrier();          // all waves done reading buf
    __builtin_amdgcn_sched_barrier(0);
    if (t + 2 < nk) stage(buf, kbeg + (t + 2) * 64);  // overwrite buf, 2 ahead
    __builtin_amdgcn_s_setprio(1);
#pragma unroll
    for (int mi = 0; mi < 2; ++mi)
#pragma unroll
      for (int ni = 0; ni < 4; ++ni)
        acc[mi][ni] = __builtin_amdgcn_mfma_f32_16x16x32_bf16(
            af[1][mi], bf[1][ni], acc[mi][ni], 0, 0, 0);
    __builtin_amdgcn_s_setprio(0);
    if (t + 1 < nk) {
      if (t + 2 < nk) asm volatile("s_waitcnt vmcnt(4)" ::: "memory");
      else            asm volatile("s_waitcnt vmcnt(0)" ::: "memory");
      __builtin_amdgcn_s_barrier();        // stage(t+1) landed
      __builtin_amdgcn_sched_barrier(0);
    }
  }

  // ---- coalesced epilogue: per-wave 32x64 bf16 tile in dead Bs, XOR-swizzled
  __syncthreads();
  {
    char* ep = (char*)&Bs[0][0] + wave * 4096;  // 32 rows x 128B
    const int crow = (lane >> 4) * 4;
    const int ccol = lane & 15;
#pragma unroll
    for (int mi = 0; mi < 2; ++mi) {
#pragma unroll
      for (int ni = 0; ni < 4; ++ni) {
        int lc = ni * 16 + ccol;
        float bv = (EPI & 1) ? bias[n0 + wc + lc] : 0.f;
#pragma unroll
        for (int j = 0; j < 4; ++j) {
          int lr = mi * 16 + crow + j;
          float v = acc[mi][ni][j] + bv;
          if (EPI & 12) v = v / (1.f + __expf(-v));
          *(bf16_t*)(ep + lr * 128 + ((lc * 2) ^ ((lr & 7) << 4))) = (bf16_t)v;
        }
      }
    }
    // read back row-major, 16B per lane; 8 consecutive lanes = one 128B row
#pragma unroll
    for (int i = 0; i < 4; ++i) {
      int idx = i * 64 + lane;
      int row = idx >> 3;
      int grp = idx & 7;
      bf16x8 v = *(const bf16x8*)(ep + row * 128 + ((grp * 16) ^ ((row & 7) << 4)));
      int64_t r = m0 + wm + row;
      int64_t cn = n0 + wc + grp * 8;
      bf16_t* dst;
      if (EPI & 4) {
        dst = (cn < 2048) ? (obf + r * 2048 + cn) : (ogate + r * 2048 + cn - 2048);
      } else if (EPI & 16) {
        dst = obf + (int64_t)bzi * ROWS * N + r * N + cn;
      } else {
        dst = obf + r * N + cn;
      }
      *(bf16x8*)dst = v;
    }
  }
}

extern "C" void kernel_launch(void* const* d_in, const int* in_sizes, int n_in,
                              void* d_out, int out_size, void* d_ws, size_t ws_size,
                              hipStream_t stream) {
  const float* x       = (const float*)d_in[0];
  const float* A_log   = (const float*)d_in[1];
  const float* g1      = (const float*)d_in[2];
  const float* g2      = (const float*)d_in[3];
  const float* W_in    = (const float*)d_in[4];
  const float* W_param = (const float*)d_in[5];
  const float* W_out   = (const float*)d_in[6];
  const float* W_ffn1  = (const float*)d_in[7];
  const float* b_ffn1  = (const float*)d_in[8];
  const float* W_ffn2  = (const float*)d_in[9];
  const float* b_ffn2  = (const float*)d_in[10];
  float* out = (float*)d_out;

  char* ws = (char*)d_ws;
  size_t off = 0;
  auto alloc = [&](size_t bytes) {
    char* p = ws + off;
    off += (bytes + 255) & ~(size_t)255;
    return p;
  };
  bf16_t* wb_in  = (bf16_t*)alloc(4096ull * 1024 * 2);
  bf16_t* wb_par = (bf16_t*)alloc((size_t)PPAD * 2048 * 2);
  bf16_t* wb_out = (bf16_t*)alloc(1024ull * 2048 * 2);
  bf16_t* wb_f1  = (bf16_t*)alloc(4096ull * 1024 * 2);
  bf16_t* wb_f2  = (bf16_t*)alloc(1024ull * 4096 * 2);
  bf16_t* zbuf   = (bf16_t*)alloc(2048ull * 1024 * 2);   // z, later h2
  float*  xzg    = (float*)alloc(2048ull * 4096 * 4);    // sgate bf16 (sk) / fp32 (fallback)
  float*  params = (float*)alloc(2048ull * PPAD * 4);    // fallback GEMM out; S/Etot overlay
  float*  ssmp   = (float*)alloc(32ull * 1024 * 48 * 4); // fallback only
  float*  xmid   = (float*)alloc(2048ull * 1024 * 4);    // bf16 (sk) / fp32 (fallback)
  char*   regA   = alloc(2048ull * 4096 * 2);            // 16MB union
  bf16_t* xz_act = (bf16_t*)regA;
  bf16_t* y_b16  = (bf16_t*)(regA + 2048ull * 2048 * 2);
  bf16_t* f_act  = (bf16_t*)regA;
  bf16_t* sgate  = (bf16_t*)xzg;                         // [2048][2048] bf16 (sk)
  bf16_t* xmid_b = (bf16_t*)xmid;                        // bf16 residual (sk)
  float* Sbuf = params;
  float* Etot = params + 32ull * 16 * 16 * 128;
  float*  psum = (float*)alloc(4ull * ROWS * 1024 * 4);  // fp32 partials (fallback)
  bf16_t* pb16 = (bf16_t*)psum;                          // bf16 partials overlay
  const bool sk = (off <= ws_size);

  dim3 b256(256), b512(512);
  // W_in/W_param -> bf16 + z = rmsnorm(x,g1)
  prep0<<<7424, b256, 0, stream>>>(W_in, W_param, wb_in, wb_par, x, g1, zbuf);

  if (sk) {
    // xz|gate = z @ W_in^T, fused: silu(xz)->xz_act, silu(gate)->sgate (bf16)
    gemm_big<4><<<dim3(32, 16), b512, 0, stream>>>(zbuf, wb_in, psum, nullptr, nullptr, xz_act, sgate, 4096, 1024);
    // param partials (bf16, SK=4) + W_out/W_f1/W_f2 conversion riding along
    gemm_param_conv<<<10560, b256, 0, stream>>>(xz_act, wb_par, pb16,
                                                W_out, W_ffn1, W_ffn2,
                                                wb_out, wb_f1, wb_f2);
    // chunked scan (coefficient prep inlined; combine inlined in ssm_out)
    ssm_chunk<1><<<480, b256, 0, stream>>>(nullptr, pb16, A_log, xz_act, Sbuf, Etot);
    ssm_out<1, 1><<<512, b256, 0, stream>>>(nullptr, pb16, A_log, xz_act, Sbuf, Etot, nullptr, sgate, 2048, y_b16);
    // xmid = x + y @ W_out^T (SK=4, bf16 partials) fused reduce+rmsnorm
    gemm_big<16><<<dim3(8, 16, 4), b512, 0, stream>>>(y_b16, wb_out, psum, nullptr, nullptr, pb16, nullptr, 1024, 512);
    reduce_rms<<<2048, b256, 0, stream>>>(pb16, x, g2, xmid_b, zbuf);
    // ffn1 + bias + silu -> f_act bf16 (fused)
    gemm_big<9><<<dim3(32, 16), b512, 0, stream>>>(zbuf, wb_f1, psum, b_ffn1, nullptr, f_act, nullptr, 4096, 1024);
    // out = xmid + b_ffn2 + f_act @ W_ffn2^T (SK=4, bf16 partials)
    gemm_big<16><<<dim3(8, 16, 4), b512, 0, stream>>>(f_act, wb_f2, psum, nullptr, nullptr, pb16, nullptr, 1024, 1024);
    reduce_bias<<<2048, b256, 0, stream>>>(pb16, xmid_b, b_ffn2, out);
  } else {
    cvt3_k<<<10240, b256, 0, stream>>>(W_out, W_ffn1, W_ffn2, wb_out, wb_f1, wb_f2);
    gemm_bt<0><<<dim3(32, 16), b256, 0, stream>>>(zbuf, wb_in, xzg, nullptr, nullptr, nullptr, nullptr, 4096, 1024);
    silu_cvt<<<4096, b256, 0, stream>>>(xzg, xz_act, 4096, 2048);
    gemm_bt<0><<<dim3(PPAD / 128, 16), b256, 0, stream>>>(xz_act, wb_par, params, nullptr, nullptr, nullptr, nullptr, PPAD, 2048);
    ssm_prep<<<128, b256, 0, stream>>>(params, A_log, ssmp);
    ssm_chunk<0><<<480, b256, 0, stream>>>(ssmp, nullptr, A_log, xz_act, Sbuf, Etot);
    ssm_out<0, 0><<<512, b256, 0, stream>>>(ssmp, nullptr, A_log, xz_act, Sbuf, Etot, xzg + 2048, nullptr, 4096, y_b16);
    gemm_bt<2><<<dim3(8, 16), b256, 0, stream>>>(y_b16, wb_out, xmid, nullptr, x, nullptr, nullptr, 1024, 2048);
    rmsnorm_k<<<2048, b256, 0, stream>>>(xmid, g2, zbuf);
    gemm_bt<1><<<dim3(32, 16), b256, 0, stream>>>(zbuf, wb_f1, xzg, b_ffn1, nullptr, nullptr, nullptr, 4096, 1024);
    silu_cvt<<<8192, b256, 0, stream>>>(xzg, f_act, 4096, 4096);
    gemm_bt<3><<<dim3(8, 16), b256, 0, stream>>>(f_act, wb_f2, out, b_ffn2, xmid, nullptr, nullptr, 1024, 4096);
  }
}